// Round 1
// baseline (8755.647 us; speedup 1.0000x reference)
//
#include <hip/hip_runtime.h>

#define NN 160
#define N3 4096000           // 160^3
#define TPI 6.28318530717958647692f
#define LAM_F 0.05f

// ---------------- complex helpers ----------------
__device__ __forceinline__ float2 cxmul(float2 a, float2 b){
    return make_float2(a.x*b.x - a.y*b.y, a.x*b.y + a.y*b.x);
}
__device__ __forceinline__ float2 cadd(float2 a, float2 b){ return make_float2(a.x+b.x, a.y+b.y); }
__device__ __forceinline__ float2 csub(float2 a, float2 b){ return make_float2(a.x-b.x, a.y-b.y); }
__device__ __forceinline__ float2 cscale(float2 a, float s){ return make_float2(a.x*s, a.y*s); }
__device__ __forceinline__ float2 shfl2(float2 v, int m){
    return make_float2(__shfl_xor(v.x, m, 64), __shfl_xor(v.y, m, 64));
}
__device__ __forceinline__ int br5(int l){
    return ((l&1)<<4)|((l&2)<<2)|(l&4)|((l&8)>>2)|((l&16)>>4);
}
// e(theta) = cos - i*S*sin ; S=+1 forward (e^{-i}), S=-1 inverse (e^{+i})
template<int SGN>
__device__ __forceinline__ float2 twid(float ang){
    float s, c; sincosf(ang, &s, &c);
    return make_float2(c, (SGN>0) ? -s : s);
}

// ---------------- radix-5 DFT (in registers) ----------------
template<int SGN>
__device__ __forceinline__ void dft5(float2 y[5]){
    const float C1 = 0.30901699437494742f;   // cos 72
    const float C2 = -0.80901699437494742f;  // cos 144
    const float S1 = 0.95105651629515357f;   // sin 72
    const float S2 = 0.58778525229247312f;   // sin 144
    float2 x0=y[0], x1=y[1], x2=y[2], x3=y[3], x4=y[4];
    float2 t1=cadd(x1,x4), t2=cadd(x2,x3), t3=csub(x1,x4), t4=csub(x2,x3);
    y[0] = cadd(x0, cadd(t1,t2));
    float2 a1 = make_float2(x0.x + C1*t1.x + C2*t2.x, x0.y + C1*t1.y + C2*t2.y);
    float2 a2 = make_float2(x0.x + C2*t1.x + C1*t2.x, x0.y + C2*t1.y + C1*t2.y);
    const float sg = (SGN>0) ? 1.f : -1.f;
    float2 b1 = make_float2(sg*(S1*t3.x + S2*t4.x), sg*(S1*t3.y + S2*t4.y));
    float2 b2 = make_float2(sg*(S2*t3.x - S1*t4.x), sg*(S2*t3.y - S1*t4.y));
    y[1] = make_float2(a1.x + b1.y, a1.y - b1.x);
    y[4] = make_float2(a1.x - b1.y, a1.y + b1.x);
    y[2] = make_float2(a2.x + b2.y, a2.y - b2.x);
    y[3] = make_float2(a2.x - b2.y, a2.y + b2.x);
}

__device__ __forceinline__ float2 bfly(float2 v, int m, float2 tw, int l){
    float2 o = shfl2(v, m);
    float2 s = cadd(v, o);
    float2 d = cxmul(csub(o, v), tw);
    return (l & m) ? d : s;
}

// full 160-pt FFT of one line: lane l in [0,32) holds y[n1]=x[n1*32+l] on entry.
// On exit, slot k holds X[k + 5*br5(l)].
template<int SGN>
__device__ __forceinline__ void linefft(float2 y[5], int l){
    dft5<SGN>(y);
    float2 w1 = twid<SGN>(TPI * (float)l * (1.f/160.f));
    float2 w2 = cxmul(w1,w1);
    float2 w3 = cxmul(w2,w1);
    float2 w4 = cxmul(w2,w2);
    y[1]=cxmul(y[1],w1); y[2]=cxmul(y[2],w2); y[3]=cxmul(y[3],w3); y[4]=cxmul(y[4],w4);
    float2 tw16 = twid<SGN>(TPI * (float)(l & 15) * (1.f/32.f));
    float2 tw8  = twid<SGN>(TPI * (float)(l & 7)  * (1.f/16.f));
    float2 tw4  = twid<SGN>(TPI * (float)(l & 3)  * (1.f/8.f));
    float2 tw2  = twid<SGN>(TPI * (float)(l & 1)  * (1.f/4.f));
    #pragma unroll
    for (int k=0;k<5;k++){
        float2 v = y[k];
        v = bfly(v,16,tw16,l);
        v = bfly(v, 8,tw8 ,l);
        v = bfly(v, 4,tw4 ,l);
        v = bfly(v, 2,tw2 ,l);
        float2 o = shfl2(v,1);
        v = (l&1) ? csub(o,v) : cadd(v,o);
        y[k] = v;
    }
}

// ---------------- z-axis (contiguous) FFT passes ----------------
// MODE 0: real in -> complex out, forward.
// MODE 1: complex in -> real out = m2w * re/160, inverse.  (PRE: m2w precomputed)
// MODE 2: complex in -> real out = LAM*aux + re/160, inverse.
template<int MODE, bool PRE>
__global__ __launch_bounds__(256) void fft_z_kernel(
    const void* __restrict__ inp, void* __restrict__ outp,
    const float* __restrict__ aux, const float* __restrict__ mask,
    const float* __restrict__ wfull, int rsel)
{
    int tid = threadIdx.x;
    int l = tid & 31;
    int line = blockIdx.x * 8 + (tid >> 5);
    int base = line * NN;
    float2 y[5];
    if (MODE == 0) {
        const float* z = (const float*)inp;
        #pragma unroll
        for (int n1=0;n1<5;n1++) y[n1] = make_float2(z[base + n1*32 + l], 0.f);
        linefft<1>(y, l);
        float2* o = (float2*)outp;
        int o5 = base + 5*br5(l);
        #pragma unroll
        for (int k=0;k<5;k++) o[o5+k] = y[k];
    } else {
        const float2* c = (const float2*)inp;
        #pragma unroll
        for (int n1=0;n1<5;n1++) y[n1] = c[base + n1*32 + l];
        linefft<-1>(y, l);
        float* o = (float*)outp;
        int o5 = base + 5*br5(l);
        const float SC = 1.f/160.f;
        #pragma unroll
        for (int k=0;k<5;k++){
            int idx = o5 + k;
            float re = y[k].x * SC;
            if (MODE == 1) {
                float m = PRE ? aux[idx] : (mask[idx]*mask[idx]*wfull[idx*3 + rsel]);
                o[idx] = m * re;
            } else {
                o[idx] = LAM_F * aux[idx] + re;
            }
        }
    }
}

// ---------------- strided (y or x axis) in-place FFT pass ----------------
// Lines along axis with element stride `stride`; a block handles 32 adjacent-z
// lines (tile), staged in LDS with +1 padding (<=2-way bank conflicts).
template<int SGN>
__global__ __launch_bounds__(256) void fft_strided_kernel(float2* __restrict__ data,
                                                          int stride, int ostride)
{
    __shared__ float2 tile[NN][33];
    int b = blockIdx.x;
    int outer = b / 5;
    int zb = (b % 5) * 32;
    int tbase = outer * ostride + zb;
    int tid = threadIdx.x;
    for (int i = tid; i < NN*32; i += 256){
        int row = i >> 5, zi = i & 31;
        tile[row][zi] = data[tbase + row*stride + zi];
    }
    __syncthreads();
    int l = tid & 31, g = tid >> 5;
    #pragma unroll
    for (int rr=0; rr<4; rr++){
        int zi = g*4 + rr;
        float2 y[5];
        #pragma unroll
        for (int n1=0;n1<5;n1++) y[n1] = tile[l + 32*n1][zi];
        linefft<SGN>(y, l);
        int o5 = 5*br5(l);
        const float SC = (SGN>0) ? 1.f : (1.f/160.f);
        #pragma unroll
        for (int k=0;k<5;k++) tile[o5+k][zi] = cscale(y[k], SC);
    }
    __syncthreads();
    for (int i = tid; i < NN*32; i += 256){
        int row = i >> 5, zi = i & 31;
        data[tbase + row*stride + zi] = tile[row][zi];
    }
}

// ---------------- pointwise k-space ops ----------------
__global__ __launch_bounds__(256) void pw_mulK_kernel(const float2* __restrict__ in,
        const float* __restrict__ Kr, float2* __restrict__ out)
{
    int i = blockIdx.x*256 + threadIdx.x;
    float k = Kr[i];
    float2 v = in[i];
    out[i] = make_float2(v.x*k, v.y*k);
}
__global__ __launch_bounds__(256) void pw_accK_kernel(const float2* __restrict__ in,
        const float* __restrict__ Kr, float2* __restrict__ acc, int first)
{
    int i = blockIdx.x*256 + threadIdx.x;
    float k = Kr[i];
    float2 v = in[i];
    float2 a = first ? make_float2(0.f,0.f) : acc[i];
    acc[i] = make_float2(a.x + v.x*k, a.y + v.y*k);
}

// ---------------- kernel precompute: K_r = (1 - SMV_r) * D ----------------
__global__ __launch_bounds__(256) void precompute_kernel(float* __restrict__ K0,
        float* __restrict__ K1, float* __restrict__ K2)
{
    int i = blockIdx.x*256 + threadIdx.x;
    int iz = i % NN;
    int iy = (i / NN) % NN;
    int ix = i / (NN*NN);
    float fx = (float)((ix < 80) ? ix : ix - 160) * (1.f/160.f);
    float fy = (float)((iy < 80) ? iy : iy - 160) * (1.f/160.f);
    float fz = (float)((iz < 80) ? iz : iz - 160) * (1.f/160.f);
    float k2 = fx*fx + fy*fy + fz*fz;
    float D = (1.f/3.f) - ((k2 == 0.f) ? 0.f : (fz*fz / k2));
    float cx[4], cy[4], cz[4];
    #pragma unroll
    for (int d=0; d<4; d++){
        cx[d] = cosf(TPI * fx * (float)d);
        cy[d] = cosf(TPI * fy * (float)d);
        cz[d] = cosf(TPI * fz * (float)d);
    }
    float s1=0.f, s2=0.f, s3=0.f;
    #pragma unroll
    for (int dx=0; dx<4; dx++)
    #pragma unroll
    for (int dy=0; dy<4; dy++)
    #pragma unroll
    for (int dz=0; dz<4; dz++){
        int q = dx*dx + dy*dy + dz*dz;
        if (q > 9) continue;
        float wgt = (dx?2.f:1.f)*(dy?2.f:1.f)*(dz?2.f:1.f);
        float t = wgt * cx[dx]*cy[dy]*cz[dz];
        if (q <= 1) s1 += t;
        if (q <= 4) s2 += t;
        s3 += t;
    }
    K0[i] = (1.f - s1*(1.f/7.f))   * D;
    K1[i] = (1.f - s2*(1.f/33.f))  * D;
    K2[i] = (1.f - s3*(1.f/123.f)) * D;
}

__global__ __launch_bounds__(256) void m2w_kernel(const float* __restrict__ mask,
        const float* __restrict__ w, float* __restrict__ M0,
        float* __restrict__ M1, float* __restrict__ M2)
{
    int i = blockIdx.x*256 + threadIdx.x;
    float m = mask[i]; float mm = m*m;
    M0[i] = mm * w[3*i+0];
    M1[i] = mm * w[3*i+1];
    M2[i] = mm * w[3*i+2];
}

// ---------------- CG vector ops + reductions ----------------
__device__ __forceinline__ void block_atomic_add(double v, double* target){
    #pragma unroll
    for (int off=32; off>0; off>>=1) v += __shfl_down(v, off, 64);
    __shared__ double sm[4];
    int wv = threadIdx.x >> 6;
    if ((threadIdx.x & 63) == 0) sm[wv] = v;
    __syncthreads();
    if (threadIdx.x == 0) atomicAdd(target, sm[0]+sm[1]+sm[2]+sm[3]);
}

#define GSTRIDE (2048*256)

__global__ __launch_bounds__(256) void copy_kernel(const float* __restrict__ a, float* __restrict__ b){
    int i = blockIdx.x*256 + threadIdx.x;
    b[i] = a[i];
}
__global__ __launch_bounds__(256) void init_r_kernel(const float* __restrict__ bb,
        const float* __restrict__ Mx, float* __restrict__ r, float* __restrict__ p, double* s)
{
    double acc = 0.0;
    for (int i = blockIdx.x*256 + threadIdx.x; i < N3; i += GSTRIDE){
        float rv = bb[i] - Mx[i];
        r[i] = rv; p[i] = rv;
        acc += (double)rv * (double)rv;
    }
    block_atomic_add(acc, &s[0]);
}
__global__ __launch_bounds__(256) void dot_kernel(const float* __restrict__ a,
        const float* __restrict__ b, double* s)
{
    double acc = 0.0;
    for (int i = blockIdx.x*256 + threadIdx.x; i < N3; i += GSTRIDE)
        acc += (double)a[i] * (double)b[i];
    block_atomic_add(acc, &s[1]);
}
__global__ __launch_bounds__(256) void upd1_kernel(float* __restrict__ x, float* __restrict__ r,
        const float* __restrict__ p, const float* __restrict__ Ap, double* s)
{
    float alpha = (float)(s[0] / (s[1] + 1e-12));
    double acc = 0.0;
    for (int i = blockIdx.x*256 + threadIdx.x; i < N3; i += GSTRIDE){
        x[i] += alpha * p[i];
        float rn = r[i] - alpha * Ap[i];
        r[i] = rn;
        acc += (double)rn * (double)rn;
    }
    block_atomic_add(acc, &s[2]);
}
__global__ __launch_bounds__(256) void upd2_kernel(float* __restrict__ p,
        const float* __restrict__ r, double* s)
{
    float beta = (float)(s[2] / (s[0] + 1e-12));
    for (int i = blockIdx.x*256 + threadIdx.x; i < N3; i += GSTRIDE)
        p[i] = r[i] + beta * p[i];
}
__global__ void advance_kernel(double* s){
    if (threadIdx.x == 0){ s[0] = s[2]; s[1] = 0.0; s[2] = 0.0; }
}
__global__ void zero_kernel(double* s){
    if (threadIdx.x < 4) s[threadIdx.x] = 0.0;
}

// ---------------- host orchestration ----------------
extern "C" void kernel_launch(void* const* d_in, const int* in_sizes, int n_in,
                              void* d_out, int out_size, void* d_ws, size_t ws_size,
                              hipStream_t stream)
{
    (void)in_sizes; (void)n_in; (void)out_size;
    const float* w    = (const float*)d_in[0];   // [N3*3], R fastest
    const float* x2   = (const float*)d_in[1];   // [N3]
    const float* mask = (const float*)d_in[2];   // [N3]
    const float* bb   = (const float*)d_in[3];   // [N3]
    float* x = (float*)d_out;
    char* ws = (char*)d_ws;

    size_t off = 0;
    auto alloc = [&](size_t bytes)->void*{
        void* pp = ws + off;
        off += (bytes + 255) & ~(size_t)255;
        return pp;
    };
    float*  K0 = (float*) alloc((size_t)N3*4);
    float*  K1 = (float*) alloc((size_t)N3*4);
    float*  K2 = (float*) alloc((size_t)N3*4);
    float2* CF = (float2*)alloc((size_t)N3*8);
    float2* C1 = (float2*)alloc((size_t)N3*8);
    float2* CS = (float2*)alloc((size_t)N3*8);
    float*  T  = (float*) alloc((size_t)N3*4);
    float*  rr = (float*) alloc((size_t)N3*4);
    float*  pp = (float*) alloc((size_t)N3*4);
    float*  Ap = (float*) alloc((size_t)N3*4);
    double* S  = (double*)alloc(64);
    bool PRE = (ws_size >= off + 3*(((size_t)N3*4 + 255) & ~(size_t)255));
    float *M0=nullptr, *M1=nullptr, *M2=nullptr;
    if (PRE){
        M0 = (float*)alloc((size_t)N3*4);
        M1 = (float*)alloc((size_t)N3*4);
        M2 = (float*)alloc((size_t)N3*4);
    }
    const float* Ks[3] = {K0, K1, K2};
    const float* Ms[3] = {M0, M1, M2};

    zero_kernel<<<1, 64, 0, stream>>>(S);
    precompute_kernel<<<16000, 256, 0, stream>>>(K0, K1, K2);
    if (PRE) m2w_kernel<<<16000, 256, 0, stream>>>(mask, w, M0, M1, M2);
    copy_kernel<<<16000, 256, 0, stream>>>(x2, x);

    auto applyM = [&](const float* z, float* out){
        // forward 3D FFT of z -> CF
        fft_z_kernel<0,true><<<3200, 256, 0, stream>>>(z, CF, nullptr, nullptr, nullptr, 0);
        fft_strided_kernel<1><<<800, 256, 0, stream>>>(CF, NN,    NN*NN);   // y
        fft_strided_kernel<1><<<800, 256, 0, stream>>>(CF, NN*NN, NN);      // x
        for (int r = 0; r < 3; r++){
            pw_mulK_kernel<<<16000, 256, 0, stream>>>(CF, Ks[r], C1);
            fft_strided_kernel<-1><<<800, 256, 0, stream>>>(C1, NN*NN, NN); // x inv
            fft_strided_kernel<-1><<<800, 256, 0, stream>>>(C1, NN,    NN*NN); // y inv
            if (PRE)
                fft_z_kernel<1,true ><<<3200, 256, 0, stream>>>(C1, T, Ms[r], nullptr, nullptr, r);
            else
                fft_z_kernel<1,false><<<3200, 256, 0, stream>>>(C1, T, nullptr, mask, w, r);
            fft_z_kernel<0,true><<<3200, 256, 0, stream>>>(T, C1, nullptr, nullptr, nullptr, 0);
            fft_strided_kernel<1><<<800, 256, 0, stream>>>(C1, NN,    NN*NN); // y
            fft_strided_kernel<1><<<800, 256, 0, stream>>>(C1, NN*NN, NN);    // x
            pw_accK_kernel<<<16000, 256, 0, stream>>>(C1, Ks[r], CS, (r==0) ? 1 : 0);
        }
        fft_strided_kernel<-1><<<800, 256, 0, stream>>>(CS, NN*NN, NN);     // x inv
        fft_strided_kernel<-1><<<800, 256, 0, stream>>>(CS, NN,    NN*NN);  // y inv
        fft_z_kernel<2,true><<<3200, 256, 0, stream>>>(CS, out, z, nullptr, nullptr, 0);
    };

    // r = b - M(x2); p = r; rs = <r,r>
    applyM(x, Ap);
    init_r_kernel<<<2048, 256, 0, stream>>>(bb, Ap, rr, pp, S);

    for (int it = 0; it < 10; it++){
        applyM(pp, Ap);
        dot_kernel<<<2048, 256, 0, stream>>>(pp, Ap, S);
        upd1_kernel<<<2048, 256, 0, stream>>>(x, rr, pp, Ap, S);
        upd2_kernel<<<2048, 256, 0, stream>>>(pp, rr, S);
        advance_kernel<<<1, 64, 0, stream>>>(S);
    }
}

// Round 2
// 5705.016 us; speedup vs baseline: 1.5347x; 1.5347x over previous
//
#include <hip/hip_runtime.h>

#define NN 160
#define N3 4096000           // 160^3
#define WZ 16                // z-width of strided tiles
#define NBZ 10               // NN/WZ
#define TPI 6.28318530717958647692f
#define LAM_F 0.05f

// ---------------- complex helpers ----------------
__device__ __forceinline__ float2 cxmul(float2 a, float2 b){
    return make_float2(a.x*b.x - a.y*b.y, a.x*b.y + a.y*b.x);
}
__device__ __forceinline__ float2 cadd(float2 a, float2 b){ return make_float2(a.x+b.x, a.y+b.y); }
__device__ __forceinline__ float2 csub(float2 a, float2 b){ return make_float2(a.x-b.x, a.y-b.y); }
__device__ __forceinline__ float2 cscale(float2 a, float s){ return make_float2(a.x*s, a.y*s); }
__device__ __forceinline__ float2 shfl2(float2 v, int m){
    return make_float2(__shfl_xor(v.x, m, 64), __shfl_xor(v.y, m, 64));
}
__device__ __forceinline__ int br5(int l){
    return ((l&1)<<4)|((l&2)<<2)|(l&4)|((l&8)>>2)|((l&16)>>4);
}
template<int SGN>
__device__ __forceinline__ float2 twid(float ang){
    float s, c; sincosf(ang, &s, &c);
    return make_float2(c, (SGN>0) ? -s : s);
}

// ---------------- radix-5 DFT (in registers) ----------------
template<int SGN>
__device__ __forceinline__ void dft5(float2 y[5]){
    const float C1 = 0.30901699437494742f;
    const float C2 = -0.80901699437494742f;
    const float S1 = 0.95105651629515357f;
    const float S2 = 0.58778525229247312f;
    float2 x0=y[0], x1=y[1], x2=y[2], x3=y[3], x4=y[4];
    float2 t1=cadd(x1,x4), t2=cadd(x2,x3), t3=csub(x1,x4), t4=csub(x2,x3);
    y[0] = cadd(x0, cadd(t1,t2));
    float2 a1 = make_float2(x0.x + C1*t1.x + C2*t2.x, x0.y + C1*t1.y + C2*t2.y);
    float2 a2 = make_float2(x0.x + C2*t1.x + C1*t2.x, x0.y + C2*t1.y + C1*t2.y);
    const float sg = (SGN>0) ? 1.f : -1.f;
    float2 b1 = make_float2(sg*(S1*t3.x + S2*t4.x), sg*(S1*t3.y + S2*t4.y));
    float2 b2 = make_float2(sg*(S2*t3.x - S1*t4.x), sg*(S2*t3.y - S1*t4.y));
    y[1] = make_float2(a1.x + b1.y, a1.y - b1.x);
    y[4] = make_float2(a1.x - b1.y, a1.y + b1.x);
    y[2] = make_float2(a2.x + b2.y, a2.y - b2.x);
    y[3] = make_float2(a2.x - b2.y, a2.y + b2.x);
}

__device__ __forceinline__ float2 bfly(float2 v, int m, float2 tw, int l){
    float2 o = shfl2(v, m);
    float2 s = cadd(v, o);
    float2 d = cxmul(csub(o, v), tw);
    return (l & m) ? d : s;
}

// 160-pt FFT: lane l in [0,32) holds y[n1]=x[n1*32+l] on entry.
// On exit, slot k holds X[k + 5*br5(l)].
template<int SGN>
__device__ __forceinline__ void linefft(float2 y[5], int l){
    dft5<SGN>(y);
    float2 w1 = twid<SGN>(TPI * (float)l * (1.f/160.f));
    float2 w2 = cxmul(w1,w1);
    float2 w3 = cxmul(w2,w1);
    float2 w4 = cxmul(w2,w2);
    y[1]=cxmul(y[1],w1); y[2]=cxmul(y[2],w2); y[3]=cxmul(y[3],w3); y[4]=cxmul(y[4],w4);
    float2 tw16 = twid<SGN>(TPI * (float)(l & 15) * (1.f/32.f));
    float2 tw8  = twid<SGN>(TPI * (float)(l & 7)  * (1.f/16.f));
    float2 tw4  = twid<SGN>(TPI * (float)(l & 3)  * (1.f/8.f));
    float2 tw2  = twid<SGN>(TPI * (float)(l & 1)  * (1.f/4.f));
    #pragma unroll
    for (int k=0;k<5;k++){
        float2 v = y[k];
        v = bfly(v,16,tw16,l);
        v = bfly(v, 8,tw8 ,l);
        v = bfly(v, 4,tw4 ,l);
        v = bfly(v, 2,tw2 ,l);
        float2 o = shfl2(v,1);
        v = (l&1) ? csub(o,v) : cadd(v,o);
        y[k] = v;
    }
}

// per-radius pointer bundle (batched dispatches index with blockIdx.y)
struct RP {
    const float* K[3];
    float2* C[3];
    const float* M[3];
};

// ---------------- z-axis kernels ----------------
// real -> complex forward FFT along z
__global__ __launch_bounds__(256) void fft_z_first(const float* __restrict__ zin,
                                                   float2* __restrict__ out)
{
    int tid = threadIdx.x, l = tid & 31, g = tid >> 5;
    size_t base = ((size_t)blockIdx.x*8 + g) * NN;
    float2 y[5];
    #pragma unroll
    for (int n1=0;n1<5;n1++) y[n1] = make_float2(zin[base + n1*32 + l], 0.f);
    linefft<1>(y, l);
    size_t o5 = base + 5*br5(l);
    #pragma unroll
    for (int k=0;k<5;k++) out[o5+k] = y[k];
}

// fused: inverse z FFT -> multiply m^2*w_r -> forward z FFT, in place, batched over r
template<bool PRE>
__global__ __launch_bounds__(256) void fft_z_mid3(RP P, const float* __restrict__ mask,
                                                  const float* __restrict__ wfull)
{
    __shared__ float lds[8][NN];
    int r = blockIdx.y;
    float2* C = P.C[r];
    int tid = threadIdx.x, l = tid & 31, g = tid >> 5;
    size_t base = ((size_t)blockIdx.x*8 + g) * NN;
    float2 y[5];
    #pragma unroll
    for (int n1=0;n1<5;n1++) y[n1] = C[base + n1*32 + l];
    linefft<-1>(y, l);
    int o5 = 5*br5(l);
    #pragma unroll
    for (int k=0;k<5;k++){
        int idx = o5 + k;
        size_t gi = base + idx;
        float u = y[k].x * (1.f/160.f);
        float m = PRE ? P.M[r][gi] : (mask[gi]*mask[gi]*wfull[gi*3 + r]);
        lds[g][idx] = u * m;
    }
    __syncthreads();
    #pragma unroll
    for (int n1=0;n1<5;n1++) y[n1] = make_float2(lds[g][n1*32 + l], 0.f);
    linefft<1>(y, l);
    #pragma unroll
    for (int k=0;k<5;k++) C[base + o5 + k] = y[k];
}

// ---------------- CG reductions ----------------
__device__ __forceinline__ void block_atomic_add(double v, double* target){
    #pragma unroll
    for (int off=32; off>0; off>>=1) v += __shfl_down(v, off, 64);
    __shared__ double sm[4];
    int wv = threadIdx.x >> 6;
    if ((threadIdx.x & 63) == 0) sm[wv] = v;
    __syncthreads();
    if (threadIdx.x == 0) atomicAdd(target, sm[0]+sm[1]+sm[2]+sm[3]);
}

// final: inverse z FFT + out = LAM*z + re/160.
// FIN=0: Ap[i]=v, accumulate dot(z,v) into S[1]
// FIN=1: rv=bb[i]-v -> rr,pp; accumulate rv^2 into S[0]
template<int FIN>
__global__ __launch_bounds__(256) void fft_z_fin(const float2* __restrict__ in,
        const float* __restrict__ z, float* __restrict__ Ap,
        const float* __restrict__ bb, float* __restrict__ rrv, float* __restrict__ ppv,
        double* __restrict__ S)
{
    int tid = threadIdx.x, l = tid & 31, g = tid >> 5;
    size_t base = ((size_t)blockIdx.x*8 + g) * NN;
    float2 y[5];
    #pragma unroll
    for (int n1=0;n1<5;n1++) y[n1] = in[base + n1*32 + l];
    linefft<-1>(y, l);
    size_t o5 = base + 5*br5(l);
    double acc = 0.0;
    #pragma unroll
    for (int k=0;k<5;k++){
        size_t idx = o5 + k;
        float v = LAM_F * z[idx] + y[k].x * (1.f/160.f);
        if (FIN == 0){
            Ap[idx] = v;
            acc += (double)z[idx] * (double)v;
        } else {
            float rv = bb[idx] - v;
            rrv[idx] = rv; ppv[idx] = rv;
            acc += (double)rv * (double)rv;
        }
    }
    block_atomic_add(acc, FIN ? &S[0] : &S[1]);
}

// ---------------- strided (y / x axis) sweeps ----------------
template<int SGN>
__device__ __forceinline__ void strided_compute(float2 tile[NN][WZ+1], int tid){
    int l = tid & 31, gq = tid >> 5;
    const float SC = (SGN>0) ? 1.f : (1.f/160.f);
    #pragma unroll
    for (int rr=0; rr<2; rr++){
        int zi = gq*2 + rr;
        float2 y[5];
        #pragma unroll
        for (int n1=0;n1<5;n1++) y[n1] = tile[l + 32*n1][zi];
        linefft<SGN>(y, l);
        int o5 = 5*br5(l);
        #pragma unroll
        for (int k=0;k<5;k++) tile[o5+k][zi] = cscale(y[k], SC);
    }
}

template<int SGN>
__global__ __launch_bounds__(256) void fft_strided_plain(float2* __restrict__ data,
                                                         int stride, int ostride)
{
    __shared__ float2 tile[NN][WZ+1];
    int b = blockIdx.x;
    int outer = b / NBZ, zb = (b % NBZ) * WZ;
    size_t tbase = (size_t)outer*ostride + zb;
    int tid = threadIdx.x;
    #pragma unroll
    for (int i = tid; i < NN*WZ; i += 256){
        int row = i >> 4, zi = i & 15;
        tile[row][zi] = data[tbase + (size_t)row*stride + zi];
    }
    __syncthreads();
    strided_compute<SGN>(tile, tid);
    __syncthreads();
    #pragma unroll
    for (int i = tid; i < NN*WZ; i += 256){
        int row = i >> 4, zi = i & 15;
        data[tbase + (size_t)row*stride + zi] = tile[row][zi];
    }
}

// batched over r, in-place on P.C[r]
template<int SGN>
__global__ __launch_bounds__(256) void fft_strided_plain3(RP P, int stride, int ostride)
{
    __shared__ float2 tile[NN][WZ+1];
    float2* data = P.C[blockIdx.y];
    int b = blockIdx.x;
    int outer = b / NBZ, zb = (b % NBZ) * WZ;
    size_t tbase = (size_t)outer*ostride + zb;
    int tid = threadIdx.x;
    #pragma unroll
    for (int i = tid; i < NN*WZ; i += 256){
        int row = i >> 4, zi = i & 15;
        tile[row][zi] = data[tbase + (size_t)row*stride + zi];
    }
    __syncthreads();
    strided_compute<SGN>(tile, tid);
    __syncthreads();
    #pragma unroll
    for (int i = tid; i < NN*WZ; i += 256){
        int row = i >> 4, zi = i & 15;
        data[tbase + (size_t)row*stride + zi] = tile[row][zi];
    }
}

// batched over r: read shared spectrum, multiply K_r on load, inverse FFT, write C_r
template<int SGN>
__global__ __launch_bounds__(256) void fft_strided_kmul3(RP P, const float2* __restrict__ in,
                                                         int stride, int ostride)
{
    __shared__ float2 tile[NN][WZ+1];
    int r = blockIdx.y;
    const float* Kf = P.K[r];
    float2* out = P.C[r];
    int b = blockIdx.x;
    int outer = b / NBZ, zb = (b % NBZ) * WZ;
    size_t tbase = (size_t)outer*ostride + zb;
    int tid = threadIdx.x;
    #pragma unroll
    for (int i = tid; i < NN*WZ; i += 256){
        int row = i >> 4, zi = i & 15;
        size_t gidx = tbase + (size_t)row*stride + zi;
        tile[row][zi] = cscale(in[gidx], Kf[gidx]);
    }
    __syncthreads();
    strided_compute<SGN>(tile, tid);
    __syncthreads();
    #pragma unroll
    for (int i = tid; i < NN*WZ; i += 256){
        int row = i >> 4, zi = i & 15;
        out[tbase + (size_t)row*stride + zi] = tile[row][zi];
    }
}

// sum_r K_r * C_r on load, inverse FFT, write out
template<int SGN>
__global__ __launch_bounds__(256) void fft_strided_ksum(RP P, float2* __restrict__ out,
                                                        int stride, int ostride)
{
    __shared__ float2 tile[NN][WZ+1];
    int b = blockIdx.x;
    int outer = b / NBZ, zb = (b % NBZ) * WZ;
    size_t tbase = (size_t)outer*ostride + zb;
    int tid = threadIdx.x;
    #pragma unroll
    for (int i = tid; i < NN*WZ; i += 256){
        int row = i >> 4, zi = i & 15;
        size_t gidx = tbase + (size_t)row*stride + zi;
        float2 a = cscale(P.C[0][gidx], P.K[0][gidx]);
        float2 bv = cscale(P.C[1][gidx], P.K[1][gidx]);
        float2 c = cscale(P.C[2][gidx], P.K[2][gidx]);
        tile[row][zi] = cadd(cadd(a,bv),c);
    }
    __syncthreads();
    strided_compute<SGN>(tile, tid);
    __syncthreads();
    #pragma unroll
    for (int i = tid; i < NN*WZ; i += 256){
        int row = i >> 4, zi = i & 15;
        out[tbase + (size_t)row*stride + zi] = tile[row][zi];
    }
}

// ---------------- k-space kernels: K_r = (1 - SMV_r) * D ----------------
__global__ __launch_bounds__(256) void precompute_kernel(float* __restrict__ K0,
        float* __restrict__ K1, float* __restrict__ K2)
{
    int i = blockIdx.x*256 + threadIdx.x;
    int iz = i % NN;
    int iy = (i / NN) % NN;
    int ix = i / (NN*NN);
    float fx = (float)((ix < 80) ? ix : ix - 160) * (1.f/160.f);
    float fy = (float)((iy < 80) ? iy : iy - 160) * (1.f/160.f);
    float fz = (float)((iz < 80) ? iz : iz - 160) * (1.f/160.f);
    float k2 = fx*fx + fy*fy + fz*fz;
    float D = (1.f/3.f) - ((k2 == 0.f) ? 0.f : (fz*fz / k2));
    float cx[4], cy[4], cz[4];
    #pragma unroll
    for (int d=0; d<4; d++){
        cx[d] = cosf(TPI * fx * (float)d);
        cy[d] = cosf(TPI * fy * (float)d);
        cz[d] = cosf(TPI * fz * (float)d);
    }
    float s1=0.f, s2=0.f, s3=0.f;
    #pragma unroll
    for (int dx=0; dx<4; dx++)
    #pragma unroll
    for (int dy=0; dy<4; dy++)
    #pragma unroll
    for (int dz=0; dz<4; dz++){
        int q = dx*dx + dy*dy + dz*dz;
        if (q > 9) continue;
        float wgt = (dx?2.f:1.f)*(dy?2.f:1.f)*(dz?2.f:1.f);
        float t = wgt * cx[dx]*cy[dy]*cz[dz];
        if (q <= 1) s1 += t;
        if (q <= 4) s2 += t;
        s3 += t;
    }
    K0[i] = (1.f - s1*(1.f/7.f))   * D;
    K1[i] = (1.f - s2*(1.f/33.f))  * D;
    K2[i] = (1.f - s3*(1.f/123.f)) * D;
}

__global__ __launch_bounds__(256) void m2w_kernel(const float* __restrict__ mask,
        const float* __restrict__ w, float* __restrict__ M0,
        float* __restrict__ M1, float* __restrict__ M2)
{
    int i = blockIdx.x*256 + threadIdx.x;
    float m = mask[i]; float mm = m*m;
    M0[i] = mm * w[3*i+0];
    M1[i] = mm * w[3*i+1];
    M2[i] = mm * w[3*i+2];
}

// ---------------- CG vector ops ----------------
#define GSTRIDE (2048*256)

__global__ __launch_bounds__(256) void copy_kernel(const float* __restrict__ a, float* __restrict__ b){
    int i = blockIdx.x*256 + threadIdx.x;
    b[i] = a[i];
}
__global__ __launch_bounds__(256) void upd1_kernel(float* __restrict__ x, float* __restrict__ r,
        const float* __restrict__ p, const float* __restrict__ Ap, double* s)
{
    float alpha = (float)(s[0] / (s[1] + 1e-12));
    double acc = 0.0;
    for (int i = blockIdx.x*256 + threadIdx.x; i < N3; i += GSTRIDE){
        x[i] += alpha * p[i];
        float rn = r[i] - alpha * Ap[i];
        r[i] = rn;
        acc += (double)rn * (double)rn;
    }
    block_atomic_add(acc, &s[2]);
}
__global__ __launch_bounds__(256) void upd2_kernel(float* __restrict__ p,
        const float* __restrict__ r, double* s)
{
    float beta = (float)(s[2] / (s[0] + 1e-12));
    for (int i = blockIdx.x*256 + threadIdx.x; i < N3; i += GSTRIDE)
        p[i] = r[i] + beta * p[i];
}
__global__ void advance_kernel(double* s){
    if (threadIdx.x == 0){ s[0] = s[2]; s[1] = 0.0; s[2] = 0.0; }
}
__global__ void zero_kernel(double* s){
    if (threadIdx.x < 4) s[threadIdx.x] = 0.0;
}

// ---------------- host orchestration ----------------
extern "C" void kernel_launch(void* const* d_in, const int* in_sizes, int n_in,
                              void* d_out, int out_size, void* d_ws, size_t ws_size,
                              hipStream_t stream)
{
    (void)in_sizes; (void)n_in; (void)out_size;
    const float* w    = (const float*)d_in[0];   // [N3*3], R fastest
    const float* x2   = (const float*)d_in[1];   // [N3]
    const float* mask = (const float*)d_in[2];   // [N3]
    const float* bb   = (const float*)d_in[3];   // [N3]
    float* x = (float*)d_out;
    char* ws = (char*)d_ws;

    size_t off = 0;
    auto alloc = [&](size_t bytes)->void*{
        void* pp = ws + off;
        off += (bytes + 255) & ~(size_t)255;
        return pp;
    };
    float*  K0 = (float*) alloc((size_t)N3*4);
    float*  K1 = (float*) alloc((size_t)N3*4);
    float*  K2 = (float*) alloc((size_t)N3*4);
    float2* CF = (float2*)alloc((size_t)N3*8);   // shared spectrum; also final accumulator
    float2* C0 = (float2*)alloc((size_t)N3*8);
    float2* C1 = (float2*)alloc((size_t)N3*8);
    float2* C2 = (float2*)alloc((size_t)N3*8);
    float*  rr = (float*) alloc((size_t)N3*4);
    float*  pp = (float*) alloc((size_t)N3*4);
    double* S  = (double*)alloc(64);
    float*  Ap = (float*)C0;                     // alias: C0 dead when Ap produced/consumed
    bool PRE = (ws_size >= off + 3*(((size_t)N3*4 + 255) & ~(size_t)255));
    float *M0=nullptr, *M1=nullptr, *M2=nullptr;
    if (PRE){
        M0 = (float*)alloc((size_t)N3*4);
        M1 = (float*)alloc((size_t)N3*4);
        M2 = (float*)alloc((size_t)N3*4);
    }
    RP P;
    P.K[0]=K0; P.K[1]=K1; P.K[2]=K2;
    P.C[0]=C0; P.C[1]=C1; P.C[2]=C2;
    P.M[0]=M0; P.M[1]=M1; P.M[2]=M2;

    zero_kernel<<<1, 64, 0, stream>>>(S);
    precompute_kernel<<<16000, 256, 0, stream>>>(K0, K1, K2);
    if (PRE) m2w_kernel<<<16000, 256, 0, stream>>>(mask, w, M0, M1, M2);
    copy_kernel<<<16000, 256, 0, stream>>>(x2, x);

    // FIN: 1 = initial residual pass, 0 = CG iteration (Ap + dot)
    auto applyM = [&](const float* z, int FIN){
        fft_z_first<<<3200, 256, 0, stream>>>(z, CF);
        fft_strided_plain<1><<<1600, 256, 0, stream>>>(CF, NN,    NN*NN);   // y fwd
        fft_strided_plain<1><<<1600, 256, 0, stream>>>(CF, NN*NN, NN);      // x fwd
        fft_strided_kmul3<-1><<<dim3(1600,3), 256, 0, stream>>>(P, CF, NN*NN, NN); // x inv * K_r
        fft_strided_plain3<-1><<<dim3(1600,3), 256, 0, stream>>>(P, NN, NN*NN);    // y inv
        if (PRE)
            fft_z_mid3<true ><<<dim3(3200,3), 256, 0, stream>>>(P, mask, w);
        else
            fft_z_mid3<false><<<dim3(3200,3), 256, 0, stream>>>(P, mask, w);
        fft_strided_plain3<1><<<dim3(1600,3), 256, 0, stream>>>(P, NN, NN*NN);     // y fwd
        fft_strided_plain3<1><<<dim3(1600,3), 256, 0, stream>>>(P, NN*NN, NN);     // x fwd
        fft_strided_ksum<-1><<<1600, 256, 0, stream>>>(P, CF, NN*NN, NN);   // x inv, sum K_r*C_r
        fft_strided_plain<-1><<<1600, 256, 0, stream>>>(CF, NN, NN*NN);     // y inv
        if (FIN)
            fft_z_fin<1><<<3200, 256, 0, stream>>>(CF, z, Ap, bb, rr, pp, S);
        else
            fft_z_fin<0><<<3200, 256, 0, stream>>>(CF, z, Ap, bb, rr, pp, S);
    };

    // r = b - M(x2); p = r; rs = <r,r>
    applyM(x, 1);

    for (int it = 0; it < 10; it++){
        applyM(pp, 0);                           // Ap = M(p), S[1] = <p,Ap>
        upd1_kernel<<<2048, 256, 0, stream>>>(x, rr, pp, Ap, S);
        upd2_kernel<<<2048, 256, 0, stream>>>(pp, rr, S);
        advance_kernel<<<1, 64, 0, stream>>>(S);
    }
}

// Round 3
// 5139.172 us; speedup vs baseline: 1.7037x; 1.1101x over previous
//
#include <hip/hip_runtime.h>

#define NN 160
#define KP 81                // kept kz planes (Hermitian half)
#define N3 4096000           // 160^3
#define NLINES 25600         // 160^2 z-lines
#define WZ 16                // tile width (kz columns) for x/y sweeps
#define NBZ 6                // ceil(81/16)
#define XS 12960             // x-stride in complex layout (160*81)
#define TPI 6.28318530717958647692f
#define LAM_F 0.05f

// ---------------- complex helpers ----------------
__device__ __forceinline__ float2 cxmul(float2 a, float2 b){
    return make_float2(a.x*b.x - a.y*b.y, a.x*b.y + a.y*b.x);
}
__device__ __forceinline__ float2 cadd(float2 a, float2 b){ return make_float2(a.x+b.x, a.y+b.y); }
__device__ __forceinline__ float2 csub(float2 a, float2 b){ return make_float2(a.x-b.x, a.y-b.y); }
__device__ __forceinline__ float2 cscale(float2 a, float s){ return make_float2(a.x*s, a.y*s); }
__device__ __forceinline__ float2 shfl2(float2 v, int m){
    return make_float2(__shfl_xor(v.x, m, 64), __shfl_xor(v.y, m, 64));
}
__device__ __forceinline__ int br5(int l){
    return ((l&1)<<4)|((l&2)<<2)|(l&4)|((l&8)>>2)|((l&16)>>4);
}
template<int SGN>
__device__ __forceinline__ float2 twid(float ang){
    float s, c; sincosf(ang, &s, &c);
    return make_float2(c, (SGN>0) ? -s : s);
}

// ---------------- radix-5 DFT ----------------
template<int SGN>
__device__ __forceinline__ void dft5(float2 y[5]){
    const float C1 = 0.30901699437494742f;
    const float C2 = -0.80901699437494742f;
    const float S1 = 0.95105651629515357f;
    const float S2 = 0.58778525229247312f;
    float2 x0=y[0], x1=y[1], x2=y[2], x3=y[3], x4=y[4];
    float2 t1=cadd(x1,x4), t2=cadd(x2,x3), t3=csub(x1,x4), t4=csub(x2,x3);
    y[0] = cadd(x0, cadd(t1,t2));
    float2 a1 = make_float2(x0.x + C1*t1.x + C2*t2.x, x0.y + C1*t1.y + C2*t2.y);
    float2 a2 = make_float2(x0.x + C2*t1.x + C1*t2.x, x0.y + C2*t1.y + C1*t2.y);
    const float sg = (SGN>0) ? 1.f : -1.f;
    float2 b1 = make_float2(sg*(S1*t3.x + S2*t4.x), sg*(S1*t3.y + S2*t4.y));
    float2 b2 = make_float2(sg*(S2*t3.x - S1*t4.x), sg*(S2*t3.y - S1*t4.y));
    y[1] = make_float2(a1.x + b1.y, a1.y - b1.x);
    y[4] = make_float2(a1.x - b1.y, a1.y + b1.x);
    y[2] = make_float2(a2.x + b2.y, a2.y - b2.x);
    y[3] = make_float2(a2.x - b2.y, a2.y + b2.x);
}

__device__ __forceinline__ float2 bfly(float2 v, int m, float2 tw, int l){
    float2 o = shfl2(v, m);
    float2 s = cadd(v, o);
    float2 d = cxmul(csub(o, v), tw);
    return (l & m) ? d : s;
}

// 160-pt FFT: lane l in [0,32) holds y[n1]=x[n1*32+l] on entry.
// On exit, slot k holds X[k + 5*br5(l)].
template<int SGN>
__device__ __forceinline__ void linefft(float2 y[5], int l){
    dft5<SGN>(y);
    float2 w1 = twid<SGN>(TPI * (float)l * (1.f/160.f));
    float2 w2 = cxmul(w1,w1);
    float2 w3 = cxmul(w2,w1);
    float2 w4 = cxmul(w2,w2);
    y[1]=cxmul(y[1],w1); y[2]=cxmul(y[2],w2); y[3]=cxmul(y[3],w3); y[4]=cxmul(y[4],w4);
    float2 tw16 = twid<SGN>(TPI * (float)(l & 15) * (1.f/32.f));
    float2 tw8  = twid<SGN>(TPI * (float)(l & 7)  * (1.f/16.f));
    float2 tw4  = twid<SGN>(TPI * (float)(l & 3)  * (1.f/8.f));
    float2 tw2  = twid<SGN>(TPI * (float)(l & 1)  * (1.f/4.f));
    #pragma unroll
    for (int k=0;k<5;k++){
        float2 v = y[k];
        v = bfly(v,16,tw16,l);
        v = bfly(v, 8,tw8 ,l);
        v = bfly(v, 4,tw4 ,l);
        v = bfly(v, 2,tw2 ,l);
        float2 o = shfl2(v,1);
        v = (l&1) ? csub(o,v) : cadd(v,o);
        y[k] = v;
    }
}

struct RPc {
    float2* C[3];
    const float* M[3];
};

// analytic kernel ingredients: Q sums over (dy,dz) ball slices, per column
struct QCol {
    float Q1_0, Q1_1;
    float Q2_0, Q2_1, Q2_2;
    float Q3_0, Q3_1, Q3_2, Q3_3;
    float fz2;
};

__device__ __forceinline__ QCol make_qcol(float ay0,float ay1,float ay2,float ay3, int kz){
    float fz = (float)kz * (1.f/160.f);
    float cz1 = __cosf(TPI*fz);
    float cz2 = 2.f*cz1*cz1 - 1.f;
    float cz3 = 2.f*cz1*cz2 - cz1;
    float az0=1.f, az1=2.f*cz1, az2=2.f*cz2, az3=2.f*cz3;
    float P00=ay0*az0, P01=ay0*az1, P02=ay0*az2, P03=ay0*az3;
    float P10=ay1*az0, P11=ay1*az1, P12=ay1*az2;
    float P20=ay2*az0, P21=ay2*az1, P22=ay2*az2;
    float P30=ay3*az0;
    QCol q;
    q.Q1_0 = P00 + P01 + P10;
    q.Q1_1 = P00;
    q.Q2_0 = P00+P01+P02+P10+P11+P20;
    q.Q2_1 = P00+P01+P10+P11;
    q.Q2_2 = P00;
    q.Q3_0 = P00+P01+P02+P03+P10+P11+P12+P20+P21+P22+P30;
    q.Q3_1 = P00+P01+P02+P10+P11+P12+P20+P21+P22;
    q.Q3_2 = P00+P01+P02+P10+P11+P12+P20+P21;
    q.Q3_3 = P00;
    return q;
}

// K_r for slot: kx in [0,160), needs fy2 (block), q (column)
template<int R>
__device__ __forceinline__ float kval(const QCol& q, float fy2, int kx){
    float c1 = __cosf(TPI * (float)kx * (1.f/160.f));
    float s;
    if (R == 0){
        s = (q.Q1_0 + 2.f*c1*q.Q1_1) * (1.f/7.f);
    } else if (R == 1){
        float c2 = 2.f*c1*c1 - 1.f;
        s = (q.Q2_0 + 2.f*(c1*q.Q2_1 + c2*q.Q2_2)) * (1.f/33.f);
    } else {
        float c2 = 2.f*c1*c1 - 1.f;
        float c3 = 2.f*c1*c2 - c1;
        s = (q.Q3_0 + 2.f*(c1*q.Q3_1 + c2*q.Q3_2 + c3*q.Q3_3)) * (1.f/123.f);
    }
    float fxw = (float)((kx < 80) ? kx : 160 - kx) * (1.f/160.f);
    float k2 = fxw*fxw + fy2 + q.fz2;
    float D = (k2 == 0.f) ? (1.f/3.f) : (1.f/3.f - q.fz2 / k2);
    return (1.f - s) * D;
}

// ---------------- CG reduction helper ----------------
__device__ __forceinline__ void block_atomic_add(double v, double* target){
    #pragma unroll
    for (int off=32; off>0; off>>=1) v += __shfl_down(v, off, 64);
    __shared__ double sm[4];
    int wv = threadIdx.x >> 6;
    if ((threadIdx.x & 63) == 0) sm[wv] = v;
    __syncthreads();
    if (threadIdx.x == 0) atomicAdd(target, sm[0]+sm[1]+sm[2]+sm[3]);
}

// ---------------- z-axis kernels (two-for-one packed, r2c half-spectrum) ----------------
// PM=0: fft real zin. PM=1: p = r + beta*p (beta=S[3]), store p, fft p.
template<int PM>
__global__ __launch_bounds__(256) void fft_z_first(const float* __restrict__ zin,
    const float* __restrict__ rrv, float* __restrict__ ppv,
    float2* __restrict__ out, const double* __restrict__ S)
{
    __shared__ float  ldsR[16*160];
    __shared__ float2 ldsC[8*162];
    int tid = threadIdx.x, l = tid & 31, g = tid >> 5;   // g = pair 0..7
    size_t base160 = (size_t)blockIdx.x * 2560;
    float beta = PM ? (float)S[3] : 0.f;
    for (int f = tid; f < 2560; f += 256){
        float v;
        if (PM){
            v = rrv[base160 + f] + beta * ppv[base160 + f];
            ppv[base160 + f] = v;
        } else v = zin[base160 + f];
        ldsR[f] = v;
    }
    __syncthreads();
    float2 y[5];
    #pragma unroll
    for (int n1=0;n1<5;n1++){
        int n = n1*32 + l;
        y[n1] = make_float2(ldsR[2*g*160 + n], ldsR[(2*g+1)*160 + n]);
    }
    linefft<1>(y, l);
    int o5 = 5*br5(l);
    #pragma unroll
    for (int k=0;k<5;k++) ldsC[g*162 + o5 + k] = y[k];
    __syncthreads();
    size_t baseC = (size_t)blockIdx.x * 1296;
    for (int f = tid; f < 1296; f += 256){
        int line = f / 81, k = f - line*81;
        int pr = line >> 1;
        float2 Sk = ldsC[pr*162 + k];
        float2 Sm = ldsC[pr*162 + ((160 - k) % 160)];
        float2 o = (line & 1)
            ? make_float2(0.5f*(Sk.y + Sm.y), -0.5f*(Sk.x - Sm.x))    // B
            : make_float2(0.5f*(Sk.x + Sm.x),  0.5f*(Sk.y - Sm.y));   // A
        out[baseC + f] = o;
    }
}

// fused: inverse-z (Hermitian reconstruct, packed pair) -> *m2w_r -> forward-z -> half-spectrum
template<bool PRE>
__global__ __launch_bounds__(256) void fft_z_mid3(RPc P, const float* __restrict__ mask,
                                                 const float* __restrict__ wfull)
{
    __shared__ float2 ldsC[8*162];   // 16 lines * 81 = exactly 8 pair-regions of 162
    __shared__ float  ldsM[16*160];
    int r = blockIdx.y;
    float2* C = P.C[r];
    int tid = threadIdx.x, l = tid & 31, g = tid >> 5;
    size_t baseC = (size_t)blockIdx.x * 1296;
    size_t base160 = (size_t)blockIdx.x * 2560;
    for (int f = tid; f < 1296; f += 256) ldsC[f] = C[baseC + f];
    if (PRE){
        const float* M = P.M[r];
        for (int f = tid; f < 2560; f += 256) ldsM[f] = M[base160 + f];
    } else {
        for (int f = tid; f < 2560; f += 256){
            float m = mask[base160 + f];
            ldsM[f] = m*m*wfull[(base160 + f)*3 + r];
        }
    }
    __syncthreads();
    int fl = g*162;
    float2 y[5];
    #pragma unroll
    for (int n1=0;n1<5;n1++){
        int e = n1*32 + l;
        float2 X;
        if (e <= 80){
            float2 A = ldsC[fl + e], B = ldsC[fl + 81 + e];
            X = make_float2(A.x - B.y, A.y + B.x);
        } else {
            int m = 160 - e;
            float2 A = ldsC[fl + m], B = ldsC[fl + 81 + m];
            X = make_float2(A.x + B.y, B.x - A.y);
        }
        y[n1] = X;
    }
    linefft<-1>(y, l);
    int o5 = 5*br5(l);
    const float SC = 1.f/160.f;
    #pragma unroll
    for (int k=0;k<5;k++){
        int n = o5 + k;
        float a = y[k].x * SC * ldsM[2*g*160 + n];
        float b = y[k].y * SC * ldsM[(2*g+1)*160 + n];
        ldsC[fl + n] = make_float2(a, b);       // packed s' (in-wave FIFO: after own gathers)
    }
    #pragma unroll
    for (int n1=0;n1<5;n1++) y[n1] = ldsC[fl + n1*32 + l];
    linefft<1>(y, l);
    #pragma unroll
    for (int k=0;k<5;k++) ldsC[fl + o5 + k] = y[k];
    __syncthreads();
    for (int f = tid; f < 1296; f += 256){
        int line = f / 81, k = f - line*81;
        int pr = line >> 1;
        float2 Sk = ldsC[pr*162 + k];
        float2 Sm = ldsC[pr*162 + ((160 - k) % 160)];
        float2 o = (line & 1)
            ? make_float2(0.5f*(Sk.y + Sm.y), -0.5f*(Sk.x - Sm.x))
            : make_float2(0.5f*(Sk.x + Sm.x),  0.5f*(Sk.y - Sm.y));
        C[baseC + f] = o;
    }
}

// final inverse-z + epilogue. FIN=0: Ap=v, S[1]+=<z,v>. FIN=1: r=b-v -> rr,pp, S[0]+=<r,r>.
template<int FIN>
__global__ __launch_bounds__(256) void fft_z_fin(const float2* __restrict__ in,
    const float* __restrict__ zsp, float* __restrict__ Ap,
    const float* __restrict__ bb, float* __restrict__ rrv, float* __restrict__ ppv,
    double* __restrict__ S)
{
    __shared__ float2 ldsC[8*162];
    __shared__ float  ldsA[16*160];
    __shared__ float  ldsB[FIN ? 16*160 : 1];
    int tid = threadIdx.x, l = tid & 31, g = tid >> 5;
    size_t baseC = (size_t)blockIdx.x * 1296;
    size_t base160 = (size_t)blockIdx.x * 2560;
    for (int f = tid; f < 1296; f += 256) ldsC[f] = in[baseC + f];
    for (int f = tid; f < 2560; f += 256) ldsA[f] = zsp[base160 + f];
    if (FIN){
        for (int f = tid; f < 2560; f += 256) ldsB[f] = bb[base160 + f];
    }
    __syncthreads();
    int fl = g*162;
    float2 y[5];
    #pragma unroll
    for (int n1=0;n1<5;n1++){
        int e = n1*32 + l;
        float2 X;
        if (e <= 80){
            float2 A = ldsC[fl + e], B = ldsC[fl + 81 + e];
            X = make_float2(A.x - B.y, A.y + B.x);
        } else {
            int m = 160 - e;
            float2 A = ldsC[fl + m], B = ldsC[fl + 81 + m];
            X = make_float2(A.x + B.y, B.x - A.y);
        }
        y[n1] = X;
    }
    linefft<-1>(y, l);
    int o5 = 5*br5(l);
    const float SC = 1.f/160.f;
    double acc = 0.0;
    #pragma unroll
    for (int k=0;k<5;k++){
        int n = o5 + k;
        int ia = 2*g*160 + n, ib = ia + 160;
        float za = ldsA[ia], zb = ldsA[ib];
        float va = LAM_F*za + y[k].x*SC;
        float vb = LAM_F*zb + y[k].y*SC;
        if (FIN == 0){
            acc += (double)za*(double)va + (double)zb*(double)vb;
            ldsA[ia] = va; ldsA[ib] = vb;
        } else {
            float ra = ldsB[ia] - va, rb = ldsB[ib] - vb;
            acc += (double)ra*(double)ra + (double)rb*(double)rb;
            ldsA[ia] = ra; ldsA[ib] = rb;
        }
    }
    __syncthreads();
    if (FIN == 0){
        for (int f = tid; f < 2560; f += 256) Ap[base160 + f] = ldsA[f];
    } else {
        for (int f = tid; f < 2560; f += 256){
            float v = ldsA[f];
            rrv[base160 + f] = v; ppv[base160 + f] = v;
        }
    }
    block_atomic_add(acc, FIN ? &S[0] : &S[1]);
}

// ---------------- y-axis sweeps (strided, guarded half-spectrum) ----------------
template<int SGN>
__device__ __forceinline__ void ycompute(float2 (*tile)[WZ+1], int tid){
    int l = tid & 31, gq = tid >> 5;
    const float SC = (SGN>0) ? 1.f : (1.f/160.f);
    #pragma unroll
    for (int rr=0; rr<2; rr++){
        int zi = gq*2 + rr;
        float2 y[5];
        #pragma unroll
        for (int n1=0;n1<5;n1++) y[n1] = tile[l + 32*n1][zi];
        linefft<SGN>(y, l);
        int o5 = 5*br5(l);
        #pragma unroll
        for (int k=0;k<5;k++) tile[o5+k][zi] = cscale(y[k], SC);
    }
}

template<int SGN>
__global__ __launch_bounds__(256) void fft_y1(float2* __restrict__ data)
{
    __shared__ float2 tile[NN][WZ+1];
    int b = blockIdx.x;
    int ix = b / NBZ, zb = (b % NBZ) * WZ;
    size_t tbase = (size_t)ix*XS + zb;
    int tid = threadIdx.x;
    for (int i = tid; i < NN*WZ; i += 256){
        int row = i >> 4, zi = i & 15;
        tile[row][zi] = (zb + zi < KP) ? data[tbase + (size_t)row*KP + zi] : make_float2(0.f,0.f);
    }
    __syncthreads();
    ycompute<SGN>(tile, tid);
    __syncthreads();
    for (int i = tid; i < NN*WZ; i += 256){
        int row = i >> 4, zi = i & 15;
        if (zb + zi < KP) data[tbase + (size_t)row*KP + zi] = tile[row][zi];
    }
}

template<int SGN>
__global__ __launch_bounds__(256) void fft_y3(RPc P)
{
    __shared__ float2 tile[NN][WZ+1];
    float2* data = P.C[blockIdx.y];
    int b = blockIdx.x;
    int ix = b / NBZ, zb = (b % NBZ) * WZ;
    size_t tbase = (size_t)ix*XS + zb;
    int tid = threadIdx.x;
    for (int i = tid; i < NN*WZ; i += 256){
        int row = i >> 4, zi = i & 15;
        tile[row][zi] = (zb + zi < KP) ? data[tbase + (size_t)row*KP + zi] : make_float2(0.f,0.f);
    }
    __syncthreads();
    ycompute<SGN>(tile, tid);
    __syncthreads();
    for (int i = tid; i < NN*WZ; i += 256){
        int row = i >> 4, zi = i & 15;
        if (zb + zi < KP) data[tbase + (size_t)row*KP + zi] = tile[row][zi];
    }
}

// ---------------- fused x-axis kernels with analytic K ----------------
// spread: CF -(fwd x, *K_r, inv x)-> C_r for r=0..2
__global__ __launch_bounds__(256) void fft_xK3(RPc P, const float2* __restrict__ in)
{
    __shared__ float2 tile[NN][WZ+1];
    int b = blockIdx.x;
    int iy = b / NBZ, zb = (b % NBZ) * WZ;
    size_t tbase = (size_t)iy*KP + zb;
    int tid = threadIdx.x, l = tid & 31, q = tid >> 5;
    for (int i = tid; i < NN*WZ; i += 256){
        int row = i >> 4, zi = i & 15;
        tile[row][zi] = (zb + zi < KP) ? in[tbase + (size_t)row*XS + zi] : make_float2(0.f,0.f);
    }
    __syncthreads();
    float fy = (float)((iy < 80) ? iy : iy - 160) * (1.f/160.f);
    float fy2 = fy*fy;
    float cy1 = __cosf(TPI*fy);
    float cy2 = 2.f*cy1*cy1 - 1.f;
    float cy3 = 2.f*cy1*cy2 - cy1;
    float ay0=1.f, ay1=2.f*cy1, ay2=2.f*cy2, ay3=2.f*cy3;

    float2 spec[2][5];
    float K0v[2][5], K1v[2][5], K2v[2][5];
    int o5 = 5*br5(l);
    #pragma unroll
    for (int cc=0; cc<2; cc++){
        int zi = q*2 + cc;
        int kz = zb + zi;
        QCol qc = make_qcol(ay0,ay1,ay2,ay3, kz);
        qc.fz2 = ((float)kz*(1.f/160.f))*((float)kz*(1.f/160.f));
        float2 y[5];
        #pragma unroll
        for (int n1=0;n1<5;n1++) y[n1] = tile[n1*32+l][zi];
        linefft<1>(y, l);
        #pragma unroll
        for (int k=0;k<5;k++){
            spec[cc][k] = y[k];
            int kx = o5 + k;
            K0v[cc][k] = kval<0>(qc, fy2, kx);
            K1v[cc][k] = kval<1>(qc, fy2, kx);
            K2v[cc][k] = kval<2>(qc, fy2, kx);
        }
    }
    #pragma unroll
    for (int r=0; r<3; r++){
        #pragma unroll
        for (int cc=0; cc<2; cc++){
            int zi = q*2 + cc;
            #pragma unroll
            for (int k=0;k<5;k++){
                float Kv = (r==0) ? K0v[cc][k] : (r==1) ? K1v[cc][k] : K2v[cc][k];
                tile[o5+k][zi] = cscale(spec[cc][k], Kv);
            }
            float2 y[5];
            #pragma unroll
            for (int n1=0;n1<5;n1++) y[n1] = tile[n1*32+l][zi];
            linefft<-1>(y, l);
            #pragma unroll
            for (int k=0;k<5;k++) tile[o5+k][zi] = cscale(y[k], 1.f/160.f);
        }
        __syncthreads();
        float2* Cr = P.C[r];
        for (int i = tid; i < NN*WZ; i += 256){
            int row = i >> 4, zi = i & 15;
            if (zb + zi < KP) Cr[tbase + (size_t)row*XS + zi] = tile[row][zi];
        }
        __syncthreads();
    }
}

// sum: CF = inv_x( sum_r K_r * fwd_x(C_r) )
__global__ __launch_bounds__(256) void fft_xKsum(RPc P, float2* __restrict__ out)
{
    __shared__ float2 tile[NN][WZ+1];
    int b = blockIdx.x;
    int iy = b / NBZ, zb = (b % NBZ) * WZ;
    size_t tbase = (size_t)iy*KP + zb;
    int tid = threadIdx.x, l = tid & 31, q = tid >> 5;
    float fy = (float)((iy < 80) ? iy : iy - 160) * (1.f/160.f);
    float fy2 = fy*fy;
    float cy1 = __cosf(TPI*fy);
    float cy2 = 2.f*cy1*cy1 - 1.f;
    float cy3 = 2.f*cy1*cy2 - cy1;
    float ay0=1.f, ay1=2.f*cy1, ay2=2.f*cy2, ay3=2.f*cy3;
    QCol qc[2];
    int o5 = 5*br5(l);
    #pragma unroll
    for (int cc=0; cc<2; cc++){
        int kz = zb + q*2 + cc;
        qc[cc] = make_qcol(ay0,ay1,ay2,ay3, kz);
        qc[cc].fz2 = ((float)kz*(1.f/160.f))*((float)kz*(1.f/160.f));
    }
    float2 acc[2][5];
    #pragma unroll
    for (int cc=0; cc<2; cc++)
    #pragma unroll
    for (int k=0;k<5;k++) acc[cc][k] = make_float2(0.f,0.f);

    #pragma unroll
    for (int r=0; r<3; r++){
        const float2* Cr = P.C[r];
        for (int i = tid; i < NN*WZ; i += 256){
            int row = i >> 4, zi = i & 15;
            tile[row][zi] = (zb + zi < KP) ? Cr[tbase + (size_t)row*XS + zi] : make_float2(0.f,0.f);
        }
        __syncthreads();
        #pragma unroll
        for (int cc=0; cc<2; cc++){
            int zi = q*2 + cc;
            float2 y[5];
            #pragma unroll
            for (int n1=0;n1<5;n1++) y[n1] = tile[n1*32+l][zi];
            linefft<1>(y, l);
            #pragma unroll
            for (int k=0;k<5;k++){
                int kx = o5 + k;
                float Kv = (r==0) ? kval<0>(qc[cc], fy2, kx)
                         : (r==1) ? kval<1>(qc[cc], fy2, kx)
                                  : kval<2>(qc[cc], fy2, kx);
                acc[cc][k] = cadd(acc[cc][k], cscale(y[k], Kv));
            }
        }
        __syncthreads();
    }
    #pragma unroll
    for (int cc=0; cc<2; cc++){
        int zi = q*2 + cc;
        #pragma unroll
        for (int k=0;k<5;k++) tile[o5+k][zi] = acc[cc][k];
        float2 y[5];
        #pragma unroll
        for (int n1=0;n1<5;n1++) y[n1] = tile[n1*32+l][zi];
        linefft<-1>(y, l);
        #pragma unroll
        for (int k=0;k<5;k++) tile[o5+k][zi] = cscale(y[k], 1.f/160.f);
    }
    __syncthreads();
    for (int i = tid; i < NN*WZ; i += 256){
        int row = i >> 4, zi = i & 15;
        if (zb + zi < KP) out[tbase + (size_t)row*XS + zi] = tile[row][zi];
    }
}

// ---------------- setup / CG vector ops ----------------
__global__ __launch_bounds__(256) void m2w_kernel(const float* __restrict__ mask,
        const float* __restrict__ w, float* __restrict__ M0,
        float* __restrict__ M1, float* __restrict__ M2)
{
    int i = blockIdx.x*256 + threadIdx.x;
    float m = mask[i]; float mm = m*m;
    M0[i] = mm * w[3*(size_t)i+0];
    M1[i] = mm * w[3*(size_t)i+1];
    M2[i] = mm * w[3*(size_t)i+2];
}

__global__ __launch_bounds__(256) void copy_kernel(const float* __restrict__ a, float* __restrict__ b){
    int i = blockIdx.x*256 + threadIdx.x;
    b[i] = a[i];
}

#define GSTRIDE (2048*256)
__global__ __launch_bounds__(256) void upd1_kernel(float* __restrict__ x, float* __restrict__ r,
        const float* __restrict__ p, const float* __restrict__ Ap, double* s)
{
    float alpha = (float)(s[0] / (s[1] + 1e-12));
    double acc = 0.0;
    for (int i = blockIdx.x*256 + threadIdx.x; i < N3; i += GSTRIDE){
        x[i] += alpha * p[i];
        float rn = r[i] - alpha * Ap[i];
        r[i] = rn;
        acc += (double)rn * (double)rn;
    }
    block_atomic_add(acc, &s[2]);
}
__global__ void advance_kernel(double* s){
    if (threadIdx.x == 0){
        s[3] = s[2] / (s[0] + 1e-12);   // beta
        s[0] = s[2]; s[1] = 0.0; s[2] = 0.0;
    }
}
__global__ void zero_kernel(double* s){
    if (threadIdx.x < 4) s[threadIdx.x] = 0.0;
}

// ---------------- host orchestration ----------------
extern "C" void kernel_launch(void* const* d_in, const int* in_sizes, int n_in,
                              void* d_out, int out_size, void* d_ws, size_t ws_size,
                              hipStream_t stream)
{
    (void)in_sizes; (void)n_in; (void)out_size;
    const float* w    = (const float*)d_in[0];   // [N3*3], R fastest
    const float* x2   = (const float*)d_in[1];   // [N3]
    const float* mask = (const float*)d_in[2];   // [N3]
    const float* bb   = (const float*)d_in[3];   // [N3]
    float* x = (float*)d_out;
    char* ws = (char*)d_ws;

    size_t off = 0;
    auto alloc = [&](size_t bytes)->void*{
        void* pp = ws + off;
        off += (bytes + 255) & ~(size_t)255;
        return pp;
    };
    const size_t CB = (size_t)NLINES * KP * sizeof(float2);   // 16.6 MB
    float2* CF = (float2*)alloc(CB);
    float2* C0 = (float2*)alloc(CB);
    float2* C1 = (float2*)alloc(CB);
    float2* C2 = (float2*)alloc(CB);
    float*  rr = (float*) alloc((size_t)N3*4);
    float*  pp = (float*) alloc((size_t)N3*4);
    double* S  = (double*)alloc(64);
    float*  Ap = (float*)C0;      // alias: C0 dead when Ap produced/consumed
    bool PRE = (ws_size >= off + 3*(((size_t)N3*4 + 255) & ~(size_t)255));
    float *M0=nullptr, *M1=nullptr, *M2=nullptr;
    if (PRE){
        M0 = (float*)alloc((size_t)N3*4);
        M1 = (float*)alloc((size_t)N3*4);
        M2 = (float*)alloc((size_t)N3*4);
    }
    RPc P;
    P.C[0]=C0; P.C[1]=C1; P.C[2]=C2;
    P.M[0]=M0; P.M[1]=M1; P.M[2]=M2;

    zero_kernel<<<1, 64, 0, stream>>>(S);
    if (PRE) m2w_kernel<<<16000, 256, 0, stream>>>(mask, w, M0, M1, M2);
    copy_kernel<<<16000, 256, 0, stream>>>(x2, x);

    // PM: 0 = plain fft of z; 1 = fused p-update. FIN: 1 = initial residual, 0 = CG iter.
    auto applyM = [&](const float* z, int FIN, int PM){
        if (PM) fft_z_first<1><<<1600, 256, 0, stream>>>(z, rr, pp, CF, S);
        else    fft_z_first<0><<<1600, 256, 0, stream>>>(z, rr, pp, CF, S);
        fft_y1<1><<<960, 256, 0, stream>>>(CF);
        fft_xK3<<<960, 256, 0, stream>>>(P, CF);
        fft_y3<-1><<<dim3(960,3), 256, 0, stream>>>(P);
        if (PRE) fft_z_mid3<true ><<<dim3(1600,3), 256, 0, stream>>>(P, mask, w);
        else     fft_z_mid3<false><<<dim3(1600,3), 256, 0, stream>>>(P, mask, w);
        fft_y3<1><<<dim3(960,3), 256, 0, stream>>>(P);
        fft_xKsum<<<960, 256, 0, stream>>>(P, CF);
        fft_y1<-1><<<960, 256, 0, stream>>>(CF);
        if (FIN) fft_z_fin<1><<<1600, 256, 0, stream>>>(CF, z, Ap, bb, rr, pp, S);
        else     fft_z_fin<0><<<1600, 256, 0, stream>>>(CF, z, Ap, bb, rr, pp, S);
    };

    // r = b - M(x2); p = r; rs = <r,r>
    applyM(x, 1, 0);

    for (int it = 0; it < 10; it++){
        applyM(pp, 0, (it == 0) ? 0 : 1);          // Ap = M(p), S[1] = <p,Ap>
        upd1_kernel<<<2048, 256, 0, stream>>>(x, rr, pp, Ap, S);
        if (it < 9) advance_kernel<<<1, 64, 0, stream>>>(S);
    }
}

// Round 4
// 3504.677 us; speedup vs baseline: 2.4983x; 1.4664x over previous
//
#include <hip/hip_runtime.h>

#define NN 160
#define KP 81                // kept kz planes (Hermitian half)
#define N3 4096000           // 160^3
#define NLINES 25600         // 160^2 z-lines
#define WZ 8                 // tile width (kz columns) for x/y sweeps
#define NBZ 11               // ceil(81/8)
#define XS 12960             // x-stride in complex layout (160*81)
#define TPI 6.28318530717958647692f
#define LAM_F 0.05f

// ---------------- complex helpers ----------------
__device__ __forceinline__ float2 cxmul(float2 a, float2 b){
    return make_float2(a.x*b.x - a.y*b.y, a.x*b.y + a.y*b.x);
}
__device__ __forceinline__ float2 cadd(float2 a, float2 b){ return make_float2(a.x+b.x, a.y+b.y); }
__device__ __forceinline__ float2 csub(float2 a, float2 b){ return make_float2(a.x-b.x, a.y-b.y); }
__device__ __forceinline__ float2 cscale(float2 a, float s){ return make_float2(a.x*s, a.y*s); }
__device__ __forceinline__ float2 shfl2(float2 v, int m){
    return make_float2(__shfl_xor(v.x, m, 64), __shfl_xor(v.y, m, 64));
}
__device__ __forceinline__ int br5(int l){
    return ((l&1)<<4)|((l&2)<<2)|(l&4)|((l&8)>>2)|((l&16)>>4);
}
template<int SGN>
__device__ __forceinline__ float2 twid(float ang){
    float s, c; sincosf(ang, &s, &c);
    return make_float2(c, (SGN>0) ? -s : s);
}

// ---------------- radix-5 DFT ----------------
template<int SGN>
__device__ __forceinline__ void dft5(float2 y[5]){
    const float C1 = 0.30901699437494742f;
    const float C2 = -0.80901699437494742f;
    const float S1 = 0.95105651629515357f;
    const float S2 = 0.58778525229247312f;
    float2 x0=y[0], x1=y[1], x2=y[2], x3=y[3], x4=y[4];
    float2 t1=cadd(x1,x4), t2=cadd(x2,x3), t3=csub(x1,x4), t4=csub(x2,x3);
    y[0] = cadd(x0, cadd(t1,t2));
    float2 a1 = make_float2(x0.x + C1*t1.x + C2*t2.x, x0.y + C1*t1.y + C2*t2.y);
    float2 a2 = make_float2(x0.x + C2*t1.x + C1*t2.x, x0.y + C2*t1.y + C1*t2.y);
    const float sg = (SGN>0) ? 1.f : -1.f;
    float2 b1 = make_float2(sg*(S1*t3.x + S2*t4.x), sg*(S1*t3.y + S2*t4.y));
    float2 b2 = make_float2(sg*(S2*t3.x - S1*t4.x), sg*(S2*t3.y - S1*t4.y));
    y[1] = make_float2(a1.x + b1.y, a1.y - b1.x);
    y[4] = make_float2(a1.x - b1.y, a1.y + b1.x);
    y[2] = make_float2(a2.x + b2.y, a2.y - b2.x);
    y[3] = make_float2(a2.x - b2.y, a2.y + b2.x);
}

__device__ __forceinline__ float2 bfly(float2 v, int m, float2 tw, int l){
    float2 o = shfl2(v, m);
    float2 s = cadd(v, o);
    float2 d = cxmul(csub(o, v), tw);
    return (l & m) ? d : s;
}

// 160-pt FFT: lane l in [0,32) holds y[n1]=x[n1*32+l] on entry.
// On exit, slot k holds X[k + 5*br5(l)].
template<int SGN>
__device__ __forceinline__ void linefft(float2 y[5], int l){
    dft5<SGN>(y);
    float2 w1 = twid<SGN>(TPI * (float)l * (1.f/160.f));
    float2 w2 = cxmul(w1,w1);
    float2 w3 = cxmul(w2,w1);
    float2 w4 = cxmul(w2,w2);
    y[1]=cxmul(y[1],w1); y[2]=cxmul(y[2],w2); y[3]=cxmul(y[3],w3); y[4]=cxmul(y[4],w4);
    float2 tw16 = twid<SGN>(TPI * (float)(l & 15) * (1.f/32.f));
    float2 tw8  = twid<SGN>(TPI * (float)(l & 7)  * (1.f/16.f));
    float2 tw4  = twid<SGN>(TPI * (float)(l & 3)  * (1.f/8.f));
    float2 tw2  = twid<SGN>(TPI * (float)(l & 1)  * (1.f/4.f));
    #pragma unroll
    for (int k=0;k<5;k++){
        float2 v = y[k];
        v = bfly(v,16,tw16,l);
        v = bfly(v, 8,tw8 ,l);
        v = bfly(v, 4,tw4 ,l);
        v = bfly(v, 2,tw2 ,l);
        float2 o = shfl2(v,1);
        v = (l&1) ? csub(o,v) : cadd(v,o);
        y[k] = v;
    }
}

struct RPc {
    float2* C[3];
    const float* M[3];
};

// analytic kernel ingredients: Q sums over (dy,dz) ball slices, per column
struct QCol {
    float Q1_0, Q1_1;
    float Q2_0, Q2_1, Q2_2;
    float Q3_0, Q3_1, Q3_2, Q3_3;
    float fz2;
};

__device__ __forceinline__ QCol make_qcol(float ay0,float ay1,float ay2,float ay3, int kz){
    float fz = (float)kz * (1.f/160.f);
    float cz1 = __cosf(TPI*fz);
    float cz2 = 2.f*cz1*cz1 - 1.f;
    float cz3 = 2.f*cz1*cz2 - cz1;
    float az0=1.f, az1=2.f*cz1, az2=2.f*cz2, az3=2.f*cz3;
    float P00=ay0*az0, P01=ay0*az1, P02=ay0*az2, P03=ay0*az3;
    float P10=ay1*az0, P11=ay1*az1, P12=ay1*az2;
    float P20=ay2*az0, P21=ay2*az1, P22=ay2*az2;
    float P30=ay3*az0;
    QCol q;
    q.Q1_0 = P00 + P01 + P10;
    q.Q1_1 = P00;
    q.Q2_0 = P00+P01+P02+P10+P11+P20;
    q.Q2_1 = P00+P01+P10+P11;
    q.Q2_2 = P00;
    q.Q3_0 = P00+P01+P02+P03+P10+P11+P12+P20+P21+P22+P30;
    q.Q3_1 = P00+P01+P02+P10+P11+P12+P20+P21+P22;
    q.Q3_2 = P00+P01+P02+P10+P11+P12+P20+P21;
    q.Q3_3 = P00;
    q.fz2 = fz*fz;
    return q;
}

// K_r for slot: kx in [0,160)
template<int R>
__device__ __forceinline__ float kval(const QCol& q, float fy2, int kx){
    float c1 = __cosf(TPI * (float)kx * (1.f/160.f));
    float s;
    if (R == 0){
        s = (q.Q1_0 + 2.f*c1*q.Q1_1) * (1.f/7.f);
    } else if (R == 1){
        float c2 = 2.f*c1*c1 - 1.f;
        s = (q.Q2_0 + 2.f*(c1*q.Q2_1 + c2*q.Q2_2)) * (1.f/33.f);
    } else {
        float c2 = 2.f*c1*c1 - 1.f;
        float c3 = 2.f*c1*c2 - c1;
        s = (q.Q3_0 + 2.f*(c1*q.Q3_1 + c2*q.Q3_2 + c3*q.Q3_3)) * (1.f/123.f);
    }
    float fxw = (float)((kx < 80) ? kx : 160 - kx) * (1.f/160.f);
    float k2 = fxw*fxw + fy2 + q.fz2;
    float D = (k2 == 0.f) ? (1.f/3.f) : (1.f/3.f - q.fz2 / k2);
    return (1.f - s) * D;
}

__device__ __forceinline__ float kval_r(int r, const QCol& q, float fy2, int kx){
    if (r == 0) return kval<0>(q, fy2, kx);
    if (r == 1) return kval<1>(q, fy2, kx);
    return kval<2>(q, fy2, kx);
}

// ---------------- CG reduction helper ----------------
__device__ __forceinline__ void block_atomic_add(double v, double* target){
    #pragma unroll
    for (int off=32; off>0; off>>=1) v += __shfl_down(v, off, 64);
    __shared__ double sm[4];
    int wv = threadIdx.x >> 6;
    if ((threadIdx.x & 63) == 0) sm[wv] = v;
    __syncthreads();
    if (threadIdx.x == 0) atomicAdd(target, sm[0]+sm[1]+sm[2]+sm[3]);
}

// ---------------- z-axis kernels (two-for-one packed, r2c half-spectrum) ----------------
// PM=0: fft real zin. PM=1: p = r + beta*p (beta=S[3]), store p, fft p.
template<int PM>
__global__ __launch_bounds__(256) void fft_z_first(const float* __restrict__ zin,
    const float* __restrict__ rrv, float* __restrict__ ppv,
    float2* __restrict__ out, const double* __restrict__ S)
{
    __shared__ float  ldsR[16*160];
    __shared__ float2 ldsC[8*162];
    int tid = threadIdx.x, l = tid & 31, g = tid >> 5;   // g = pair 0..7
    size_t base160 = (size_t)blockIdx.x * 2560;
    float beta = PM ? (float)S[3] : 0.f;
    for (int f = tid; f < 2560; f += 256){
        float v;
        if (PM){
            v = rrv[base160 + f] + beta * ppv[base160 + f];
            ppv[base160 + f] = v;
        } else v = zin[base160 + f];
        ldsR[f] = v;
    }
    __syncthreads();
    float2 y[5];
    #pragma unroll
    for (int n1=0;n1<5;n1++){
        int n = n1*32 + l;
        y[n1] = make_float2(ldsR[2*g*160 + n], ldsR[(2*g+1)*160 + n]);
    }
    linefft<1>(y, l);
    int o5 = 5*br5(l);
    #pragma unroll
    for (int k=0;k<5;k++) ldsC[g*162 + o5 + k] = y[k];
    __syncthreads();
    size_t baseC = (size_t)blockIdx.x * 1296;
    for (int f = tid; f < 1296; f += 256){
        int line = f / 81, k = f - line*81;
        int pr = line >> 1;
        float2 Sk = ldsC[pr*162 + k];
        float2 Sm = ldsC[pr*162 + ((160 - k) % 160)];
        float2 o = (line & 1)
            ? make_float2(0.5f*(Sk.y + Sm.y), -0.5f*(Sk.x - Sm.x))    // B
            : make_float2(0.5f*(Sk.x + Sm.x),  0.5f*(Sk.y - Sm.y));   // A
        out[baseC + f] = o;
    }
}

// fused: inverse-z (Hermitian reconstruct, packed pair) -> *m2w_r -> forward-z -> half-spectrum
template<bool PRE>
__global__ __launch_bounds__(256) void fft_z_mid3(RPc P, const float* __restrict__ mask,
                                                 const float* __restrict__ wfull)
{
    __shared__ float2 ldsC[8*162];
    __shared__ float  ldsM[16*160];
    int r = blockIdx.y;
    float2* C = P.C[r];
    int tid = threadIdx.x, l = tid & 31, g = tid >> 5;
    size_t baseC = (size_t)blockIdx.x * 1296;
    size_t base160 = (size_t)blockIdx.x * 2560;
    for (int f = tid; f < 1296; f += 256) ldsC[f] = C[baseC + f];
    if (PRE){
        const float* M = P.M[r];
        for (int f = tid; f < 2560; f += 256) ldsM[f] = M[base160 + f];
    } else {
        for (int f = tid; f < 2560; f += 256){
            float m = mask[base160 + f];
            ldsM[f] = m*m*wfull[(base160 + f)*3 + r];
        }
    }
    __syncthreads();
    int fl = g*162;
    float2 y[5];
    #pragma unroll
    for (int n1=0;n1<5;n1++){
        int e = n1*32 + l;
        float2 X;
        if (e <= 80){
            float2 A = ldsC[fl + e], B = ldsC[fl + 81 + e];
            X = make_float2(A.x - B.y, A.y + B.x);
        } else {
            int m = 160 - e;
            float2 A = ldsC[fl + m], B = ldsC[fl + 81 + m];
            X = make_float2(A.x + B.y, B.x - A.y);
        }
        y[n1] = X;
    }
    linefft<-1>(y, l);
    int o5 = 5*br5(l);
    const float SC = 1.f/160.f;
    #pragma unroll
    for (int k=0;k<5;k++){
        int n = o5 + k;
        float a = y[k].x * SC * ldsM[2*g*160 + n];
        float b = y[k].y * SC * ldsM[(2*g+1)*160 + n];
        ldsC[fl + n] = make_float2(a, b);
    }
    #pragma unroll
    for (int n1=0;n1<5;n1++) y[n1] = ldsC[fl + n1*32 + l];
    linefft<1>(y, l);
    #pragma unroll
    for (int k=0;k<5;k++) ldsC[fl + o5 + k] = y[k];
    __syncthreads();
    for (int f = tid; f < 1296; f += 256){
        int line = f / 81, k = f - line*81;
        int pr = line >> 1;
        float2 Sk = ldsC[pr*162 + k];
        float2 Sm = ldsC[pr*162 + ((160 - k) % 160)];
        float2 o = (line & 1)
            ? make_float2(0.5f*(Sk.y + Sm.y), -0.5f*(Sk.x - Sm.x))
            : make_float2(0.5f*(Sk.x + Sm.x),  0.5f*(Sk.y - Sm.y));
        C[baseC + f] = o;
    }
}

// final inverse-z + epilogue. FIN=0: Ap=v, S[1]+=<z,v>. FIN=1: r=b-v -> rr,pp, S[0]+=<r,r>.
template<int FIN>
__global__ __launch_bounds__(256) void fft_z_fin(const float2* __restrict__ in,
    const float* __restrict__ zsp, float* __restrict__ Ap,
    const float* __restrict__ bb, float* __restrict__ rrv, float* __restrict__ ppv,
    double* __restrict__ S)
{
    __shared__ float2 ldsC[8*162];
    __shared__ float  ldsA[16*160];
    __shared__ float  ldsB[FIN ? 16*160 : 1];
    int tid = threadIdx.x, l = tid & 31, g = tid >> 5;
    size_t baseC = (size_t)blockIdx.x * 1296;
    size_t base160 = (size_t)blockIdx.x * 2560;
    for (int f = tid; f < 1296; f += 256) ldsC[f] = in[baseC + f];
    for (int f = tid; f < 2560; f += 256) ldsA[f] = zsp[base160 + f];
    if (FIN){
        for (int f = tid; f < 2560; f += 256) ldsB[f] = bb[base160 + f];
    }
    __syncthreads();
    int fl = g*162;
    float2 y[5];
    #pragma unroll
    for (int n1=0;n1<5;n1++){
        int e = n1*32 + l;
        float2 X;
        if (e <= 80){
            float2 A = ldsC[fl + e], B = ldsC[fl + 81 + e];
            X = make_float2(A.x - B.y, A.y + B.x);
        } else {
            int m = 160 - e;
            float2 A = ldsC[fl + m], B = ldsC[fl + 81 + m];
            X = make_float2(A.x + B.y, B.x - A.y);
        }
        y[n1] = X;
    }
    linefft<-1>(y, l);
    int o5 = 5*br5(l);
    const float SC = 1.f/160.f;
    double acc = 0.0;
    #pragma unroll
    for (int k=0;k<5;k++){
        int n = o5 + k;
        int ia = 2*g*160 + n, ib = ia + 160;
        float za = ldsA[ia], zb = ldsA[ib];
        float va = LAM_F*za + y[k].x*SC;
        float vb = LAM_F*zb + y[k].y*SC;
        if (FIN == 0){
            acc += (double)za*(double)va + (double)zb*(double)vb;
            ldsA[ia] = va; ldsA[ib] = vb;
        } else {
            float ra = ldsB[ia] - va, rb = ldsB[ib] - vb;
            acc += (double)ra*(double)ra + (double)rb*(double)rb;
            ldsA[ia] = ra; ldsA[ib] = rb;
        }
    }
    __syncthreads();
    if (FIN == 0){
        for (int f = tid; f < 2560; f += 256) Ap[base160 + f] = ldsA[f];
    } else {
        for (int f = tid; f < 2560; f += 256){
            float v = ldsA[f];
            rrv[base160 + f] = v; ppv[base160 + f] = v;
        }
    }
    block_atomic_add(acc, FIN ? &S[0] : &S[1]);
}

// ---------------- y-axis sweeps (strided, guarded half-spectrum, W=8) ----------------
// one column per 32-lane group
template<int SGN>
__device__ __forceinline__ void ycompute(float2 (*tile)[WZ+1], int tid){
    int l = tid & 31, q = tid >> 5;
    const float SC = (SGN>0) ? 1.f : (1.f/160.f);
    float2 y[5];
    #pragma unroll
    for (int n1=0;n1<5;n1++) y[n1] = tile[l + 32*n1][q];
    linefft<SGN>(y, l);
    int o5 = 5*br5(l);
    #pragma unroll
    for (int k=0;k<5;k++) tile[o5+k][q] = cscale(y[k], SC);
}

// b = zchunk*160 + ix  (zb-outer so line-sharing blocks b, b+160 share an XCD)
template<int SGN>
__global__ __launch_bounds__(256) void fft_y1(float2* __restrict__ data)
{
    __shared__ float2 tile[NN][WZ+1];
    int b = blockIdx.x;
    int ix = b % 160, zb = (b / 160) * WZ;
    size_t tbase = (size_t)ix*XS + zb;
    int tid = threadIdx.x;
    for (int i = tid; i < NN*WZ; i += 256){
        int row = i >> 3, zi = i & 7;
        tile[row][zi] = (zb + zi < KP) ? data[tbase + (size_t)row*KP + zi] : make_float2(0.f,0.f);
    }
    __syncthreads();
    ycompute<SGN>(tile, tid);
    __syncthreads();
    for (int i = tid; i < NN*WZ; i += 256){
        int row = i >> 3, zi = i & 7;
        if (zb + zi < KP) data[tbase + (size_t)row*KP + zi] = tile[row][zi];
    }
}

template<int SGN>
__global__ __launch_bounds__(256) void fft_y3(RPc P)
{
    __shared__ float2 tile[NN][WZ+1];
    float2* data = P.C[blockIdx.y];
    int b = blockIdx.x;
    int ix = b % 160, zb = (b / 160) * WZ;
    size_t tbase = (size_t)ix*XS + zb;
    int tid = threadIdx.x;
    for (int i = tid; i < NN*WZ; i += 256){
        int row = i >> 3, zi = i & 7;
        tile[row][zi] = (zb + zi < KP) ? data[tbase + (size_t)row*KP + zi] : make_float2(0.f,0.f);
    }
    __syncthreads();
    ycompute<SGN>(tile, tid);
    __syncthreads();
    for (int i = tid; i < NN*WZ; i += 256){
        int row = i >> 3, zi = i & 7;
        if (zb + zi < KP) data[tbase + (size_t)row*KP + zi] = tile[row][zi];
    }
}

// ---------------- x-axis kernels with analytic K (batched over r) ----------------
// spread: C_r = invx( K_r * fwdx(CF) ), one radius per block (fwd recomputed per r)
__global__ __launch_bounds__(256) void fft_xK(RPc P, const float2* __restrict__ in)
{
    __shared__ float2 tile[NN][WZ+1];
    int r = blockIdx.y;
    int b = blockIdx.x;
    int iy = b % 160, zb = (b / 160) * WZ;
    size_t tbase = (size_t)iy*KP + zb;
    int tid = threadIdx.x, l = tid & 31, q = tid >> 5;
    for (int i = tid; i < NN*WZ; i += 256){
        int row = i >> 3, zi = i & 7;
        tile[row][zi] = (zb + zi < KP) ? in[tbase + (size_t)row*XS + zi] : make_float2(0.f,0.f);
    }
    __syncthreads();
    float fy = (float)((iy < 80) ? iy : iy - 160) * (1.f/160.f);
    float fy2 = fy*fy;
    float cy1 = __cosf(TPI*fy);
    float cy2 = 2.f*cy1*cy1 - 1.f;
    float cy3 = 2.f*cy1*cy2 - cy1;
    QCol qc = make_qcol(1.f, 2.f*cy1, 2.f*cy2, 2.f*cy3, zb + q);
    float2 y[5];
    #pragma unroll
    for (int n1=0;n1<5;n1++) y[n1] = tile[n1*32 + l][q];
    linefft<1>(y, l);
    int o5 = 5*br5(l);
    #pragma unroll
    for (int k=0;k<5;k++) tile[o5+k][q] = cscale(y[k], kval_r(r, qc, fy2, o5+k));
    #pragma unroll
    for (int n1=0;n1<5;n1++) y[n1] = tile[n1*32 + l][q];
    linefft<-1>(y, l);
    #pragma unroll
    for (int k=0;k<5;k++) tile[o5+k][q] = cscale(y[k], 1.f/160.f);
    __syncthreads();
    float2* Cr = P.C[r];
    for (int i = tid; i < NN*WZ; i += 256){
        int row = i >> 3, zi = i & 7;
        if (zb + zi < KP) Cr[tbase + (size_t)row*XS + zi] = tile[row][zi];
    }
}

// in-place: C_r = K_r * fwdx(C_r)   (natural kx order)
__global__ __launch_bounds__(256) void fft_xfwdK(RPc P)
{
    __shared__ float2 tile[NN][WZ+1];
    int r = blockIdx.y;
    int b = blockIdx.x;
    int iy = b % 160, zb = (b / 160) * WZ;
    size_t tbase = (size_t)iy*KP + zb;
    int tid = threadIdx.x, l = tid & 31, q = tid >> 5;
    float2* Cr = P.C[r];
    for (int i = tid; i < NN*WZ; i += 256){
        int row = i >> 3, zi = i & 7;
        tile[row][zi] = (zb + zi < KP) ? Cr[tbase + (size_t)row*XS + zi] : make_float2(0.f,0.f);
    }
    __syncthreads();
    float fy = (float)((iy < 80) ? iy : iy - 160) * (1.f/160.f);
    float fy2 = fy*fy;
    float cy1 = __cosf(TPI*fy);
    float cy2 = 2.f*cy1*cy1 - 1.f;
    float cy3 = 2.f*cy1*cy2 - cy1;
    QCol qc = make_qcol(1.f, 2.f*cy1, 2.f*cy2, 2.f*cy3, zb + q);
    float2 y[5];
    #pragma unroll
    for (int n1=0;n1<5;n1++) y[n1] = tile[n1*32 + l][q];
    linefft<1>(y, l);
    int o5 = 5*br5(l);
    #pragma unroll
    for (int k=0;k<5;k++) tile[o5+k][q] = cscale(y[k], kval_r(r, qc, fy2, o5+k));
    __syncthreads();
    for (int i = tid; i < NN*WZ; i += 256){
        int row = i >> 3, zi = i & 7;
        if (zb + zi < KP) Cr[tbase + (size_t)row*XS + zi] = tile[row][zi];
    }
}

// CF = invx( C0 + C1 + C2 )
__global__ __launch_bounds__(256) void fft_xsuminv(RPc P, float2* __restrict__ out)
{
    __shared__ float2 tile[NN][WZ+1];
    int b = blockIdx.x;
    int iy = b % 160, zb = (b / 160) * WZ;
    size_t tbase = (size_t)iy*KP + zb;
    int tid = threadIdx.x, l = tid & 31, q = tid >> 5;
    for (int i = tid; i < NN*WZ; i += 256){
        int row = i >> 3, zi = i & 7;
        float2 v = make_float2(0.f,0.f);
        if (zb + zi < KP){
            size_t gidx = tbase + (size_t)row*XS + zi;
            v = cadd(cadd(P.C[0][gidx], P.C[1][gidx]), P.C[2][gidx]);
        }
        tile[row][zi] = v;
    }
    __syncthreads();
    float2 y[5];
    #pragma unroll
    for (int n1=0;n1<5;n1++) y[n1] = tile[n1*32 + l][q];
    linefft<-1>(y, l);
    int o5 = 5*br5(l);
    #pragma unroll
    for (int k=0;k<5;k++) tile[o5+k][q] = cscale(y[k], 1.f/160.f);
    __syncthreads();
    for (int i = tid; i < NN*WZ; i += 256){
        int row = i >> 3, zi = i & 7;
        if (zb + zi < KP) out[tbase + (size_t)row*XS + zi] = tile[row][zi];
    }
}

// ---------------- setup / CG vector ops ----------------
__global__ __launch_bounds__(256) void m2w_kernel(const float* __restrict__ mask,
        const float* __restrict__ w, float* __restrict__ M0,
        float* __restrict__ M1, float* __restrict__ M2)
{
    int i = blockIdx.x*256 + threadIdx.x;
    float m = mask[i]; float mm = m*m;
    M0[i] = mm * w[3*(size_t)i+0];
    M1[i] = mm * w[3*(size_t)i+1];
    M2[i] = mm * w[3*(size_t)i+2];
}

__global__ __launch_bounds__(256) void copy_kernel(const float* __restrict__ a, float* __restrict__ b){
    int i = blockIdx.x*256 + threadIdx.x;
    b[i] = a[i];
}

#define GSTRIDE (2048*256)
__global__ __launch_bounds__(256) void upd1_kernel(float* __restrict__ x, float* __restrict__ r,
        const float* __restrict__ p, const float* __restrict__ Ap, double* s)
{
    float alpha = (float)(s[0] / (s[1] + 1e-12));
    double acc = 0.0;
    for (int i = blockIdx.x*256 + threadIdx.x; i < N3; i += GSTRIDE){
        x[i] += alpha * p[i];
        float rn = r[i] - alpha * Ap[i];
        r[i] = rn;
        acc += (double)rn * (double)rn;
    }
    block_atomic_add(acc, &s[2]);
}
__global__ void advance_kernel(double* s){
    if (threadIdx.x == 0){
        s[3] = s[2] / (s[0] + 1e-12);   // beta
        s[0] = s[2]; s[1] = 0.0; s[2] = 0.0;
    }
}
__global__ void zero_kernel(double* s){
    if (threadIdx.x < 4) s[threadIdx.x] = 0.0;
}

// ---------------- host orchestration ----------------
extern "C" void kernel_launch(void* const* d_in, const int* in_sizes, int n_in,
                              void* d_out, int out_size, void* d_ws, size_t ws_size,
                              hipStream_t stream)
{
    (void)in_sizes; (void)n_in; (void)out_size;
    const float* w    = (const float*)d_in[0];   // [N3*3], R fastest
    const float* x2   = (const float*)d_in[1];   // [N3]
    const float* mask = (const float*)d_in[2];   // [N3]
    const float* bb   = (const float*)d_in[3];   // [N3]
    float* x = (float*)d_out;
    char* ws = (char*)d_ws;

    size_t off = 0;
    auto alloc = [&](size_t bytes)->void*{
        void* pp = ws + off;
        off += (bytes + 255) & ~(size_t)255;
        return pp;
    };
    const size_t CB = (size_t)NLINES * KP * sizeof(float2);   // 16.6 MB
    float2* CF = (float2*)alloc(CB);
    float2* C0 = (float2*)alloc(CB);
    float2* C1 = (float2*)alloc(CB);
    float2* C2 = (float2*)alloc(CB);
    float*  rr = (float*) alloc((size_t)N3*4);
    float*  pp = (float*) alloc((size_t)N3*4);
    double* S  = (double*)alloc(64);
    float*  Ap = (float*)C0;      // alias: C0 dead when Ap produced/consumed
    bool PRE = (ws_size >= off + 3*(((size_t)N3*4 + 255) & ~(size_t)255));
    float *M0=nullptr, *M1=nullptr, *M2=nullptr;
    if (PRE){
        M0 = (float*)alloc((size_t)N3*4);
        M1 = (float*)alloc((size_t)N3*4);
        M2 = (float*)alloc((size_t)N3*4);
    }
    RPc P;
    P.C[0]=C0; P.C[1]=C1; P.C[2]=C2;
    P.M[0]=M0; P.M[1]=M1; P.M[2]=M2;

    zero_kernel<<<1, 64, 0, stream>>>(S);
    if (PRE) m2w_kernel<<<16000, 256, 0, stream>>>(mask, w, M0, M1, M2);
    copy_kernel<<<16000, 256, 0, stream>>>(x2, x);

    const int GY = NBZ * 160;    // 1760
    // PM: 0 = plain fft of z; 1 = fused p-update. FIN: 1 = initial residual, 0 = CG iter.
    auto applyM = [&](const float* z, int FIN, int PM){
        if (PM) fft_z_first<1><<<1600, 256, 0, stream>>>(z, rr, pp, CF, S);
        else    fft_z_first<0><<<1600, 256, 0, stream>>>(z, rr, pp, CF, S);
        fft_y1<1><<<GY, 256, 0, stream>>>(CF);
        fft_xK<<<dim3(GY,3), 256, 0, stream>>>(P, CF);
        fft_y3<-1><<<dim3(GY,3), 256, 0, stream>>>(P);
        if (PRE) fft_z_mid3<true ><<<dim3(1600,3), 256, 0, stream>>>(P, mask, w);
        else     fft_z_mid3<false><<<dim3(1600,3), 256, 0, stream>>>(P, mask, w);
        fft_y3<1><<<dim3(GY,3), 256, 0, stream>>>(P);
        fft_xfwdK<<<dim3(GY,3), 256, 0, stream>>>(P);
        fft_xsuminv<<<GY, 256, 0, stream>>>(P, CF);
        fft_y1<-1><<<GY, 256, 0, stream>>>(CF);
        if (FIN) fft_z_fin<1><<<1600, 256, 0, stream>>>(CF, z, Ap, bb, rr, pp, S);
        else     fft_z_fin<0><<<1600, 256, 0, stream>>>(CF, z, Ap, bb, rr, pp, S);
    };

    // r = b - M(x2); p = r; rs = <r,r>
    applyM(x, 1, 0);

    for (int it = 0; it < 10; it++){
        applyM(pp, 0, (it == 0) ? 0 : 1);          // Ap = M(p), S[1] = <p,Ap>
        upd1_kernel<<<2048, 256, 0, stream>>>(x, rr, pp, Ap, S);
        if (it < 9) advance_kernel<<<1, 64, 0, stream>>>(S);
    }
}

// Round 5
// 3144.954 us; speedup vs baseline: 2.7840x; 1.1144x over previous
//
#include <hip/hip_runtime.h>

#define NN 160
#define KP 81                // kept kz planes (Hermitian half)
#define N3 4096000           // 160^3
#define NLINES 25600         // 160^2 z-lines
#define WZ 8                 // tile width (kz columns) for x/y sweeps
#define NBZ 11               // ceil(81/8)
#define XS 12960             // x-stride in complex layout (160*81)
#define TPI 6.28318530717958647692f
#define LAM_F 0.05f

// ---------------- complex helpers ----------------
__device__ __forceinline__ float2 cxmul(float2 a, float2 b){
    return make_float2(a.x*b.x - a.y*b.y, a.x*b.y + a.y*b.x);
}
__device__ __forceinline__ float2 cadd(float2 a, float2 b){ return make_float2(a.x+b.x, a.y+b.y); }
__device__ __forceinline__ float2 csub(float2 a, float2 b){ return make_float2(a.x-b.x, a.y-b.y); }
__device__ __forceinline__ float2 cscale(float2 a, float s){ return make_float2(a.x*s, a.y*s); }
__device__ __forceinline__ float2 shfl2(float2 v, int m){
    return make_float2(__shfl_xor(v.x, m, 64), __shfl_xor(v.y, m, 64));
}
__device__ __forceinline__ int br5(int l){
    return ((l&1)<<4)|((l&2)<<2)|(l&4)|((l&8)>>2)|((l&16)>>4);
}
// rev in revolutions (angle/2pi), |rev| < 256. v_sin_f32/v_cos_f32 are
// revolution-input on gfx950 -> 1 instr each, no range reduction needed.
__device__ __forceinline__ float fsin_rev(float rev){ return __builtin_amdgcn_sinf(rev); }
__device__ __forceinline__ float fcos_rev(float rev){ return __builtin_amdgcn_cosf(rev); }
template<int SGN>
__device__ __forceinline__ float2 twid(float rev){
    float s = fsin_rev(rev), c = fcos_rev(rev);
    return make_float2(c, (SGN>0) ? -s : s);
}

// ---------------- radix-5 DFT ----------------
template<int SGN>
__device__ __forceinline__ void dft5(float2 y[5]){
    const float C1 = 0.30901699437494742f;
    const float C2 = -0.80901699437494742f;
    const float S1 = 0.95105651629515357f;
    const float S2 = 0.58778525229247312f;
    float2 x0=y[0], x1=y[1], x2=y[2], x3=y[3], x4=y[4];
    float2 t1=cadd(x1,x4), t2=cadd(x2,x3), t3=csub(x1,x4), t4=csub(x2,x3);
    y[0] = cadd(x0, cadd(t1,t2));
    float2 a1 = make_float2(x0.x + C1*t1.x + C2*t2.x, x0.y + C1*t1.y + C2*t2.y);
    float2 a2 = make_float2(x0.x + C2*t1.x + C1*t2.x, x0.y + C2*t1.y + C1*t2.y);
    const float sg = (SGN>0) ? 1.f : -1.f;
    float2 b1 = make_float2(sg*(S1*t3.x + S2*t4.x), sg*(S1*t3.y + S2*t4.y));
    float2 b2 = make_float2(sg*(S2*t3.x - S1*t4.x), sg*(S2*t3.y - S1*t4.y));
    y[1] = make_float2(a1.x + b1.y, a1.y - b1.x);
    y[4] = make_float2(a1.x - b1.y, a1.y + b1.x);
    y[2] = make_float2(a2.x + b2.y, a2.y - b2.x);
    y[3] = make_float2(a2.x - b2.y, a2.y + b2.x);
}

__device__ __forceinline__ float2 bfly(float2 v, int m, float2 tw, int l){
    float2 o = shfl2(v, m);
    float2 s = cadd(v, o);
    float2 d = cxmul(csub(o, v), tw);
    return (l & m) ? d : s;
}

// 160-pt FFT: lane l in [0,32) holds y[n1]=x[n1*32+l] on entry.
// On exit, slot k holds X[k + 5*br5(l)].
template<int SGN>
__device__ __forceinline__ void linefft(float2 y[5], int l){
    dft5<SGN>(y);
    float2 w1 = twid<SGN>((float)l * (1.f/160.f));
    float2 w2 = cxmul(w1,w1);
    float2 w3 = cxmul(w2,w1);
    float2 w4 = cxmul(w2,w2);
    y[1]=cxmul(y[1],w1); y[2]=cxmul(y[2],w2); y[3]=cxmul(y[3],w3); y[4]=cxmul(y[4],w4);
    float2 tw16 = twid<SGN>((float)(l & 15) * (1.f/32.f));
    float2 tw8  = twid<SGN>((float)(l & 7)  * (1.f/16.f));
    float2 tw4  = twid<SGN>((float)(l & 3)  * (1.f/8.f));
    float2 tw2  = twid<SGN>((float)(l & 1)  * (1.f/4.f));
    #pragma unroll
    for (int k=0;k<5;k++){
        float2 v = y[k];
        v = bfly(v,16,tw16,l);
        v = bfly(v, 8,tw8 ,l);
        v = bfly(v, 4,tw4 ,l);
        v = bfly(v, 2,tw2 ,l);
        float2 o = shfl2(v,1);
        v = (l&1) ? csub(o,v) : cadd(v,o);
        y[k] = v;
    }
}

struct RPc {
    float2* C[3];
    const float* M[3];
};

// analytic kernel ingredients: Q sums over (dy,dz) ball slices, per column
struct QCol {
    float Q1_0, Q1_1;
    float Q2_0, Q2_1, Q2_2;
    float Q3_0, Q3_1, Q3_2, Q3_3;
    float fz2;
};

__device__ __forceinline__ QCol make_qcol(float ay0,float ay1,float ay2,float ay3, int kz){
    float fz = (float)kz * (1.f/160.f);
    float cz1 = fcos_rev(fz);
    float cz2 = 2.f*cz1*cz1 - 1.f;
    float cz3 = 2.f*cz1*cz2 - cz1;
    float az0=1.f, az1=2.f*cz1, az2=2.f*cz2, az3=2.f*cz3;
    float P00=ay0*az0, P01=ay0*az1, P02=ay0*az2, P03=ay0*az3;
    float P10=ay1*az0, P11=ay1*az1, P12=ay1*az2;
    float P20=ay2*az0, P21=ay2*az1, P22=ay2*az2;
    float P30=ay3*az0;
    QCol q;
    q.Q1_0 = P00 + P01 + P10;
    q.Q1_1 = P00;
    q.Q2_0 = P00+P01+P02+P10+P11+P20;
    q.Q2_1 = P00+P01+P10+P11;
    q.Q2_2 = P00;
    q.Q3_0 = P00+P01+P02+P03+P10+P11+P12+P20+P21+P22+P30;
    q.Q3_1 = P00+P01+P02+P10+P11+P12+P20+P21+P22;
    q.Q3_2 = P00+P01+P02+P10+P11+P12+P20+P21;
    q.Q3_3 = P00;
    q.fz2 = fz*fz;
    return q;
}

// K_r for slot: kx in [0,160)
template<int R>
__device__ __forceinline__ float kval(const QCol& q, float fy2, int kx){
    float c1 = fcos_rev((float)kx * (1.f/160.f));
    float s;
    if (R == 0){
        s = (q.Q1_0 + 2.f*c1*q.Q1_1) * (1.f/7.f);
    } else if (R == 1){
        float c2 = 2.f*c1*c1 - 1.f;
        s = (q.Q2_0 + 2.f*(c1*q.Q2_1 + c2*q.Q2_2)) * (1.f/33.f);
    } else {
        float c2 = 2.f*c1*c1 - 1.f;
        float c3 = 2.f*c1*c2 - c1;
        s = (q.Q3_0 + 2.f*(c1*q.Q3_1 + c2*q.Q3_2 + c3*q.Q3_3)) * (1.f/123.f);
    }
    float fxw = (float)((kx < 80) ? kx : 160 - kx) * (1.f/160.f);
    float k2 = fxw*fxw + fy2 + q.fz2;
    float D = (1.f/3.f) - ((k2 == 0.f) ? 0.f : q.fz2 * __builtin_amdgcn_rcpf(k2));
    return (1.f - s) * D;
}

__device__ __forceinline__ float kval_r(int r, const QCol& q, float fy2, int kx){
    if (r == 0) return kval<0>(q, fy2, kx);
    if (r == 1) return kval<1>(q, fy2, kx);
    return kval<2>(q, fy2, kx);
}

// ---------------- CG reduction helper ----------------
__device__ __forceinline__ void block_atomic_add(double v, double* target){
    #pragma unroll
    for (int off=32; off>0; off>>=1) v += __shfl_down(v, off, 64);
    __shared__ double sm[4];
    int wv = threadIdx.x >> 6;
    if ((threadIdx.x & 63) == 0) sm[wv] = v;
    __syncthreads();
    if (threadIdx.x == 0) atomicAdd(target, sm[0]+sm[1]+sm[2]+sm[3]);
}

// ---------------- z-axis kernels (two-for-one packed, r2c half-spectrum) ----------------
// PM=0: fft real zin. PM=1: p = r + beta*p (beta=S[3]), store p, fft p.
template<int PM>
__global__ __launch_bounds__(256) void fft_z_first(const float* __restrict__ zin,
    const float* __restrict__ rrv, float* __restrict__ ppv,
    float2* __restrict__ out, const double* __restrict__ S)
{
    __shared__ float  ldsR[16*160];
    __shared__ float2 ldsC[8*162];
    int tid = threadIdx.x, l = tid & 31, g = tid >> 5;   // g = pair 0..7
    size_t base160 = (size_t)blockIdx.x * 2560;
    float beta = PM ? (float)S[3] : 0.f;
    for (int f = tid; f < 2560; f += 256){
        float v;
        if (PM){
            v = rrv[base160 + f] + beta * ppv[base160 + f];
            ppv[base160 + f] = v;
        } else v = zin[base160 + f];
        ldsR[f] = v;
    }
    __syncthreads();
    float2 y[5];
    #pragma unroll
    for (int n1=0;n1<5;n1++){
        int n = n1*32 + l;
        y[n1] = make_float2(ldsR[2*g*160 + n], ldsR[(2*g+1)*160 + n]);
    }
    linefft<1>(y, l);
    int o5 = 5*br5(l);
    #pragma unroll
    for (int k=0;k<5;k++) ldsC[g*162 + o5 + k] = y[k];
    __syncthreads();
    size_t baseC = (size_t)blockIdx.x * 1296;
    for (int f = tid; f < 1296; f += 256){
        int line = f / 81, k = f - line*81;
        int pr = line >> 1;
        float2 Sk = ldsC[pr*162 + k];
        float2 Sm = ldsC[pr*162 + ((160 - k) % 160)];
        float2 o = (line & 1)
            ? make_float2(0.5f*(Sk.y + Sm.y), -0.5f*(Sk.x - Sm.x))    // B
            : make_float2(0.5f*(Sk.x + Sm.x),  0.5f*(Sk.y - Sm.y));   // A
        out[baseC + f] = o;
    }
}

// fused: inverse-z (Hermitian reconstruct, packed pair) -> *m2w_r -> forward-z -> half-spectrum
template<bool PRE>
__global__ __launch_bounds__(256) void fft_z_mid3(RPc P, const float* __restrict__ mask,
                                                 const float* __restrict__ wfull)
{
    __shared__ float2 ldsC[8*162];
    __shared__ float  ldsM[16*160];
    int r = blockIdx.y;
    float2* C = P.C[r];
    int tid = threadIdx.x, l = tid & 31, g = tid >> 5;
    size_t baseC = (size_t)blockIdx.x * 1296;
    size_t base160 = (size_t)blockIdx.x * 2560;
    for (int f = tid; f < 1296; f += 256) ldsC[f] = C[baseC + f];
    if (PRE){
        const float* M = P.M[r];
        for (int f = tid; f < 2560; f += 256) ldsM[f] = M[base160 + f];
    } else {
        for (int f = tid; f < 2560; f += 256){
            float m = mask[base160 + f];
            ldsM[f] = m*m*wfull[(base160 + f)*3 + r];
        }
    }
    __syncthreads();
    int fl = g*162;
    float2 y[5];
    #pragma unroll
    for (int n1=0;n1<5;n1++){
        int e = n1*32 + l;
        float2 X;
        if (e <= 80){
            float2 A = ldsC[fl + e], B = ldsC[fl + 81 + e];
            X = make_float2(A.x - B.y, A.y + B.x);
        } else {
            int m = 160 - e;
            float2 A = ldsC[fl + m], B = ldsC[fl + 81 + m];
            X = make_float2(A.x + B.y, B.x - A.y);
        }
        y[n1] = X;
    }
    linefft<-1>(y, l);
    int o5 = 5*br5(l);
    const float SC = 1.f/160.f;
    #pragma unroll
    for (int k=0;k<5;k++){
        int n = o5 + k;
        float a = y[k].x * SC * ldsM[2*g*160 + n];
        float b = y[k].y * SC * ldsM[(2*g+1)*160 + n];
        ldsC[fl + n] = make_float2(a, b);
    }
    #pragma unroll
    for (int n1=0;n1<5;n1++) y[n1] = ldsC[fl + n1*32 + l];
    linefft<1>(y, l);
    #pragma unroll
    for (int k=0;k<5;k++) ldsC[fl + o5 + k] = y[k];
    __syncthreads();
    for (int f = tid; f < 1296; f += 256){
        int line = f / 81, k = f - line*81;
        int pr = line >> 1;
        float2 Sk = ldsC[pr*162 + k];
        float2 Sm = ldsC[pr*162 + ((160 - k) % 160)];
        float2 o = (line & 1)
            ? make_float2(0.5f*(Sk.y + Sm.y), -0.5f*(Sk.x - Sm.x))
            : make_float2(0.5f*(Sk.x + Sm.x),  0.5f*(Sk.y - Sm.y));
        C[baseC + f] = o;
    }
}

// final inverse-z + epilogue. FIN=0: Ap=v, S[1]+=<z,v>. FIN=1: r=b-v -> rr,pp, S[0]+=<r,r>.
template<int FIN>
__global__ __launch_bounds__(256) void fft_z_fin(const float2* __restrict__ in,
    const float* __restrict__ zsp, float* __restrict__ Ap,
    const float* __restrict__ bb, float* __restrict__ rrv, float* __restrict__ ppv,
    double* __restrict__ S)
{
    __shared__ float2 ldsC[8*162];
    __shared__ float  ldsA[16*160];
    __shared__ float  ldsB[FIN ? 16*160 : 1];
    int tid = threadIdx.x, l = tid & 31, g = tid >> 5;
    size_t baseC = (size_t)blockIdx.x * 1296;
    size_t base160 = (size_t)blockIdx.x * 2560;
    for (int f = tid; f < 1296; f += 256) ldsC[f] = in[baseC + f];
    for (int f = tid; f < 2560; f += 256) ldsA[f] = zsp[base160 + f];
    if (FIN){
        for (int f = tid; f < 2560; f += 256) ldsB[f] = bb[base160 + f];
    }
    __syncthreads();
    int fl = g*162;
    float2 y[5];
    #pragma unroll
    for (int n1=0;n1<5;n1++){
        int e = n1*32 + l;
        float2 X;
        if (e <= 80){
            float2 A = ldsC[fl + e], B = ldsC[fl + 81 + e];
            X = make_float2(A.x - B.y, A.y + B.x);
        } else {
            int m = 160 - e;
            float2 A = ldsC[fl + m], B = ldsC[fl + 81 + m];
            X = make_float2(A.x + B.y, B.x - A.y);
        }
        y[n1] = X;
    }
    linefft<-1>(y, l);
    int o5 = 5*br5(l);
    const float SC = 1.f/160.f;
    double acc = 0.0;
    #pragma unroll
    for (int k=0;k<5;k++){
        int n = o5 + k;
        int ia = 2*g*160 + n, ib = ia + 160;
        float za = ldsA[ia], zb = ldsA[ib];
        float va = LAM_F*za + y[k].x*SC;
        float vb = LAM_F*zb + y[k].y*SC;
        if (FIN == 0){
            acc += (double)za*(double)va + (double)zb*(double)vb;
            ldsA[ia] = va; ldsA[ib] = vb;
        } else {
            float ra = ldsB[ia] - va, rb = ldsB[ib] - vb;
            acc += (double)ra*(double)ra + (double)rb*(double)rb;
            ldsA[ia] = ra; ldsA[ib] = rb;
        }
    }
    __syncthreads();
    if (FIN == 0){
        for (int f = tid; f < 2560; f += 256) Ap[base160 + f] = ldsA[f];
    } else {
        for (int f = tid; f < 2560; f += 256){
            float v = ldsA[f];
            rrv[base160 + f] = v; ppv[base160 + f] = v;
        }
    }
    block_atomic_add(acc, FIN ? &S[0] : &S[1]);
}

// ---------------- y-axis sweeps (strided, guarded half-spectrum, W=8) ----------------
// one column per 32-lane group
template<int SGN>
__device__ __forceinline__ void ycompute(float2 (*tile)[WZ+1], int tid){
    int l = tid & 31, q = tid >> 5;
    const float SC = (SGN>0) ? 1.f : (1.f/160.f);
    float2 y[5];
    #pragma unroll
    for (int n1=0;n1<5;n1++) y[n1] = tile[l + 32*n1][q];
    linefft<SGN>(y, l);
    int o5 = 5*br5(l);
    #pragma unroll
    for (int k=0;k<5;k++) tile[o5+k][q] = cscale(y[k], SC);
}

// b = zchunk*160 + ix  (zb-outer so line-sharing blocks b, b+160 share an XCD)
template<int SGN>
__global__ __launch_bounds__(256) void fft_y1(float2* __restrict__ data)
{
    __shared__ float2 tile[NN][WZ+1];
    int b = blockIdx.x;
    int ix = b % 160, zb = (b / 160) * WZ;
    size_t tbase = (size_t)ix*XS + zb;
    int tid = threadIdx.x;
    for (int i = tid; i < NN*WZ; i += 256){
        int row = i >> 3, zi = i & 7;
        tile[row][zi] = (zb + zi < KP) ? data[tbase + (size_t)row*KP + zi] : make_float2(0.f,0.f);
    }
    __syncthreads();
    ycompute<SGN>(tile, tid);
    __syncthreads();
    for (int i = tid; i < NN*WZ; i += 256){
        int row = i >> 3, zi = i & 7;
        if (zb + zi < KP) data[tbase + (size_t)row*KP + zi] = tile[row][zi];
    }
}

template<int SGN>
__global__ __launch_bounds__(256) void fft_y3(RPc P)
{
    __shared__ float2 tile[NN][WZ+1];
    float2* data = P.C[blockIdx.y];
    int b = blockIdx.x;
    int ix = b % 160, zb = (b / 160) * WZ;
    size_t tbase = (size_t)ix*XS + zb;
    int tid = threadIdx.x;
    for (int i = tid; i < NN*WZ; i += 256){
        int row = i >> 3, zi = i & 7;
        tile[row][zi] = (zb + zi < KP) ? data[tbase + (size_t)row*KP + zi] : make_float2(0.f,0.f);
    }
    __syncthreads();
    ycompute<SGN>(tile, tid);
    __syncthreads();
    for (int i = tid; i < NN*WZ; i += 256){
        int row = i >> 3, zi = i & 7;
        if (zb + zi < KP) data[tbase + (size_t)row*KP + zi] = tile[row][zi];
    }
}

// ---------------- x-axis kernels with analytic K (batched over r) ----------------
// spread: C_r = invx( K_r * fwdx(CF) ), one radius per block (fwd recomputed per r)
__global__ __launch_bounds__(256) void fft_xK(RPc P, const float2* __restrict__ in)
{
    __shared__ float2 tile[NN][WZ+1];
    int r = blockIdx.y;
    int b = blockIdx.x;
    int iy = b % 160, zb = (b / 160) * WZ;
    size_t tbase = (size_t)iy*KP + zb;
    int tid = threadIdx.x, l = tid & 31, q = tid >> 5;
    for (int i = tid; i < NN*WZ; i += 256){
        int row = i >> 3, zi = i & 7;
        tile[row][zi] = (zb + zi < KP) ? in[tbase + (size_t)row*XS + zi] : make_float2(0.f,0.f);
    }
    __syncthreads();
    float fy = (float)((iy < 80) ? iy : iy - 160) * (1.f/160.f);
    float fy2 = fy*fy;
    float cy1 = fcos_rev(fy);
    float cy2 = 2.f*cy1*cy1 - 1.f;
    float cy3 = 2.f*cy1*cy2 - cy1;
    QCol qc = make_qcol(1.f, 2.f*cy1, 2.f*cy2, 2.f*cy3, zb + q);
    float2 y[5];
    #pragma unroll
    for (int n1=0;n1<5;n1++) y[n1] = tile[n1*32 + l][q];
    linefft<1>(y, l);
    int o5 = 5*br5(l);
    #pragma unroll
    for (int k=0;k<5;k++) tile[o5+k][q] = cscale(y[k], kval_r(r, qc, fy2, o5+k));
    #pragma unroll
    for (int n1=0;n1<5;n1++) y[n1] = tile[n1*32 + l][q];
    linefft<-1>(y, l);
    #pragma unroll
    for (int k=0;k<5;k++) tile[o5+k][q] = cscale(y[k], 1.f/160.f);
    __syncthreads();
    float2* Cr = P.C[r];
    for (int i = tid; i < NN*WZ; i += 256){
        int row = i >> 3, zi = i & 7;
        if (zb + zi < KP) Cr[tbase + (size_t)row*XS + zi] = tile[row][zi];
    }
}

// in-place: C_r = K_r * fwdx(C_r)   (natural kx order)
__global__ __launch_bounds__(256) void fft_xfwdK(RPc P)
{
    __shared__ float2 tile[NN][WZ+1];
    int r = blockIdx.y;
    int b = blockIdx.x;
    int iy = b % 160, zb = (b / 160) * WZ;
    size_t tbase = (size_t)iy*KP + zb;
    int tid = threadIdx.x, l = tid & 31, q = tid >> 5;
    float2* Cr = P.C[r];
    for (int i = tid; i < NN*WZ; i += 256){
        int row = i >> 3, zi = i & 7;
        tile[row][zi] = (zb + zi < KP) ? Cr[tbase + (size_t)row*XS + zi] : make_float2(0.f,0.f);
    }
    __syncthreads();
    float fy = (float)((iy < 80) ? iy : iy - 160) * (1.f/160.f);
    float fy2 = fy*fy;
    float cy1 = fcos_rev(fy);
    float cy2 = 2.f*cy1*cy1 - 1.f;
    float cy3 = 2.f*cy1*cy2 - cy1;
    QCol qc = make_qcol(1.f, 2.f*cy1, 2.f*cy2, 2.f*cy3, zb + q);
    float2 y[5];
    #pragma unroll
    for (int n1=0;n1<5;n1++) y[n1] = tile[n1*32 + l][q];
    linefft<1>(y, l);
    int o5 = 5*br5(l);
    #pragma unroll
    for (int k=0;k<5;k++) tile[o5+k][q] = cscale(y[k], kval_r(r, qc, fy2, o5+k));
    __syncthreads();
    for (int i = tid; i < NN*WZ; i += 256){
        int row = i >> 3, zi = i & 7;
        if (zb + zi < KP) Cr[tbase + (size_t)row*XS + zi] = tile[row][zi];
    }
}

// CF = invx( C0 + C1 + C2 )
__global__ __launch_bounds__(256) void fft_xsuminv(RPc P, float2* __restrict__ out)
{
    __shared__ float2 tile[NN][WZ+1];
    int b = blockIdx.x;
    int iy = b % 160, zb = (b / 160) * WZ;
    size_t tbase = (size_t)iy*KP + zb;
    int tid = threadIdx.x, l = tid & 31, q = tid >> 5;
    for (int i = tid; i < NN*WZ; i += 256){
        int row = i >> 3, zi = i & 7;
        float2 v = make_float2(0.f,0.f);
        if (zb + zi < KP){
            size_t gidx = tbase + (size_t)row*XS + zi;
            v = cadd(cadd(P.C[0][gidx], P.C[1][gidx]), P.C[2][gidx]);
        }
        tile[row][zi] = v;
    }
    __syncthreads();
    float2 y[5];
    #pragma unroll
    for (int n1=0;n1<5;n1++) y[n1] = tile[n1*32 + l][q];
    linefft<-1>(y, l);
    int o5 = 5*br5(l);
    #pragma unroll
    for (int k=0;k<5;k++) tile[o5+k][q] = cscale(y[k], 1.f/160.f);
    __syncthreads();
    for (int i = tid; i < NN*WZ; i += 256){
        int row = i >> 3, zi = i & 7;
        if (zb + zi < KP) out[tbase + (size_t)row*XS + zi] = tile[row][zi];
    }
}

// ---------------- setup / CG vector ops ----------------
__global__ __launch_bounds__(256) void m2w_kernel(const float* __restrict__ mask,
        const float* __restrict__ w, float* __restrict__ M0,
        float* __restrict__ M1, float* __restrict__ M2)
{
    int i = blockIdx.x*256 + threadIdx.x;
    float m = mask[i]; float mm = m*m;
    M0[i] = mm * w[3*(size_t)i+0];
    M1[i] = mm * w[3*(size_t)i+1];
    M2[i] = mm * w[3*(size_t)i+2];
}

__global__ __launch_bounds__(256) void copy_kernel(const float* __restrict__ a, float* __restrict__ b){
    int i = blockIdx.x*256 + threadIdx.x;
    b[i] = a[i];
}

#define GSTRIDE (2048*256)
__global__ __launch_bounds__(256) void upd1_kernel(float* __restrict__ x, float* __restrict__ r,
        const float* __restrict__ p, const float* __restrict__ Ap, double* s)
{
    float alpha = (float)(s[0] / (s[1] + 1e-12));
    double acc = 0.0;
    for (int i = blockIdx.x*256 + threadIdx.x; i < N3; i += GSTRIDE){
        x[i] += alpha * p[i];
        float rn = r[i] - alpha * Ap[i];
        r[i] = rn;
        acc += (double)rn * (double)rn;
    }
    block_atomic_add(acc, &s[2]);
}
__global__ void advance_kernel(double* s){
    if (threadIdx.x == 0){
        s[3] = s[2] / (s[0] + 1e-12);   // beta
        s[0] = s[2]; s[1] = 0.0; s[2] = 0.0;
    }
}
__global__ void zero_kernel(double* s){
    if (threadIdx.x < 4) s[threadIdx.x] = 0.0;
}

// ---------------- host orchestration ----------------
extern "C" void kernel_launch(void* const* d_in, const int* in_sizes, int n_in,
                              void* d_out, int out_size, void* d_ws, size_t ws_size,
                              hipStream_t stream)
{
    (void)in_sizes; (void)n_in; (void)out_size;
    const float* w    = (const float*)d_in[0];   // [N3*3], R fastest
    const float* x2   = (const float*)d_in[1];   // [N3]
    const float* mask = (const float*)d_in[2];   // [N3]
    const float* bb   = (const float*)d_in[3];   // [N3]
    float* x = (float*)d_out;
    char* ws = (char*)d_ws;

    size_t off = 0;
    auto alloc = [&](size_t bytes)->void*{
        void* pp = ws + off;
        off += (bytes + 255) & ~(size_t)255;
        return pp;
    };
    const size_t CB = (size_t)NLINES * KP * sizeof(float2);   // 16.6 MB
    float2* CF = (float2*)alloc(CB);
    float2* C0 = (float2*)alloc(CB);
    float2* C1 = (float2*)alloc(CB);
    float2* C2 = (float2*)alloc(CB);
    float*  rr = (float*) alloc((size_t)N3*4);
    float*  pp = (float*) alloc((size_t)N3*4);
    double* S  = (double*)alloc(64);
    float*  Ap = (float*)C0;      // alias: C0 dead when Ap produced/consumed
    bool PRE = (ws_size >= off + 3*(((size_t)N3*4 + 255) & ~(size_t)255));
    float *M0=nullptr, *M1=nullptr, *M2=nullptr;
    if (PRE){
        M0 = (float*)alloc((size_t)N3*4);
        M1 = (float*)alloc((size_t)N3*4);
        M2 = (float*)alloc((size_t)N3*4);
    }
    RPc P;
    P.C[0]=C0; P.C[1]=C1; P.C[2]=C2;
    P.M[0]=M0; P.M[1]=M1; P.M[2]=M2;

    zero_kernel<<<1, 64, 0, stream>>>(S);
    if (PRE) m2w_kernel<<<16000, 256, 0, stream>>>(mask, w, M0, M1, M2);
    copy_kernel<<<16000, 256, 0, stream>>>(x2, x);

    const int GY = NBZ * 160;    // 1760
    // PM: 0 = plain fft of z; 1 = fused p-update. FIN: 1 = initial residual, 0 = CG iter.
    auto applyM = [&](const float* z, int FIN, int PM){
        if (PM) fft_z_first<1><<<1600, 256, 0, stream>>>(z, rr, pp, CF, S);
        else    fft_z_first<0><<<1600, 256, 0, stream>>>(z, rr, pp, CF, S);
        fft_y1<1><<<GY, 256, 0, stream>>>(CF);
        fft_xK<<<dim3(GY,3), 256, 0, stream>>>(P, CF);
        fft_y3<-1><<<dim3(GY,3), 256, 0, stream>>>(P);
        if (PRE) fft_z_mid3<true ><<<dim3(1600,3), 256, 0, stream>>>(P, mask, w);
        else     fft_z_mid3<false><<<dim3(1600,3), 256, 0, stream>>>(P, mask, w);
        fft_y3<1><<<dim3(GY,3), 256, 0, stream>>>(P);
        fft_xfwdK<<<dim3(GY,3), 256, 0, stream>>>(P);
        fft_xsuminv<<<GY, 256, 0, stream>>>(P, CF);
        fft_y1<-1><<<GY, 256, 0, stream>>>(CF);
        if (FIN) fft_z_fin<1><<<1600, 256, 0, stream>>>(CF, z, Ap, bb, rr, pp, S);
        else     fft_z_fin<0><<<1600, 256, 0, stream>>>(CF, z, Ap, bb, rr, pp, S);
    };

    // r = b - M(x2); p = r; rs = <r,r>
    applyM(x, 1, 0);

    for (int it = 0; it < 10; it++){
        applyM(pp, 0, (it == 0) ? 0 : 1);          // Ap = M(p), S[1] = <p,Ap>
        upd1_kernel<<<2048, 256, 0, stream>>>(x, rr, pp, Ap, S);
        if (it < 9) advance_kernel<<<1, 64, 0, stream>>>(S);
    }
}

// Round 6
// 2986.023 us; speedup vs baseline: 2.9322x; 1.0532x over previous
//
#include <hip/hip_runtime.h>

#define NN 160
#define KP 81                // kept kz planes (Hermitian half)
#define N3 4096000           // 160^3
#define NLINES 25600         // 160^2 z-lines
#define WZ 8                 // tile width (kz columns) for x/y sweeps
#define NBZ 11               // ceil(81/8)
#define XS 12960             // x-stride in complex layout (160*81)
#define TPI 6.28318530717958647692f
#define LAM_F 0.05f

// ---------------- complex helpers ----------------
__device__ __forceinline__ float2 cxmul(float2 a, float2 b){
    return make_float2(a.x*b.x - a.y*b.y, a.x*b.y + a.y*b.x);
}
__device__ __forceinline__ float2 cadd(float2 a, float2 b){ return make_float2(a.x+b.x, a.y+b.y); }
__device__ __forceinline__ float2 csub(float2 a, float2 b){ return make_float2(a.x-b.x, a.y-b.y); }
__device__ __forceinline__ float2 cscale(float2 a, float s){ return make_float2(a.x*s, a.y*s); }
__device__ __forceinline__ float2 shfl2(float2 v, int m){
    return make_float2(__shfl_xor(v.x, m, 64), __shfl_xor(v.y, m, 64));
}
__device__ __forceinline__ int br5(int l){
    return ((l&1)<<4)|((l&2)<<2)|(l&4)|((l&8)>>2)|((l&16)>>4);
}
// rev in revolutions (angle/2pi). v_sin_f32/v_cos_f32 are revolution-input
// on gfx950 -> 1 instr each, no range reduction needed.
__device__ __forceinline__ float fsin_rev(float rev){ return __builtin_amdgcn_sinf(rev); }
__device__ __forceinline__ float fcos_rev(float rev){ return __builtin_amdgcn_cosf(rev); }
template<int SGN>
__device__ __forceinline__ float2 twid(float rev){
    float s = fsin_rev(rev), c = fcos_rev(rev);
    return make_float2(c, (SGN>0) ? -s : s);
}

// ---------------- radix-5 DFT ----------------
template<int SGN>
__device__ __forceinline__ void dft5(float2 y[5]){
    const float C1 = 0.30901699437494742f;
    const float C2 = -0.80901699437494742f;
    const float S1 = 0.95105651629515357f;
    const float S2 = 0.58778525229247312f;
    float2 x0=y[0], x1=y[1], x2=y[2], x3=y[3], x4=y[4];
    float2 t1=cadd(x1,x4), t2=cadd(x2,x3), t3=csub(x1,x4), t4=csub(x2,x3);
    y[0] = cadd(x0, cadd(t1,t2));
    float2 a1 = make_float2(x0.x + C1*t1.x + C2*t2.x, x0.y + C1*t1.y + C2*t2.y);
    float2 a2 = make_float2(x0.x + C2*t1.x + C1*t2.x, x0.y + C2*t1.y + C1*t2.y);
    const float sg = (SGN>0) ? 1.f : -1.f;
    float2 b1 = make_float2(sg*(S1*t3.x + S2*t4.x), sg*(S1*t3.y + S2*t4.y));
    float2 b2 = make_float2(sg*(S2*t3.x - S1*t4.x), sg*(S2*t3.y - S1*t4.y));
    y[1] = make_float2(a1.x + b1.y, a1.y - b1.x);
    y[4] = make_float2(a1.x - b1.y, a1.y + b1.x);
    y[2] = make_float2(a2.x + b2.y, a2.y - b2.x);
    y[3] = make_float2(a2.x - b2.y, a2.y + b2.x);
}

__device__ __forceinline__ float2 bfly(float2 v, int m, float2 tw, int l){
    float2 o = shfl2(v, m);
    float2 s = cadd(v, o);
    float2 d = cxmul(csub(o, v), tw);
    return (l & m) ? d : s;
}

// 160-pt FFT: lane l in [0,32) holds y[n1]=x[n1*32+l] on entry.
// On exit, slot k holds X[k + 5*br5(l)].
template<int SGN>
__device__ __forceinline__ void linefft(float2 y[5], int l){
    dft5<SGN>(y);
    float2 w1 = twid<SGN>((float)l * (1.f/160.f));
    float2 w2 = cxmul(w1,w1);
    float2 w3 = cxmul(w2,w1);
    float2 w4 = cxmul(w2,w2);
    y[1]=cxmul(y[1],w1); y[2]=cxmul(y[2],w2); y[3]=cxmul(y[3],w3); y[4]=cxmul(y[4],w4);
    float2 tw16 = twid<SGN>((float)(l & 15) * (1.f/32.f));
    float2 tw8  = twid<SGN>((float)(l & 7)  * (1.f/16.f));
    float2 tw4  = twid<SGN>((float)(l & 3)  * (1.f/8.f));
    float2 tw2  = twid<SGN>((float)(l & 1)  * (1.f/4.f));
    #pragma unroll
    for (int k=0;k<5;k++){
        float2 v = y[k];
        v = bfly(v,16,tw16,l);
        v = bfly(v, 8,tw8 ,l);
        v = bfly(v, 4,tw4 ,l);
        v = bfly(v, 2,tw2 ,l);
        float2 o = shfl2(v,1);
        v = (l&1) ? csub(o,v) : cadd(v,o);
        y[k] = v;
    }
}

struct RPc {
    float2* C[3];
    const float* M[3];
};

// analytic kernel ingredients: Q sums over (dy,dz) ball slices, per column
struct QCol {
    float Q1_0, Q1_1;
    float Q2_0, Q2_1, Q2_2;
    float Q3_0, Q3_1, Q3_2, Q3_3;
    float fz2;
};

__device__ __forceinline__ QCol make_qcol(float ay0,float ay1,float ay2,float ay3, int kz){
    float fz = (float)kz * (1.f/160.f);
    float cz1 = fcos_rev(fz);
    float cz2 = 2.f*cz1*cz1 - 1.f;
    float cz3 = 2.f*cz1*cz2 - cz1;
    float az0=1.f, az1=2.f*cz1, az2=2.f*cz2, az3=2.f*cz3;
    float P00=ay0*az0, P01=ay0*az1, P02=ay0*az2, P03=ay0*az3;
    float P10=ay1*az0, P11=ay1*az1, P12=ay1*az2;
    float P20=ay2*az0, P21=ay2*az1, P22=ay2*az2;
    float P30=ay3*az0;
    QCol q;
    q.Q1_0 = P00 + P01 + P10;
    q.Q1_1 = P00;
    q.Q2_0 = P00+P01+P02+P10+P11+P20;
    q.Q2_1 = P00+P01+P10+P11;
    q.Q2_2 = P00;
    q.Q3_0 = P00+P01+P02+P03+P10+P11+P12+P20+P21+P22+P30;
    q.Q3_1 = P00+P01+P02+P10+P11+P12+P20+P21+P22;
    q.Q3_2 = P00+P01+P02+P10+P11+P12+P20+P21;
    q.Q3_3 = P00;
    q.fz2 = fz*fz;
    return q;
}

// K_r for slot: kx in [0,160)
template<int R>
__device__ __forceinline__ float kval(const QCol& q, float fy2, int kx){
    float c1 = fcos_rev((float)kx * (1.f/160.f));
    float s;
    if (R == 0){
        s = (q.Q1_0 + 2.f*c1*q.Q1_1) * (1.f/7.f);
    } else if (R == 1){
        float c2 = 2.f*c1*c1 - 1.f;
        s = (q.Q2_0 + 2.f*(c1*q.Q2_1 + c2*q.Q2_2)) * (1.f/33.f);
    } else {
        float c2 = 2.f*c1*c1 - 1.f;
        float c3 = 2.f*c1*c2 - c1;
        s = (q.Q3_0 + 2.f*(c1*q.Q3_1 + c2*q.Q3_2 + c3*q.Q3_3)) * (1.f/123.f);
    }
    float fxw = (float)((kx < 80) ? kx : 160 - kx) * (1.f/160.f);
    float k2 = fxw*fxw + fy2 + q.fz2;
    float D = (1.f/3.f) - ((k2 == 0.f) ? 0.f : q.fz2 * __builtin_amdgcn_rcpf(k2));
    return (1.f - s) * D;
}

__device__ __forceinline__ float kval_r(int r, const QCol& q, float fy2, int kx){
    if (r == 0) return kval<0>(q, fy2, kx);
    if (r == 1) return kval<1>(q, fy2, kx);
    return kval<2>(q, fy2, kx);
}

// ---------------- CG reduction helper ----------------
__device__ __forceinline__ void block_atomic_add(double v, double* target){
    #pragma unroll
    for (int off=32; off>0; off>>=1) v += __shfl_down(v, off, 64);
    __shared__ double sm[4];
    int wv = threadIdx.x >> 6;
    if ((threadIdx.x & 63) == 0) sm[wv] = v;
    __syncthreads();
    if (threadIdx.x == 0) atomicAdd(target, sm[0]+sm[1]+sm[2]+sm[3]);
}

// ======== z-axis kernels: wave-local, barrier-free ========
// Each 32-lane group owns one PAIR of z-lines (packed two-for-one FFT) and a
// private 162-float2 LDS region. No __syncthreads anywhere in the FFT path:
// within-wave LDS ordering (in-order LDS FIFO) is the only sync needed.

// PM=0: fft real zin. PM=1: p = r + beta*p (beta=S[3]), store p, fft p.
template<int PM>
__global__ __launch_bounds__(256) void fft_z_first(const float* __restrict__ zin,
    const float* __restrict__ rrv, float* __restrict__ ppv,
    float2* __restrict__ out, const double* __restrict__ S)
{
    __shared__ float2 ldsC[8*162];
    int tid = threadIdx.x, l = tid & 31, g = tid >> 5;
    int fl = g*162;
    size_t base160 = (size_t)blockIdx.x * 2560 + (size_t)(2*g)*160;
    size_t baseC   = (size_t)blockIdx.x * 1296 + (size_t)g*162;
    float beta = PM ? (float)S[3] : 0.f;
    // direct stride-32 coalesced loads of the group's two lines
    float2 y[5];
    #pragma unroll
    for (int n1=0;n1<5;n1++){
        int n = n1*32 + l;
        float a, b;
        if (PM){
            a = rrv[base160 + n]       + beta * ppv[base160 + n];
            b = rrv[base160 + 160 + n] + beta * ppv[base160 + 160 + n];
            ppv[base160 + n] = a;
            ppv[base160 + 160 + n] = b;
        } else {
            a = zin[base160 + n];
            b = zin[base160 + 160 + n];
        }
        y[n1] = make_float2(a, b);
    }
    linefft<1>(y, l);
    int o5 = 5*br5(l);
    #pragma unroll
    for (int k=0;k<5;k++) ldsC[fl + o5 + k] = y[k];
    // Hermitian split A/B within own region (in-wave), coalesced store
    #pragma unroll
    for (int t=0;t<6;t++){
        int j = l + 32*t;
        if (j < 162){
            int k = (j < 81) ? j : j - 81;
            float2 Sk = ldsC[fl + k];
            float2 Sm = ldsC[fl + ((160 - k) % 160)];
            float2 o = (j >= 81)
                ? make_float2(0.5f*(Sk.y + Sm.y), -0.5f*(Sk.x - Sm.x))    // B
                : make_float2(0.5f*(Sk.x + Sm.x),  0.5f*(Sk.y - Sm.y));   // A
            out[baseC + j] = o;
        }
    }
}

// fused: inverse-z (Hermitian reconstruct, packed pair) -> *m2w_r -> forward-z
template<bool PRE>
__global__ __launch_bounds__(256) void fft_z_mid3(RPc P, const float* __restrict__ mask,
                                                 const float* __restrict__ wfull)
{
    __shared__ float2 ldsC[8*162];
    int r = blockIdx.y;
    float2* C = P.C[r];
    int tid = threadIdx.x, l = tid & 31, g = tid >> 5;
    int fl = g*162;
    size_t baseC   = (size_t)blockIdx.x * 1296 + (size_t)g*162;
    size_t base160 = (size_t)blockIdx.x * 2560 + (size_t)(2*g)*160;
    int o5 = 5*br5(l);
    // early direct loads of m^2*w at the permuted slots (hide under FFT)
    float ma[5], mb[5];
    if (PRE){
        const float* M = P.M[r];
        #pragma unroll
        for (int k=0;k<5;k++){
            ma[k] = M[base160 + o5 + k];
            mb[k] = M[base160 + 160 + o5 + k];
        }
    } else {
        #pragma unroll
        for (int k=0;k<5;k++){
            size_t ia = base160 + o5 + k, ib = base160 + 160 + o5 + k;
            float m1 = mask[ia], m2 = mask[ib];
            ma[k] = m1*m1*wfull[ia*3 + r];
            mb[k] = m2*m2*wfull[ib*3 + r];
        }
    }
    // load own packed region (coalesced)
    #pragma unroll
    for (int t=0;t<6;t++){
        int j = l + 32*t;
        if (j < 162) ldsC[fl + j] = C[baseC + j];
    }
    // Hermitian reconstruct of packed pair spectrum
    float2 y[5];
    #pragma unroll
    for (int n1=0;n1<5;n1++){
        int e = n1*32 + l;
        float2 X;
        if (e <= 80){
            float2 A = ldsC[fl + e], B = ldsC[fl + 81 + e];
            X = make_float2(A.x - B.y, A.y + B.x);
        } else {
            int m = 160 - e;
            float2 A = ldsC[fl + m], B = ldsC[fl + 81 + m];
            X = make_float2(A.x + B.y, B.x - A.y);
        }
        y[n1] = X;
    }
    linefft<-1>(y, l);
    const float SC = 1.f/160.f;
    #pragma unroll
    for (int k=0;k<5;k++){
        float a = y[k].x * SC * ma[k];
        float b = y[k].y * SC * mb[k];
        ldsC[fl + o5 + k] = make_float2(a, b);   // packed s' (in-wave exchange)
    }
    #pragma unroll
    for (int n1=0;n1<5;n1++) y[n1] = ldsC[fl + n1*32 + l];
    linefft<1>(y, l);
    #pragma unroll
    for (int k=0;k<5;k++) ldsC[fl + o5 + k] = y[k];
    // Hermitian split + coalesced store
    #pragma unroll
    for (int t=0;t<6;t++){
        int j = l + 32*t;
        if (j < 162){
            int k = (j < 81) ? j : j - 81;
            float2 Sk = ldsC[fl + k];
            float2 Sm = ldsC[fl + ((160 - k) % 160)];
            float2 o = (j >= 81)
                ? make_float2(0.5f*(Sk.y + Sm.y), -0.5f*(Sk.x - Sm.x))
                : make_float2(0.5f*(Sk.x + Sm.x),  0.5f*(Sk.y - Sm.y));
            C[baseC + j] = o;
        }
    }
}

// final inverse-z + epilogue. FIN=0: Ap=v, S[1]+=<z,v>. FIN=1: r=b-v -> rr,pp, S[0]+=<r,r>.
template<int FIN>
__global__ __launch_bounds__(256) void fft_z_fin(const float2* __restrict__ in,
    const float* __restrict__ zsp, float* __restrict__ Ap,
    const float* __restrict__ bb, float* __restrict__ rrv, float* __restrict__ ppv,
    double* __restrict__ S)
{
    __shared__ float2 ldsC[8*162];
    float* ldsF = (float*)ldsC;      // region g: floats [324g, 324g+320)
    int tid = threadIdx.x, l = tid & 31, g = tid >> 5;
    int fl = g*162;
    size_t baseC   = (size_t)blockIdx.x * 1296 + (size_t)g*162;
    size_t base160 = (size_t)blockIdx.x * 2560 + (size_t)(2*g)*160;
    int o5 = 5*br5(l);
    // early direct loads (hide under LDS load + FFT)
    float za[5], zb[5], pa[5], pb[5];
    #pragma unroll
    for (int k=0;k<5;k++){
        za[k] = zsp[base160 + o5 + k];
        zb[k] = zsp[base160 + 160 + o5 + k];
        if (FIN){
            pa[k] = bb[base160 + o5 + k];
            pb[k] = bb[base160 + 160 + o5 + k];
        }
    }
    #pragma unroll
    for (int t=0;t<6;t++){
        int j = l + 32*t;
        if (j < 162) ldsC[fl + j] = in[baseC + j];
    }
    float2 y[5];
    #pragma unroll
    for (int n1=0;n1<5;n1++){
        int e = n1*32 + l;
        float2 X;
        if (e <= 80){
            float2 A = ldsC[fl + e], B = ldsC[fl + 81 + e];
            X = make_float2(A.x - B.y, A.y + B.x);
        } else {
            int m = 160 - e;
            float2 A = ldsC[fl + m], B = ldsC[fl + 81 + m];
            X = make_float2(A.x + B.y, B.x - A.y);
        }
        y[n1] = X;
    }
    linefft<-1>(y, l);
    const float SC = 1.f/160.f;
    double acc = 0.0;
    int fb = g*324;
    #pragma unroll
    for (int k=0;k<5;k++){
        float va = LAM_F*za[k] + y[k].x*SC;
        float vb = LAM_F*zb[k] + y[k].y*SC;
        if (FIN == 0){
            acc += (double)za[k]*(double)va + (double)zb[k]*(double)vb;
            ldsF[fb + o5 + k] = va;
            ldsF[fb + 160 + o5 + k] = vb;
        } else {
            float ra = pa[k] - va, rb = pb[k] - vb;
            acc += (double)ra*(double)ra + (double)rb*(double)rb;
            ldsF[fb + o5 + k] = ra;
            ldsF[fb + 160 + o5 + k] = rb;
        }
    }
    // coalesced store of own 320 floats (in-wave)
    #pragma unroll
    for (int t=0;t<10;t++){
        int n = l + 32*t;
        float v = ldsF[fb + n];
        if (FIN == 0){
            Ap[base160 + n] = v;
        } else {
            rrv[base160 + n] = v;
            ppv[base160 + n] = v;
        }
    }
    block_atomic_add(acc, FIN ? &S[0] : &S[1]);
}

// ---------------- y-axis sweeps (strided, guarded half-spectrum, W=8) ----------------
template<int SGN>
__device__ __forceinline__ void ycompute(float2 (*tile)[WZ+1], int tid){
    int l = tid & 31, q = tid >> 5;
    const float SC = (SGN>0) ? 1.f : (1.f/160.f);
    float2 y[5];
    #pragma unroll
    for (int n1=0;n1<5;n1++) y[n1] = tile[l + 32*n1][q];
    linefft<SGN>(y, l);
    int o5 = 5*br5(l);
    #pragma unroll
    for (int k=0;k<5;k++) tile[o5+k][q] = cscale(y[k], SC);
}

// b = zchunk*160 + ix  (zb-outer so line-sharing blocks b, b+160 share an XCD)
template<int SGN>
__global__ __launch_bounds__(256) void fft_y1(float2* __restrict__ data)
{
    __shared__ float2 tile[NN][WZ+1];
    int b = blockIdx.x;
    int ix = b % 160, zb = (b / 160) * WZ;
    size_t tbase = (size_t)ix*XS + zb;
    int tid = threadIdx.x;
    for (int i = tid; i < NN*WZ; i += 256){
        int row = i >> 3, zi = i & 7;
        tile[row][zi] = (zb + zi < KP) ? data[tbase + (size_t)row*KP + zi] : make_float2(0.f,0.f);
    }
    __syncthreads();
    ycompute<SGN>(tile, tid);
    __syncthreads();
    for (int i = tid; i < NN*WZ; i += 256){
        int row = i >> 3, zi = i & 7;
        if (zb + zi < KP) data[tbase + (size_t)row*KP + zi] = tile[row][zi];
    }
}

template<int SGN>
__global__ __launch_bounds__(256) void fft_y3(RPc P)
{
    __shared__ float2 tile[NN][WZ+1];
    float2* data = P.C[blockIdx.y];
    int b = blockIdx.x;
    int ix = b % 160, zb = (b / 160) * WZ;
    size_t tbase = (size_t)ix*XS + zb;
    int tid = threadIdx.x;
    for (int i = tid; i < NN*WZ; i += 256){
        int row = i >> 3, zi = i & 7;
        tile[row][zi] = (zb + zi < KP) ? data[tbase + (size_t)row*KP + zi] : make_float2(0.f,0.f);
    }
    __syncthreads();
    ycompute<SGN>(tile, tid);
    __syncthreads();
    for (int i = tid; i < NN*WZ; i += 256){
        int row = i >> 3, zi = i & 7;
        if (zb + zi < KP) data[tbase + (size_t)row*KP + zi] = tile[row][zi];
    }
}

// ---------------- x-axis kernels with analytic K (batched over r) ----------------
__global__ __launch_bounds__(256) void fft_xK(RPc P, const float2* __restrict__ in)
{
    __shared__ float2 tile[NN][WZ+1];
    int r = blockIdx.y;
    int b = blockIdx.x;
    int iy = b % 160, zb = (b / 160) * WZ;
    size_t tbase = (size_t)iy*KP + zb;
    int tid = threadIdx.x, l = tid & 31, q = tid >> 5;
    for (int i = tid; i < NN*WZ; i += 256){
        int row = i >> 3, zi = i & 7;
        tile[row][zi] = (zb + zi < KP) ? in[tbase + (size_t)row*XS + zi] : make_float2(0.f,0.f);
    }
    __syncthreads();
    float fy = (float)((iy < 80) ? iy : iy - 160) * (1.f/160.f);
    float fy2 = fy*fy;
    float cy1 = fcos_rev(fy);
    float cy2 = 2.f*cy1*cy1 - 1.f;
    float cy3 = 2.f*cy1*cy2 - cy1;
    QCol qc = make_qcol(1.f, 2.f*cy1, 2.f*cy2, 2.f*cy3, zb + q);
    float2 y[5];
    #pragma unroll
    for (int n1=0;n1<5;n1++) y[n1] = tile[n1*32 + l][q];
    linefft<1>(y, l);
    int o5 = 5*br5(l);
    #pragma unroll
    for (int k=0;k<5;k++) tile[o5+k][q] = cscale(y[k], kval_r(r, qc, fy2, o5+k));
    #pragma unroll
    for (int n1=0;n1<5;n1++) y[n1] = tile[n1*32 + l][q];
    linefft<-1>(y, l);
    #pragma unroll
    for (int k=0;k<5;k++) tile[o5+k][q] = cscale(y[k], 1.f/160.f);
    __syncthreads();
    float2* Cr = P.C[r];
    for (int i = tid; i < NN*WZ; i += 256){
        int row = i >> 3, zi = i & 7;
        if (zb + zi < KP) Cr[tbase + (size_t)row*XS + zi] = tile[row][zi];
    }
}

// in-place: C_r = K_r * fwdx(C_r)   (natural kx order)
__global__ __launch_bounds__(256) void fft_xfwdK(RPc P)
{
    __shared__ float2 tile[NN][WZ+1];
    int r = blockIdx.y;
    int b = blockIdx.x;
    int iy = b % 160, zb = (b / 160) * WZ;
    size_t tbase = (size_t)iy*KP + zb;
    int tid = threadIdx.x, l = tid & 31, q = tid >> 5;
    float2* Cr = P.C[r];
    for (int i = tid; i < NN*WZ; i += 256){
        int row = i >> 3, zi = i & 7;
        tile[row][zi] = (zb + zi < KP) ? Cr[tbase + (size_t)row*XS + zi] : make_float2(0.f,0.f);
    }
    __syncthreads();
    float fy = (float)((iy < 80) ? iy : iy - 160) * (1.f/160.f);
    float fy2 = fy*fy;
    float cy1 = fcos_rev(fy);
    float cy2 = 2.f*cy1*cy1 - 1.f;
    float cy3 = 2.f*cy1*cy2 - cy1;
    QCol qc = make_qcol(1.f, 2.f*cy1, 2.f*cy2, 2.f*cy3, zb + q);
    float2 y[5];
    #pragma unroll
    for (int n1=0;n1<5;n1++) y[n1] = tile[n1*32 + l][q];
    linefft<1>(y, l);
    int o5 = 5*br5(l);
    #pragma unroll
    for (int k=0;k<5;k++) tile[o5+k][q] = cscale(y[k], kval_r(r, qc, fy2, o5+k));
    __syncthreads();
    for (int i = tid; i < NN*WZ; i += 256){
        int row = i >> 3, zi = i & 7;
        if (zb + zi < KP) Cr[tbase + (size_t)row*XS + zi] = tile[row][zi];
    }
}

// CF = invx( C0 + C1 + C2 )
__global__ __launch_bounds__(256) void fft_xsuminv(RPc P, float2* __restrict__ out)
{
    __shared__ float2 tile[NN][WZ+1];
    int b = blockIdx.x;
    int iy = b % 160, zb = (b / 160) * WZ;
    size_t tbase = (size_t)iy*KP + zb;
    int tid = threadIdx.x, l = tid & 31, q = tid >> 5;
    for (int i = tid; i < NN*WZ; i += 256){
        int row = i >> 3, zi = i & 7;
        float2 v = make_float2(0.f,0.f);
        if (zb + zi < KP){
            size_t gidx = tbase + (size_t)row*XS + zi;
            v = cadd(cadd(P.C[0][gidx], P.C[1][gidx]), P.C[2][gidx]);
        }
        tile[row][zi] = v;
    }
    __syncthreads();
    float2 y[5];
    #pragma unroll
    for (int n1=0;n1<5;n1++) y[n1] = tile[n1*32 + l][q];
    linefft<-1>(y, l);
    int o5 = 5*br5(l);
    #pragma unroll
    for (int k=0;k<5;k++) tile[o5+k][q] = cscale(y[k], 1.f/160.f);
    __syncthreads();
    for (int i = tid; i < NN*WZ; i += 256){
        int row = i >> 3, zi = i & 7;
        if (zb + zi < KP) out[tbase + (size_t)row*XS + zi] = tile[row][zi];
    }
}

// ---------------- setup / CG vector ops ----------------
__global__ __launch_bounds__(256) void m2w_kernel(const float* __restrict__ mask,
        const float* __restrict__ w, float* __restrict__ M0,
        float* __restrict__ M1, float* __restrict__ M2)
{
    int i = blockIdx.x*256 + threadIdx.x;
    float m = mask[i]; float mm = m*m;
    M0[i] = mm * w[3*(size_t)i+0];
    M1[i] = mm * w[3*(size_t)i+1];
    M2[i] = mm * w[3*(size_t)i+2];
}

__global__ __launch_bounds__(256) void copy_kernel(const float* __restrict__ a, float* __restrict__ b){
    int i = blockIdx.x*256 + threadIdx.x;
    b[i] = a[i];
}

#define GSTRIDE (2048*256)
__global__ __launch_bounds__(256) void upd1_kernel(float* __restrict__ x, float* __restrict__ r,
        const float* __restrict__ p, const float* __restrict__ Ap, double* s)
{
    float alpha = (float)(s[0] / (s[1] + 1e-12));
    double acc = 0.0;
    for (int i = blockIdx.x*256 + threadIdx.x; i < N3; i += GSTRIDE){
        x[i] += alpha * p[i];
        float rn = r[i] - alpha * Ap[i];
        r[i] = rn;
        acc += (double)rn * (double)rn;
    }
    block_atomic_add(acc, &s[2]);
}
__global__ void advance_kernel(double* s){
    if (threadIdx.x == 0){
        s[3] = s[2] / (s[0] + 1e-12);   // beta
        s[0] = s[2]; s[1] = 0.0; s[2] = 0.0;
    }
}
__global__ void zero_kernel(double* s){
    if (threadIdx.x < 4) s[threadIdx.x] = 0.0;
}

// ---------------- host orchestration ----------------
extern "C" void kernel_launch(void* const* d_in, const int* in_sizes, int n_in,
                              void* d_out, int out_size, void* d_ws, size_t ws_size,
                              hipStream_t stream)
{
    (void)in_sizes; (void)n_in; (void)out_size;
    const float* w    = (const float*)d_in[0];   // [N3*3], R fastest
    const float* x2   = (const float*)d_in[1];   // [N3]
    const float* mask = (const float*)d_in[2];   // [N3]
    const float* bb   = (const float*)d_in[3];   // [N3]
    float* x = (float*)d_out;
    char* ws = (char*)d_ws;

    size_t off = 0;
    auto alloc = [&](size_t bytes)->void*{
        void* pp = ws + off;
        off += (bytes + 255) & ~(size_t)255;
        return pp;
    };
    const size_t CB = (size_t)NLINES * KP * sizeof(float2);   // 16.6 MB
    float2* CF = (float2*)alloc(CB);
    float2* C0 = (float2*)alloc(CB);
    float2* C1 = (float2*)alloc(CB);
    float2* C2 = (float2*)alloc(CB);
    float*  rr = (float*) alloc((size_t)N3*4);
    float*  pp = (float*) alloc((size_t)N3*4);
    double* S  = (double*)alloc(64);
    float*  Ap = (float*)C0;      // alias: C0 dead when Ap produced/consumed
    bool PRE = (ws_size >= off + 3*(((size_t)N3*4 + 255) & ~(size_t)255));
    float *M0=nullptr, *M1=nullptr, *M2=nullptr;
    if (PRE){
        M0 = (float*)alloc((size_t)N3*4);
        M1 = (float*)alloc((size_t)N3*4);
        M2 = (float*)alloc((size_t)N3*4);
    }
    RPc P;
    P.C[0]=C0; P.C[1]=C1; P.C[2]=C2;
    P.M[0]=M0; P.M[1]=M1; P.M[2]=M2;

    zero_kernel<<<1, 64, 0, stream>>>(S);
    if (PRE) m2w_kernel<<<16000, 256, 0, stream>>>(mask, w, M0, M1, M2);
    copy_kernel<<<16000, 256, 0, stream>>>(x2, x);

    const int GY = NBZ * 160;    // 1760
    // PM: 0 = plain fft of z; 1 = fused p-update. FIN: 1 = initial residual, 0 = CG iter.
    auto applyM = [&](const float* z, int FIN, int PM){
        if (PM) fft_z_first<1><<<1600, 256, 0, stream>>>(z, rr, pp, CF, S);
        else    fft_z_first<0><<<1600, 256, 0, stream>>>(z, rr, pp, CF, S);
        fft_y1<1><<<GY, 256, 0, stream>>>(CF);
        fft_xK<<<dim3(GY,3), 256, 0, stream>>>(P, CF);
        fft_y3<-1><<<dim3(GY,3), 256, 0, stream>>>(P);
        if (PRE) fft_z_mid3<true ><<<dim3(1600,3), 256, 0, stream>>>(P, mask, w);
        else     fft_z_mid3<false><<<dim3(1600,3), 256, 0, stream>>>(P, mask, w);
        fft_y3<1><<<dim3(GY,3), 256, 0, stream>>>(P);
        fft_xfwdK<<<dim3(GY,3), 256, 0, stream>>>(P);
        fft_xsuminv<<<GY, 256, 0, stream>>>(P, CF);
        fft_y1<-1><<<GY, 256, 0, stream>>>(CF);
        if (FIN) fft_z_fin<1><<<1600, 256, 0, stream>>>(CF, x, Ap, bb, rr, pp, S);
        else     fft_z_fin<0><<<1600, 256, 0, stream>>>(CF, pp, Ap, bb, rr, pp, S);
    };

    // r = b - M(x2); p = r; rs = <r,r>
    applyM(x, 1, 0);

    for (int it = 0; it < 10; it++){
        applyM(pp, 0, (it == 0) ? 0 : 1);          // Ap = M(p), S[1] = <p,Ap>
        upd1_kernel<<<2048, 256, 0, stream>>>(x, rr, pp, Ap, S);
        if (it < 9) advance_kernel<<<1, 64, 0, stream>>>(S);
    }
}

// Round 7
// 2833.425 us; speedup vs baseline: 3.0901x; 1.0539x over previous
//
#include <hip/hip_runtime.h>

#define NN 160
#define KP 81                // kept kz planes (Hermitian half)
#define N3 4096000           // 160^3
#define NLINES 25600         // 160^2 z-lines
#define WZ 8                 // tile width (kz columns) for x/y sweeps
#define NBZ 11               // ceil(81/8)
#define XS 12960             // x-stride in complex layout (160*81)
#define TPI 6.28318530717958647692f
#define LAM_F 0.05f

// ---------------- complex helpers ----------------
__device__ __forceinline__ float2 cxmul(float2 a, float2 b){
    return make_float2(a.x*b.x - a.y*b.y, a.x*b.y + a.y*b.x);
}
__device__ __forceinline__ float2 cadd(float2 a, float2 b){ return make_float2(a.x+b.x, a.y+b.y); }
__device__ __forceinline__ float2 csub(float2 a, float2 b){ return make_float2(a.x-b.x, a.y-b.y); }
__device__ __forceinline__ float2 cscale(float2 a, float s){ return make_float2(a.x*s, a.y*s); }
__device__ __forceinline__ float2 shfl2(float2 v, int m){
    return make_float2(__shfl_xor(v.x, m, 64), __shfl_xor(v.y, m, 64));
}
__device__ __forceinline__ int br5(int l){
    return ((l&1)<<4)|((l&2)<<2)|(l&4)|((l&8)>>2)|((l&16)>>4);
}
// rev in revolutions (angle/2pi). v_sin_f32/v_cos_f32 are revolution-input
// on gfx950 -> 1 instr each, no range reduction needed.
__device__ __forceinline__ float fsin_rev(float rev){ return __builtin_amdgcn_sinf(rev); }
__device__ __forceinline__ float fcos_rev(float rev){ return __builtin_amdgcn_cosf(rev); }
template<int SGN>
__device__ __forceinline__ float2 twid(float rev){
    float s = fsin_rev(rev), c = fcos_rev(rev);
    return make_float2(c, (SGN>0) ? -s : s);
}

// ---------------- radix-5 DFT ----------------
template<int SGN>
__device__ __forceinline__ void dft5(float2 y[5]){
    const float C1 = 0.30901699437494742f;
    const float C2 = -0.80901699437494742f;
    const float S1 = 0.95105651629515357f;
    const float S2 = 0.58778525229247312f;
    float2 x0=y[0], x1=y[1], x2=y[2], x3=y[3], x4=y[4];
    float2 t1=cadd(x1,x4), t2=cadd(x2,x3), t3=csub(x1,x4), t4=csub(x2,x3);
    y[0] = cadd(x0, cadd(t1,t2));
    float2 a1 = make_float2(x0.x + C1*t1.x + C2*t2.x, x0.y + C1*t1.y + C2*t2.y);
    float2 a2 = make_float2(x0.x + C2*t1.x + C1*t2.x, x0.y + C2*t1.y + C1*t2.y);
    const float sg = (SGN>0) ? 1.f : -1.f;
    float2 b1 = make_float2(sg*(S1*t3.x + S2*t4.x), sg*(S1*t3.y + S2*t4.y));
    float2 b2 = make_float2(sg*(S2*t3.x - S1*t4.x), sg*(S2*t3.y - S1*t4.y));
    y[1] = make_float2(a1.x + b1.y, a1.y - b1.x);
    y[4] = make_float2(a1.x - b1.y, a1.y + b1.x);
    y[2] = make_float2(a2.x + b2.y, a2.y - b2.x);
    y[3] = make_float2(a2.x - b2.y, a2.y + b2.x);
}

__device__ __forceinline__ float2 bfly(float2 v, int m, float2 tw, int l){
    float2 o = shfl2(v, m);
    float2 s = cadd(v, o);
    float2 d = cxmul(csub(o, v), tw);
    return (l & m) ? d : s;
}

// 160-pt FFT: lane l in [0,32) holds y[n1]=x[n1*32+l] on entry.
// On exit, slot k holds X[k + 5*br5(l)].
template<int SGN>
__device__ __forceinline__ void linefft(float2 y[5], int l){
    dft5<SGN>(y);
    float2 w1 = twid<SGN>((float)l * (1.f/160.f));
    float2 w2 = cxmul(w1,w1);
    float2 w3 = cxmul(w2,w1);
    float2 w4 = cxmul(w2,w2);
    y[1]=cxmul(y[1],w1); y[2]=cxmul(y[2],w2); y[3]=cxmul(y[3],w3); y[4]=cxmul(y[4],w4);
    float2 tw16 = twid<SGN>((float)(l & 15) * (1.f/32.f));
    float2 tw8  = twid<SGN>((float)(l & 7)  * (1.f/16.f));
    float2 tw4  = twid<SGN>((float)(l & 3)  * (1.f/8.f));
    float2 tw2  = twid<SGN>((float)(l & 1)  * (1.f/4.f));
    #pragma unroll
    for (int k=0;k<5;k++){
        float2 v = y[k];
        v = bfly(v,16,tw16,l);
        v = bfly(v, 8,tw8 ,l);
        v = bfly(v, 4,tw4 ,l);
        v = bfly(v, 2,tw2 ,l);
        float2 o = shfl2(v,1);
        v = (l&1) ? csub(o,v) : cadd(v,o);
        y[k] = v;
    }
}

// DIT butterfly: low lane: v + tw*o ; high lane: o - tw*v
__device__ __forceinline__ float2 bflyi(float2 v, int m, float2 tw, int l){
    float2 o = shfl2(v, m);
    float2 t = cxmul(tw, (l & m) ? v : o);
    return (l & m) ? csub(o, t) : cadd(v, t);
}

// inverse 160-pt FFT consuming the forward's permuted register layout:
// entry: slot k lane l = X[k + 5*br5(l)]; exit: y[n1] = x[n1*32+l] (UNscaled).
// Mirror network: DIT 32-IFFT (bit-reversed input -> natural), conj lane
// twiddle, inverse dft5.
__device__ __forceinline__ void ilinefft_perm(float2 y[5], int l){
    float2 tw2  = twid<-1>((float)(l & 1)  * (1.f/4.f));
    float2 tw4  = twid<-1>((float)(l & 3)  * (1.f/8.f));
    float2 tw8  = twid<-1>((float)(l & 7)  * (1.f/16.f));
    float2 tw16 = twid<-1>((float)(l & 15) * (1.f/32.f));
    #pragma unroll
    for (int k=0;k<5;k++){
        float2 v = y[k];
        { float2 o = shfl2(v,1); v = (l&1) ? csub(o,v) : cadd(v,o); }
        v = bflyi(v, 2, tw2 , l);
        v = bflyi(v, 4, tw4 , l);
        v = bflyi(v, 8, tw8 , l);
        v = bflyi(v,16, tw16, l);
        y[k] = v;
    }
    float2 w1 = twid<-1>((float)l * (1.f/160.f));
    float2 w2 = cxmul(w1,w1);
    float2 w3 = cxmul(w2,w1);
    float2 w4 = cxmul(w2,w2);
    y[1]=cxmul(y[1],w1); y[2]=cxmul(y[2],w2); y[3]=cxmul(y[3],w3); y[4]=cxmul(y[4],w4);
    dft5<-1>(y);
}

struct RPc {
    float2* C[3];
    const float* M[3];
};

// analytic kernel ingredients: Q sums over (dy,dz) ball slices, per column
struct QCol {
    float Q1_0, Q1_1;
    float Q2_0, Q2_1, Q2_2;
    float Q3_0, Q3_1, Q3_2, Q3_3;
    float fz2;
};

__device__ __forceinline__ QCol make_qcol(float ay0,float ay1,float ay2,float ay3, int kz){
    float fz = (float)kz * (1.f/160.f);
    float cz1 = fcos_rev(fz);
    float cz2 = 2.f*cz1*cz1 - 1.f;
    float cz3 = 2.f*cz1*cz2 - cz1;
    float az0=1.f, az1=2.f*cz1, az2=2.f*cz2, az3=2.f*cz3;
    float P00=ay0*az0, P01=ay0*az1, P02=ay0*az2, P03=ay0*az3;
    float P10=ay1*az0, P11=ay1*az1, P12=ay1*az2;
    float P20=ay2*az0, P21=ay2*az1, P22=ay2*az2;
    float P30=ay3*az0;
    QCol q;
    q.Q1_0 = P00 + P01 + P10;
    q.Q1_1 = P00;
    q.Q2_0 = P00+P01+P02+P10+P11+P20;
    q.Q2_1 = P00+P01+P10+P11;
    q.Q2_2 = P00;
    q.Q3_0 = P00+P01+P02+P03+P10+P11+P12+P20+P21+P22+P30;
    q.Q3_1 = P00+P01+P02+P10+P11+P12+P20+P21+P22;
    q.Q3_2 = P00+P01+P02+P10+P11+P12+P20+P21;
    q.Q3_3 = P00;
    q.fz2 = fz*fz;
    return q;
}

// K_r for slot: kx in [0,160)
template<int R>
__device__ __forceinline__ float kval(const QCol& q, float fy2, int kx){
    float c1 = fcos_rev((float)kx * (1.f/160.f));
    float s;
    if (R == 0){
        s = (q.Q1_0 + 2.f*c1*q.Q1_1) * (1.f/7.f);
    } else if (R == 1){
        float c2 = 2.f*c1*c1 - 1.f;
        s = (q.Q2_0 + 2.f*(c1*q.Q2_1 + c2*q.Q2_2)) * (1.f/33.f);
    } else {
        float c2 = 2.f*c1*c1 - 1.f;
        float c3 = 2.f*c1*c2 - c1;
        s = (q.Q3_0 + 2.f*(c1*q.Q3_1 + c2*q.Q3_2 + c3*q.Q3_3)) * (1.f/123.f);
    }
    float fxw = (float)((kx < 80) ? kx : 160 - kx) * (1.f/160.f);
    float k2 = fxw*fxw + fy2 + q.fz2;
    float D = (1.f/3.f) - ((k2 == 0.f) ? 0.f : q.fz2 * __builtin_amdgcn_rcpf(k2));
    return (1.f - s) * D;
}

__device__ __forceinline__ float kval_r(int r, const QCol& q, float fy2, int kx){
    if (r == 0) return kval<0>(q, fy2, kx);
    if (r == 1) return kval<1>(q, fy2, kx);
    return kval<2>(q, fy2, kx);
}

// ---------------- CG reduction helper ----------------
__device__ __forceinline__ void block_atomic_add(double v, double* target){
    #pragma unroll
    for (int off=32; off>0; off>>=1) v += __shfl_down(v, off, 64);
    __shared__ double sm[4];
    int wv = threadIdx.x >> 6;
    if ((threadIdx.x & 63) == 0) sm[wv] = v;
    __syncthreads();
    if (threadIdx.x == 0) atomicAdd(target, sm[0]+sm[1]+sm[2]+sm[3]);
}

// ======== z-axis kernels: wave-local, barrier-free ========
// PM=0: fft real zin. PM=1: p = r + beta*p (beta=S[3]), store p, fft p.
template<int PM>
__global__ __launch_bounds__(256) void fft_z_first(const float* __restrict__ zin,
    const float* __restrict__ rrv, float* __restrict__ ppv,
    float2* __restrict__ out, const double* __restrict__ S)
{
    __shared__ float2 ldsC[8*162];
    int tid = threadIdx.x, l = tid & 31, g = tid >> 5;
    int fl = g*162;
    size_t base160 = (size_t)blockIdx.x * 2560 + (size_t)(2*g)*160;
    size_t baseC   = (size_t)blockIdx.x * 1296 + (size_t)g*162;
    float beta = PM ? (float)S[3] : 0.f;
    float2 y[5];
    #pragma unroll
    for (int n1=0;n1<5;n1++){
        int n = n1*32 + l;
        float a, b;
        if (PM){
            a = rrv[base160 + n]       + beta * ppv[base160 + n];
            b = rrv[base160 + 160 + n] + beta * ppv[base160 + 160 + n];
            ppv[base160 + n] = a;
            ppv[base160 + 160 + n] = b;
        } else {
            a = zin[base160 + n];
            b = zin[base160 + 160 + n];
        }
        y[n1] = make_float2(a, b);
    }
    linefft<1>(y, l);
    int o5 = 5*br5(l);
    #pragma unroll
    for (int k=0;k<5;k++) ldsC[fl + o5 + k] = y[k];
    #pragma unroll
    for (int t=0;t<6;t++){
        int j = l + 32*t;
        if (j < 162){
            int k = (j < 81) ? j : j - 81;
            float2 Sk = ldsC[fl + k];
            float2 Sm = ldsC[fl + ((160 - k) % 160)];
            float2 o = (j >= 81)
                ? make_float2(0.5f*(Sk.y + Sm.y), -0.5f*(Sk.x - Sm.x))    // B
                : make_float2(0.5f*(Sk.x + Sm.x),  0.5f*(Sk.y - Sm.y));   // A
            out[baseC + j] = o;
        }
    }
}

// fused: inverse-z (Hermitian reconstruct, packed pair) -> *m2w_r -> forward-z
template<bool PRE>
__global__ __launch_bounds__(256) void fft_z_mid3(RPc P, const float* __restrict__ mask,
                                                 const float* __restrict__ wfull)
{
    __shared__ float2 ldsC[8*162];
    int r = blockIdx.y;
    float2* C = P.C[r];
    int tid = threadIdx.x, l = tid & 31, g = tid >> 5;
    int fl = g*162;
    size_t baseC   = (size_t)blockIdx.x * 1296 + (size_t)g*162;
    size_t base160 = (size_t)blockIdx.x * 2560 + (size_t)(2*g)*160;
    int o5 = 5*br5(l);
    float ma[5], mb[5];
    if (PRE){
        const float* M = P.M[r];
        #pragma unroll
        for (int k=0;k<5;k++){
            ma[k] = M[base160 + o5 + k];
            mb[k] = M[base160 + 160 + o5 + k];
        }
    } else {
        #pragma unroll
        for (int k=0;k<5;k++){
            size_t ia = base160 + o5 + k, ib = base160 + 160 + o5 + k;
            float m1 = mask[ia], m2 = mask[ib];
            ma[k] = m1*m1*wfull[ia*3 + r];
            mb[k] = m2*m2*wfull[ib*3 + r];
        }
    }
    #pragma unroll
    for (int t=0;t<6;t++){
        int j = l + 32*t;
        if (j < 162) ldsC[fl + j] = C[baseC + j];
    }
    float2 y[5];
    #pragma unroll
    for (int n1=0;n1<5;n1++){
        int e = n1*32 + l;
        float2 X;
        if (e <= 80){
            float2 A = ldsC[fl + e], B = ldsC[fl + 81 + e];
            X = make_float2(A.x - B.y, A.y + B.x);
        } else {
            int m = 160 - e;
            float2 A = ldsC[fl + m], B = ldsC[fl + 81 + m];
            X = make_float2(A.x + B.y, B.x - A.y);
        }
        y[n1] = X;
    }
    linefft<-1>(y, l);
    const float SC = 1.f/160.f;
    #pragma unroll
    for (int k=0;k<5;k++){
        float a = y[k].x * SC * ma[k];
        float b = y[k].y * SC * mb[k];
        ldsC[fl + o5 + k] = make_float2(a, b);
    }
    #pragma unroll
    for (int n1=0;n1<5;n1++) y[n1] = ldsC[fl + n1*32 + l];
    linefft<1>(y, l);
    #pragma unroll
    for (int k=0;k<5;k++) ldsC[fl + o5 + k] = y[k];
    #pragma unroll
    for (int t=0;t<6;t++){
        int j = l + 32*t;
        if (j < 162){
            int k = (j < 81) ? j : j - 81;
            float2 Sk = ldsC[fl + k];
            float2 Sm = ldsC[fl + ((160 - k) % 160)];
            float2 o = (j >= 81)
                ? make_float2(0.5f*(Sk.y + Sm.y), -0.5f*(Sk.x - Sm.x))
                : make_float2(0.5f*(Sk.x + Sm.x),  0.5f*(Sk.y - Sm.y));
            C[baseC + j] = o;
        }
    }
}

// final inverse-z + epilogue. FIN=0: Ap=v, S[1]+=<z,v>. FIN=1: r=b-v -> rr,pp, S[0]+=<r,r>.
template<int FIN>
__global__ __launch_bounds__(256) void fft_z_fin(const float2* __restrict__ in,
    const float* __restrict__ zsp, float* __restrict__ Ap,
    const float* __restrict__ bb, float* __restrict__ rrv, float* __restrict__ ppv,
    double* __restrict__ S)
{
    __shared__ float2 ldsC[8*162];
    float* ldsF = (float*)ldsC;      // region g: floats [324g, 324g+320)
    int tid = threadIdx.x, l = tid & 31, g = tid >> 5;
    int fl = g*162;
    size_t baseC   = (size_t)blockIdx.x * 1296 + (size_t)g*162;
    size_t base160 = (size_t)blockIdx.x * 2560 + (size_t)(2*g)*160;
    int o5 = 5*br5(l);
    float za[5], zb[5], pa[5], pb[5];
    #pragma unroll
    for (int k=0;k<5;k++){
        za[k] = zsp[base160 + o5 + k];
        zb[k] = zsp[base160 + 160 + o5 + k];
        if (FIN){
            pa[k] = bb[base160 + o5 + k];
            pb[k] = bb[base160 + 160 + o5 + k];
        }
    }
    #pragma unroll
    for (int t=0;t<6;t++){
        int j = l + 32*t;
        if (j < 162) ldsC[fl + j] = in[baseC + j];
    }
    float2 y[5];
    #pragma unroll
    for (int n1=0;n1<5;n1++){
        int e = n1*32 + l;
        float2 X;
        if (e <= 80){
            float2 A = ldsC[fl + e], B = ldsC[fl + 81 + e];
            X = make_float2(A.x - B.y, A.y + B.x);
        } else {
            int m = 160 - e;
            float2 A = ldsC[fl + m], B = ldsC[fl + 81 + m];
            X = make_float2(A.x + B.y, B.x - A.y);
        }
        y[n1] = X;
    }
    linefft<-1>(y, l);
    const float SC = 1.f/160.f;
    double acc = 0.0;
    int fb = g*324;
    #pragma unroll
    for (int k=0;k<5;k++){
        float va = LAM_F*za[k] + y[k].x*SC;
        float vb = LAM_F*zb[k] + y[k].y*SC;
        if (FIN == 0){
            acc += (double)za[k]*(double)va + (double)zb[k]*(double)vb;
            ldsF[fb + o5 + k] = va;
            ldsF[fb + 160 + o5 + k] = vb;
        } else {
            float ra = pa[k] - va, rb = pb[k] - vb;
            acc += (double)ra*(double)ra + (double)rb*(double)rb;
            ldsF[fb + o5 + k] = ra;
            ldsF[fb + 160 + o5 + k] = rb;
        }
    }
    #pragma unroll
    for (int t=0;t<10;t++){
        int n = l + 32*t;
        float v = ldsF[fb + n];
        if (FIN == 0){
            Ap[base160 + n] = v;
        } else {
            rrv[base160 + n] = v;
            ppv[base160 + n] = v;
        }
    }
    block_atomic_add(acc, FIN ? &S[0] : &S[1]);
}

// ---------------- y-axis sweeps (strided, guarded half-spectrum, W=8) ----------------
template<int SGN>
__device__ __forceinline__ void ycompute(float2 (*tile)[WZ+1], int tid){
    int l = tid & 31, q = tid >> 5;
    const float SC = (SGN>0) ? 1.f : (1.f/160.f);
    float2 y[5];
    #pragma unroll
    for (int n1=0;n1<5;n1++) y[n1] = tile[l + 32*n1][q];
    linefft<SGN>(y, l);
    int o5 = 5*br5(l);
    #pragma unroll
    for (int k=0;k<5;k++) tile[o5+k][q] = cscale(y[k], SC);
}

// b = zchunk*160 + ix  (zb-outer so line-sharing blocks b, b+160 share an XCD)
template<int SGN>
__global__ __launch_bounds__(256) void fft_y1(float2* __restrict__ data)
{
    __shared__ float2 tile[NN][WZ+1];
    int b = blockIdx.x;
    int ix = b % 160, zb = (b / 160) * WZ;
    size_t tbase = (size_t)ix*XS + zb;
    int tid = threadIdx.x;
    for (int i = tid; i < NN*WZ; i += 256){
        int row = i >> 3, zi = i & 7;
        tile[row][zi] = (zb + zi < KP) ? data[tbase + (size_t)row*KP + zi] : make_float2(0.f,0.f);
    }
    __syncthreads();
    ycompute<SGN>(tile, tid);
    __syncthreads();
    for (int i = tid; i < NN*WZ; i += 256){
        int row = i >> 3, zi = i & 7;
        if (zb + zi < KP) data[tbase + (size_t)row*KP + zi] = tile[row][zi];
    }
}

template<int SGN>
__global__ __launch_bounds__(256) void fft_y3(RPc P)
{
    __shared__ float2 tile[NN][WZ+1];
    float2* data = P.C[blockIdx.y];
    int b = blockIdx.x;
    int ix = b % 160, zb = (b / 160) * WZ;
    size_t tbase = (size_t)ix*XS + zb;
    int tid = threadIdx.x;
    for (int i = tid; i < NN*WZ; i += 256){
        int row = i >> 3, zi = i & 7;
        tile[row][zi] = (zb + zi < KP) ? data[tbase + (size_t)row*KP + zi] : make_float2(0.f,0.f);
    }
    __syncthreads();
    ycompute<SGN>(tile, tid);
    __syncthreads();
    for (int i = tid; i < NN*WZ; i += 256){
        int row = i >> 3, zi = i & 7;
        if (zb + zi < KP) data[tbase + (size_t)row*KP + zi] = tile[row][zi];
    }
}

// ---------------- x-axis kernels with analytic K ----------------
// spread: C_r = invx( K_r * fwdx(CF) ), one radius per block.
// fwd->K->inv entirely in registers via ilinefft_perm (no mid LDS round-trip).
__global__ __launch_bounds__(256) void fft_xK(RPc P, const float2* __restrict__ in)
{
    __shared__ float2 tile[NN][WZ+1];
    int r = blockIdx.y;
    int b = blockIdx.x;
    int iy = b % 160, zb = (b / 160) * WZ;
    size_t tbase = (size_t)iy*KP + zb;
    int tid = threadIdx.x, l = tid & 31, q = tid >> 5;
    for (int i = tid; i < NN*WZ; i += 256){
        int row = i >> 3, zi = i & 7;
        tile[row][zi] = (zb + zi < KP) ? in[tbase + (size_t)row*XS + zi] : make_float2(0.f,0.f);
    }
    __syncthreads();
    float fy = (float)((iy < 80) ? iy : iy - 160) * (1.f/160.f);
    float fy2 = fy*fy;
    float cy1 = fcos_rev(fy);
    float cy2 = 2.f*cy1*cy1 - 1.f;
    float cy3 = 2.f*cy1*cy2 - cy1;
    QCol qc = make_qcol(1.f, 2.f*cy1, 2.f*cy2, 2.f*cy3, zb + q);
    float2 y[5];
    #pragma unroll
    for (int n1=0;n1<5;n1++) y[n1] = tile[n1*32 + l][q];
    linefft<1>(y, l);
    int o5 = 5*br5(l);
    #pragma unroll
    for (int k=0;k<5;k++) y[k] = cscale(y[k], kval_r(r, qc, fy2, o5+k) * (1.f/160.f));
    ilinefft_perm(y, l);
    // own-column write (group-private) then barrier before cooperative store
    #pragma unroll
    for (int n1=0;n1<5;n1++) tile[n1*32 + l][q] = y[n1];
    __syncthreads();
    float2* Cr = P.C[r];
    for (int i = tid; i < NN*WZ; i += 256){
        int row = i >> 3, zi = i & 7;
        if (zb + zi < KP) Cr[tbase + (size_t)row*XS + zi] = tile[row][zi];
    }
}

// gather: CF = invx( sum_r K_r * fwdx(C_r) ), fused (no spectrum round-trip)
__global__ __launch_bounds__(256) void fft_xgather(RPc P, float2* __restrict__ out)
{
    __shared__ float2 t0[NN][WZ+1], t1[NN][WZ+1], t2[NN][WZ+1];
    int b = blockIdx.x;
    int iy = b % 160, zb = (b / 160) * WZ;
    size_t tbase = (size_t)iy*KP + zb;
    int tid = threadIdx.x, l = tid & 31, q = tid >> 5;
    for (int i = tid; i < NN*WZ; i += 256){
        int row = i >> 3, zi = i & 7;
        bool ok = (zb + zi < KP);
        size_t gidx = tbase + (size_t)row*XS + zi;
        t0[row][zi] = ok ? P.C[0][gidx] : make_float2(0.f,0.f);
        t1[row][zi] = ok ? P.C[1][gidx] : make_float2(0.f,0.f);
        t2[row][zi] = ok ? P.C[2][gidx] : make_float2(0.f,0.f);
    }
    __syncthreads();
    float fy = (float)((iy < 80) ? iy : iy - 160) * (1.f/160.f);
    float fy2 = fy*fy;
    float cy1 = fcos_rev(fy);
    float cy2 = 2.f*cy1*cy1 - 1.f;
    float cy3 = 2.f*cy1*cy2 - cy1;
    QCol qc = make_qcol(1.f, 2.f*cy1, 2.f*cy2, 2.f*cy3, zb + q);
    int o5 = 5*br5(l);
    float2 y[5], acc[5];
    #pragma unroll
    for (int n1=0;n1<5;n1++) y[n1] = t0[n1*32 + l][q];
    linefft<1>(y, l);
    #pragma unroll
    for (int k=0;k<5;k++) acc[k] = cscale(y[k], kval<0>(qc, fy2, o5+k) * (1.f/160.f));
    #pragma unroll
    for (int n1=0;n1<5;n1++) y[n1] = t1[n1*32 + l][q];
    linefft<1>(y, l);
    #pragma unroll
    for (int k=0;k<5;k++) acc[k] = cadd(acc[k], cscale(y[k], kval<1>(qc, fy2, o5+k) * (1.f/160.f)));
    #pragma unroll
    for (int n1=0;n1<5;n1++) y[n1] = t2[n1*32 + l][q];
    linefft<1>(y, l);
    #pragma unroll
    for (int k=0;k<5;k++) acc[k] = cadd(acc[k], cscale(y[k], kval<2>(qc, fy2, o5+k) * (1.f/160.f)));
    ilinefft_perm(acc, l);
    // own-column write into t0 (each group only touches its column)
    #pragma unroll
    for (int n1=0;n1<5;n1++) t0[n1*32 + l][q] = acc[n1];
    __syncthreads();
    for (int i = tid; i < NN*WZ; i += 256){
        int row = i >> 3, zi = i & 7;
        if (zb + zi < KP) out[tbase + (size_t)row*XS + zi] = t0[row][zi];
    }
}

// ---------------- setup / CG vector ops ----------------
__global__ __launch_bounds__(256) void m2w_kernel(const float* __restrict__ mask,
        const float* __restrict__ w, float* __restrict__ M0,
        float* __restrict__ M1, float* __restrict__ M2)
{
    int i = blockIdx.x*256 + threadIdx.x;
    float m = mask[i]; float mm = m*m;
    M0[i] = mm * w[3*(size_t)i+0];
    M1[i] = mm * w[3*(size_t)i+1];
    M2[i] = mm * w[3*(size_t)i+2];
}

__global__ __launch_bounds__(256) void copy_kernel(const float* __restrict__ a, float* __restrict__ b){
    int i = blockIdx.x*256 + threadIdx.x;
    b[i] = a[i];
}

#define GSTRIDE (2048*256)
__global__ __launch_bounds__(256) void upd1_kernel(float* __restrict__ x, float* __restrict__ r,
        const float* __restrict__ p, const float* __restrict__ Ap, double* s)
{
    float alpha = (float)(s[0] / (s[1] + 1e-12));
    double acc = 0.0;
    for (int i = blockIdx.x*256 + threadIdx.x; i < N3; i += GSTRIDE){
        x[i] += alpha * p[i];
        float rn = r[i] - alpha * Ap[i];
        r[i] = rn;
        acc += (double)rn * (double)rn;
    }
    block_atomic_add(acc, &s[2]);
}
__global__ void advance_kernel(double* s){
    if (threadIdx.x == 0){
        s[3] = s[2] / (s[0] + 1e-12);   // beta
        s[0] = s[2]; s[1] = 0.0; s[2] = 0.0;
    }
}
__global__ void zero_kernel(double* s){
    if (threadIdx.x < 4) s[threadIdx.x] = 0.0;
}

// ---------------- host orchestration ----------------
extern "C" void kernel_launch(void* const* d_in, const int* in_sizes, int n_in,
                              void* d_out, int out_size, void* d_ws, size_t ws_size,
                              hipStream_t stream)
{
    (void)in_sizes; (void)n_in; (void)out_size;
    const float* w    = (const float*)d_in[0];   // [N3*3], R fastest
    const float* x2   = (const float*)d_in[1];   // [N3]
    const float* mask = (const float*)d_in[2];   // [N3]
    const float* bb   = (const float*)d_in[3];   // [N3]
    float* x = (float*)d_out;
    char* ws = (char*)d_ws;

    size_t off = 0;
    auto alloc = [&](size_t bytes)->void*{
        void* pp = ws + off;
        off += (bytes + 255) & ~(size_t)255;
        return pp;
    };
    const size_t CB = (size_t)NLINES * KP * sizeof(float2);   // 16.6 MB
    float2* CF = (float2*)alloc(CB);
    float2* C0 = (float2*)alloc(CB);
    float2* C1 = (float2*)alloc(CB);
    float2* C2 = (float2*)alloc(CB);
    float*  rr = (float*) alloc((size_t)N3*4);
    float*  pp = (float*) alloc((size_t)N3*4);
    double* S  = (double*)alloc(64);
    float*  Ap = (float*)C0;      // alias: C0 dead when Ap produced/consumed
    bool PRE = (ws_size >= off + 3*(((size_t)N3*4 + 255) & ~(size_t)255));
    float *M0=nullptr, *M1=nullptr, *M2=nullptr;
    if (PRE){
        M0 = (float*)alloc((size_t)N3*4);
        M1 = (float*)alloc((size_t)N3*4);
        M2 = (float*)alloc((size_t)N3*4);
    }
    RPc P;
    P.C[0]=C0; P.C[1]=C1; P.C[2]=C2;
    P.M[0]=M0; P.M[1]=M1; P.M[2]=M2;

    zero_kernel<<<1, 64, 0, stream>>>(S);
    if (PRE) m2w_kernel<<<16000, 256, 0, stream>>>(mask, w, M0, M1, M2);
    copy_kernel<<<16000, 256, 0, stream>>>(x2, x);

    const int GY = NBZ * 160;    // 1760
    // PM: 0 = plain fft of z; 1 = fused p-update. FIN: 1 = initial residual, 0 = CG iter.
    auto applyM = [&](const float* z, int FIN, int PM){
        if (PM) fft_z_first<1><<<1600, 256, 0, stream>>>(z, rr, pp, CF, S);
        else    fft_z_first<0><<<1600, 256, 0, stream>>>(z, rr, pp, CF, S);
        fft_y1<1><<<GY, 256, 0, stream>>>(CF);
        fft_xK<<<dim3(GY,3), 256, 0, stream>>>(P, CF);
        fft_y3<-1><<<dim3(GY,3), 256, 0, stream>>>(P);
        if (PRE) fft_z_mid3<true ><<<dim3(1600,3), 256, 0, stream>>>(P, mask, w);
        else     fft_z_mid3<false><<<dim3(1600,3), 256, 0, stream>>>(P, mask, w);
        fft_y3<1><<<dim3(GY,3), 256, 0, stream>>>(P);
        fft_xgather<<<GY, 256, 0, stream>>>(P, CF);
        fft_y1<-1><<<GY, 256, 0, stream>>>(CF);
        if (FIN) fft_z_fin<1><<<1600, 256, 0, stream>>>(CF, x, Ap, bb, rr, pp, S);
        else     fft_z_fin<0><<<1600, 256, 0, stream>>>(CF, pp, Ap, bb, rr, pp, S);
    };

    // r = b - M(x2); p = r; rs = <r,r>
    applyM(x, 1, 0);

    for (int it = 0; it < 10; it++){
        applyM(pp, 0, (it == 0) ? 0 : 1);          // Ap = M(p), S[1] = <p,Ap>
        upd1_kernel<<<2048, 256, 0, stream>>>(x, rr, pp, Ap, S);
        if (it < 9) advance_kernel<<<1, 64, 0, stream>>>(S);
    }
}

// Round 8
// 2722.552 us; speedup vs baseline: 3.2160x; 1.0407x over previous
//
#include <hip/hip_runtime.h>

#define NN 160
#define KP 81                // kept kz planes (Hermitian half)
#define N3 4096000           // 160^3
#define NLINES 25600         // 160^2 z-lines
#define WZ 8                 // tile width (kz columns) for x/y sweeps
#define NBZ 11               // ceil(81/8)
#define XS 12960             // x-stride in complex layout (160*81)
#define TPI 6.28318530717958647692f
#define LAM_F 0.05f

// ---------------- complex helpers ----------------
__device__ __forceinline__ float2 cxmul(float2 a, float2 b){
    return make_float2(a.x*b.x - a.y*b.y, a.x*b.y + a.y*b.x);
}
__device__ __forceinline__ float2 cadd(float2 a, float2 b){ return make_float2(a.x+b.x, a.y+b.y); }
__device__ __forceinline__ float2 csub(float2 a, float2 b){ return make_float2(a.x-b.x, a.y-b.y); }
__device__ __forceinline__ float2 cscale(float2 a, float s){ return make_float2(a.x*s, a.y*s); }
__device__ __forceinline__ float2 shfl2(float2 v, int m){
    return make_float2(__shfl_xor(v.x, m, 64), __shfl_xor(v.y, m, 64));
}
__device__ __forceinline__ int br5(int l){
    return ((l&1)<<4)|((l&2)<<2)|(l&4)|((l&8)>>2)|((l&16)>>4);
}
// rev in revolutions (angle/2pi). v_sin_f32/v_cos_f32 are revolution-input
// on gfx950 -> 1 instr each, no range reduction needed.
__device__ __forceinline__ float fsin_rev(float rev){ return __builtin_amdgcn_sinf(rev); }
__device__ __forceinline__ float fcos_rev(float rev){ return __builtin_amdgcn_cosf(rev); }
template<int SGN>
__device__ __forceinline__ float2 twid(float rev){
    float s = fsin_rev(rev), c = fcos_rev(rev);
    return make_float2(c, (SGN>0) ? -s : s);
}

// ---------------- radix-5 DFT ----------------
template<int SGN>
__device__ __forceinline__ void dft5(float2 y[5]){
    const float C1 = 0.30901699437494742f;
    const float C2 = -0.80901699437494742f;
    const float S1 = 0.95105651629515357f;
    const float S2 = 0.58778525229247312f;
    float2 x0=y[0], x1=y[1], x2=y[2], x3=y[3], x4=y[4];
    float2 t1=cadd(x1,x4), t2=cadd(x2,x3), t3=csub(x1,x4), t4=csub(x2,x3);
    y[0] = cadd(x0, cadd(t1,t2));
    float2 a1 = make_float2(x0.x + C1*t1.x + C2*t2.x, x0.y + C1*t1.y + C2*t2.y);
    float2 a2 = make_float2(x0.x + C2*t1.x + C1*t2.x, x0.y + C2*t1.y + C1*t2.y);
    const float sg = (SGN>0) ? 1.f : -1.f;
    float2 b1 = make_float2(sg*(S1*t3.x + S2*t4.x), sg*(S1*t3.y + S2*t4.y));
    float2 b2 = make_float2(sg*(S2*t3.x - S1*t4.x), sg*(S2*t3.y - S1*t4.y));
    y[1] = make_float2(a1.x + b1.y, a1.y - b1.x);
    y[4] = make_float2(a1.x - b1.y, a1.y + b1.x);
    y[2] = make_float2(a2.x + b2.y, a2.y - b2.x);
    y[3] = make_float2(a2.x - b2.y, a2.y + b2.x);
}

__device__ __forceinline__ float2 bfly(float2 v, int m, float2 tw, int l){
    float2 o = shfl2(v, m);
    float2 s = cadd(v, o);
    float2 d = cxmul(csub(o, v), tw);
    return (l & m) ? d : s;
}

// 160-pt FFT: lane l in [0,32) holds y[n1]=x[n1*32+l] on entry.
// On exit, slot k holds X[k + 5*br5(l)].
template<int SGN>
__device__ __forceinline__ void linefft(float2 y[5], int l){
    dft5<SGN>(y);
    float2 w1 = twid<SGN>((float)l * (1.f/160.f));
    float2 w2 = cxmul(w1,w1);
    float2 w3 = cxmul(w2,w1);
    float2 w4 = cxmul(w2,w2);
    y[1]=cxmul(y[1],w1); y[2]=cxmul(y[2],w2); y[3]=cxmul(y[3],w3); y[4]=cxmul(y[4],w4);
    float2 tw16 = twid<SGN>((float)(l & 15) * (1.f/32.f));
    float2 tw8  = twid<SGN>((float)(l & 7)  * (1.f/16.f));
    float2 tw4  = twid<SGN>((float)(l & 3)  * (1.f/8.f));
    float2 tw2  = twid<SGN>((float)(l & 1)  * (1.f/4.f));
    #pragma unroll
    for (int k=0;k<5;k++){
        float2 v = y[k];
        v = bfly(v,16,tw16,l);
        v = bfly(v, 8,tw8 ,l);
        v = bfly(v, 4,tw4 ,l);
        v = bfly(v, 2,tw2 ,l);
        float2 o = shfl2(v,1);
        v = (l&1) ? csub(o,v) : cadd(v,o);
        y[k] = v;
    }
}

// DIT butterfly: low lane: v + tw*o ; high lane: o - tw*v
__device__ __forceinline__ float2 bflyi(float2 v, int m, float2 tw, int l){
    float2 o = shfl2(v, m);
    float2 t = cxmul(tw, (l & m) ? v : o);
    return (l & m) ? csub(o, t) : cadd(v, t);
}

// inverse 160-pt FFT consuming the forward's permuted register layout:
// entry: slot k lane l = X[k + 5*br5(l)]; exit: y[n1] = x[n1*32+l] (UNscaled).
__device__ __forceinline__ void ilinefft_perm(float2 y[5], int l){
    float2 tw2  = twid<-1>((float)(l & 1)  * (1.f/4.f));
    float2 tw4  = twid<-1>((float)(l & 3)  * (1.f/8.f));
    float2 tw8  = twid<-1>((float)(l & 7)  * (1.f/16.f));
    float2 tw16 = twid<-1>((float)(l & 15) * (1.f/32.f));
    #pragma unroll
    for (int k=0;k<5;k++){
        float2 v = y[k];
        { float2 o = shfl2(v,1); v = (l&1) ? csub(o,v) : cadd(v,o); }
        v = bflyi(v, 2, tw2 , l);
        v = bflyi(v, 4, tw4 , l);
        v = bflyi(v, 8, tw8 , l);
        v = bflyi(v,16, tw16, l);
        y[k] = v;
    }
    float2 w1 = twid<-1>((float)l * (1.f/160.f));
    float2 w2 = cxmul(w1,w1);
    float2 w3 = cxmul(w2,w1);
    float2 w4 = cxmul(w2,w2);
    y[1]=cxmul(y[1],w1); y[2]=cxmul(y[2],w2); y[3]=cxmul(y[3],w3); y[4]=cxmul(y[4],w4);
    dft5<-1>(y);
}

struct RPc {
    float2* C[3];
    const float* M[3];
};

// analytic kernel ingredients: Q sums over (dy,dz) ball slices, per column
struct QCol {
    float Q1_0, Q1_1;
    float Q2_0, Q2_1, Q2_2;
    float Q3_0, Q3_1, Q3_2, Q3_3;
    float fz2;
};

__device__ __forceinline__ QCol make_qcol(float ay0,float ay1,float ay2,float ay3, int kz){
    float fz = (float)kz * (1.f/160.f);
    float cz1 = fcos_rev(fz);
    float cz2 = 2.f*cz1*cz1 - 1.f;
    float cz3 = 2.f*cz1*cz2 - cz1;
    float az0=1.f, az1=2.f*cz1, az2=2.f*cz2, az3=2.f*cz3;
    float P00=ay0*az0, P01=ay0*az1, P02=ay0*az2, P03=ay0*az3;
    float P10=ay1*az0, P11=ay1*az1, P12=ay1*az2;
    float P20=ay2*az0, P21=ay2*az1, P22=ay2*az2;
    float P30=ay3*az0;
    QCol q;
    q.Q1_0 = P00 + P01 + P10;
    q.Q1_1 = P00;
    q.Q2_0 = P00+P01+P02+P10+P11+P20;
    q.Q2_1 = P00+P01+P10+P11;
    q.Q2_2 = P00;
    q.Q3_0 = P00+P01+P02+P03+P10+P11+P12+P20+P21+P22+P30;
    q.Q3_1 = P00+P01+P02+P10+P11+P12+P20+P21+P22;
    q.Q3_2 = P00+P01+P02+P10+P11+P12+P20+P21;
    q.Q3_3 = P00;
    q.fz2 = fz*fz;
    return q;
}

// all three K_r with one cosine chain. kx in [0,160).
__device__ __forceinline__ void kval3(const QCol& q, float fy2, int kx, float K[3]){
    float c1 = fcos_rev((float)kx * (1.f/160.f));
    float c2 = 2.f*c1*c1 - 1.f;
    float c3 = 2.f*c1*c2 - c1;
    float s1 = (q.Q1_0 + 2.f*c1*q.Q1_1) * (1.f/7.f);
    float s2 = (q.Q2_0 + 2.f*(c1*q.Q2_1 + c2*q.Q2_2)) * (1.f/33.f);
    float s3 = (q.Q3_0 + 2.f*(c1*q.Q3_1 + c2*q.Q3_2 + c3*q.Q3_3)) * (1.f/123.f);
    float fxw = (float)((kx < 80) ? kx : 160 - kx) * (1.f/160.f);
    float k2 = fxw*fxw + fy2 + q.fz2;
    float D = (1.f/3.f) - ((k2 == 0.f) ? 0.f : q.fz2 * __builtin_amdgcn_rcpf(k2));
    K[0] = (1.f - s1) * D;
    K[1] = (1.f - s2) * D;
    K[2] = (1.f - s3) * D;
}

// ---------------- CG reduction helper ----------------
__device__ __forceinline__ void block_atomic_add(double v, double* target){
    #pragma unroll
    for (int off=32; off>0; off>>=1) v += __shfl_down(v, off, 64);
    __shared__ double sm[4];
    int wv = threadIdx.x >> 6;
    if ((threadIdx.x & 63) == 0) sm[wv] = v;
    __syncthreads();
    if (threadIdx.x == 0) atomicAdd(target, sm[0]+sm[1]+sm[2]+sm[3]);
}

// ======== z-axis kernels: wave-local, barrier-free ========
// PM=0: fft real zin. PM=1: p = r + beta*p (beta=S[3]), store p, fft p.
template<int PM>
__global__ __launch_bounds__(256) void fft_z_first(const float* __restrict__ zin,
    const float* __restrict__ rrv, float* __restrict__ ppv,
    float2* __restrict__ out, const double* __restrict__ S)
{
    __shared__ float2 ldsC[8*162];
    int tid = threadIdx.x, l = tid & 31, g = tid >> 5;
    int fl = g*162;
    size_t base160 = (size_t)blockIdx.x * 2560 + (size_t)(2*g)*160;
    size_t baseC   = (size_t)blockIdx.x * 1296 + (size_t)g*162;
    float beta = PM ? (float)S[3] : 0.f;
    float2 y[5];
    #pragma unroll
    for (int n1=0;n1<5;n1++){
        int n = n1*32 + l;
        float a, b;
        if (PM){
            a = rrv[base160 + n]       + beta * ppv[base160 + n];
            b = rrv[base160 + 160 + n] + beta * ppv[base160 + 160 + n];
            ppv[base160 + n] = a;
            ppv[base160 + 160 + n] = b;
        } else {
            a = zin[base160 + n];
            b = zin[base160 + 160 + n];
        }
        y[n1] = make_float2(a, b);
    }
    linefft<1>(y, l);
    int o5 = 5*br5(l);
    #pragma unroll
    for (int k=0;k<5;k++) ldsC[fl + o5 + k] = y[k];
    #pragma unroll
    for (int t=0;t<6;t++){
        int j = l + 32*t;
        if (j < 162){
            int k = (j < 81) ? j : j - 81;
            float2 Sk = ldsC[fl + k];
            float2 Sm = ldsC[fl + ((160 - k) % 160)];
            float2 o = (j >= 81)
                ? make_float2(0.5f*(Sk.y + Sm.y), -0.5f*(Sk.x - Sm.x))    // B
                : make_float2(0.5f*(Sk.x + Sm.x),  0.5f*(Sk.y - Sm.y));   // A
            out[baseC + j] = o;
        }
    }
}

// fused: inverse-z (Hermitian reconstruct, packed pair) -> *m2w_r -> forward-z
template<bool PRE>
__global__ __launch_bounds__(256) void fft_z_mid3(RPc P, const float* __restrict__ mask,
                                                 const float* __restrict__ wfull)
{
    __shared__ float2 ldsC[8*162];
    int r = blockIdx.y;
    float2* C = P.C[r];
    int tid = threadIdx.x, l = tid & 31, g = tid >> 5;
    int fl = g*162;
    size_t baseC   = (size_t)blockIdx.x * 1296 + (size_t)g*162;
    size_t base160 = (size_t)blockIdx.x * 2560 + (size_t)(2*g)*160;
    int o5 = 5*br5(l);
    float ma[5], mb[5];
    if (PRE){
        const float* M = P.M[r];
        #pragma unroll
        for (int k=0;k<5;k++){
            ma[k] = M[base160 + o5 + k];
            mb[k] = M[base160 + 160 + o5 + k];
        }
    } else {
        #pragma unroll
        for (int k=0;k<5;k++){
            size_t ia = base160 + o5 + k, ib = base160 + 160 + o5 + k;
            float m1 = mask[ia], m2 = mask[ib];
            ma[k] = m1*m1*wfull[ia*3 + r];
            mb[k] = m2*m2*wfull[ib*3 + r];
        }
    }
    #pragma unroll
    for (int t=0;t<6;t++){
        int j = l + 32*t;
        if (j < 162) ldsC[fl + j] = C[baseC + j];
    }
    float2 y[5];
    #pragma unroll
    for (int n1=0;n1<5;n1++){
        int e = n1*32 + l;
        float2 X;
        if (e <= 80){
            float2 A = ldsC[fl + e], B = ldsC[fl + 81 + e];
            X = make_float2(A.x - B.y, A.y + B.x);
        } else {
            int m = 160 - e;
            float2 A = ldsC[fl + m], B = ldsC[fl + 81 + m];
            X = make_float2(A.x + B.y, B.x - A.y);
        }
        y[n1] = X;
    }
    linefft<-1>(y, l);
    const float SC = 1.f/160.f;
    #pragma unroll
    for (int k=0;k<5;k++){
        float a = y[k].x * SC * ma[k];
        float b = y[k].y * SC * mb[k];
        ldsC[fl + o5 + k] = make_float2(a, b);
    }
    #pragma unroll
    for (int n1=0;n1<5;n1++) y[n1] = ldsC[fl + n1*32 + l];
    linefft<1>(y, l);
    #pragma unroll
    for (int k=0;k<5;k++) ldsC[fl + o5 + k] = y[k];
    #pragma unroll
    for (int t=0;t<6;t++){
        int j = l + 32*t;
        if (j < 162){
            int k = (j < 81) ? j : j - 81;
            float2 Sk = ldsC[fl + k];
            float2 Sm = ldsC[fl + ((160 - k) % 160)];
            float2 o = (j >= 81)
                ? make_float2(0.5f*(Sk.y + Sm.y), -0.5f*(Sk.x - Sm.x))
                : make_float2(0.5f*(Sk.x + Sm.x),  0.5f*(Sk.y - Sm.y));
            C[baseC + j] = o;
        }
    }
}

// final inverse-z + epilogue. FIN=0: Ap=v, S[1]+=<z,v>. FIN=1: r=b-v -> rr,pp, S[0]+=<r,r>.
template<int FIN>
__global__ __launch_bounds__(256) void fft_z_fin(const float2* __restrict__ in,
    const float* __restrict__ zsp, float* __restrict__ Ap,
    const float* __restrict__ bb, float* __restrict__ rrv, float* __restrict__ ppv,
    double* __restrict__ S)
{
    __shared__ float2 ldsC[8*162];
    float* ldsF = (float*)ldsC;      // region g: floats [324g, 324g+320)
    int tid = threadIdx.x, l = tid & 31, g = tid >> 5;
    int fl = g*162;
    size_t baseC   = (size_t)blockIdx.x * 1296 + (size_t)g*162;
    size_t base160 = (size_t)blockIdx.x * 2560 + (size_t)(2*g)*160;
    int o5 = 5*br5(l);
    float za[5], zb[5], pa[5], pb[5];
    #pragma unroll
    for (int k=0;k<5;k++){
        za[k] = zsp[base160 + o5 + k];
        zb[k] = zsp[base160 + 160 + o5 + k];
        if (FIN){
            pa[k] = bb[base160 + o5 + k];
            pb[k] = bb[base160 + 160 + o5 + k];
        }
    }
    #pragma unroll
    for (int t=0;t<6;t++){
        int j = l + 32*t;
        if (j < 162) ldsC[fl + j] = in[baseC + j];
    }
    float2 y[5];
    #pragma unroll
    for (int n1=0;n1<5;n1++){
        int e = n1*32 + l;
        float2 X;
        if (e <= 80){
            float2 A = ldsC[fl + e], B = ldsC[fl + 81 + e];
            X = make_float2(A.x - B.y, A.y + B.x);
        } else {
            int m = 160 - e;
            float2 A = ldsC[fl + m], B = ldsC[fl + 81 + m];
            X = make_float2(A.x + B.y, B.x - A.y);
        }
        y[n1] = X;
    }
    linefft<-1>(y, l);
    const float SC = 1.f/160.f;
    double acc = 0.0;
    int fb = g*324;
    #pragma unroll
    for (int k=0;k<5;k++){
        float va = LAM_F*za[k] + y[k].x*SC;
        float vb = LAM_F*zb[k] + y[k].y*SC;
        if (FIN == 0){
            acc += (double)za[k]*(double)va + (double)zb[k]*(double)vb;
            ldsF[fb + o5 + k] = va;
            ldsF[fb + 160 + o5 + k] = vb;
        } else {
            float ra = pa[k] - va, rb = pb[k] - vb;
            acc += (double)ra*(double)ra + (double)rb*(double)rb;
            ldsF[fb + o5 + k] = ra;
            ldsF[fb + 160 + o5 + k] = rb;
        }
    }
    #pragma unroll
    for (int t=0;t<10;t++){
        int n = l + 32*t;
        float v = ldsF[fb + n];
        if (FIN == 0){
            Ap[base160 + n] = v;
        } else {
            rrv[base160 + n] = v;
            ppv[base160 + n] = v;
        }
    }
    block_atomic_add(acc, FIN ? &S[0] : &S[1]);
}

// ---------------- y-axis sweeps (strided, guarded half-spectrum, W=8) ----------------
template<int SGN>
__device__ __forceinline__ void ycompute(float2 (*tile)[WZ+1], int tid){
    int l = tid & 31, q = tid >> 5;
    const float SC = (SGN>0) ? 1.f : (1.f/160.f);
    float2 y[5];
    #pragma unroll
    for (int n1=0;n1<5;n1++) y[n1] = tile[l + 32*n1][q];
    linefft<SGN>(y, l);
    int o5 = 5*br5(l);
    #pragma unroll
    for (int k=0;k<5;k++) tile[o5+k][q] = cscale(y[k], SC);
}

// b = zchunk*160 + ix  (zb-outer so line-sharing blocks b, b+160 share an XCD)
template<int SGN>
__global__ __launch_bounds__(256) void fft_y1(float2* __restrict__ data)
{
    __shared__ float2 tile[NN][WZ+1];
    int b = blockIdx.x;
    int ix = b % 160, zb = (b / 160) * WZ;
    size_t tbase = (size_t)ix*XS + zb;
    int tid = threadIdx.x;
    for (int i = tid; i < NN*WZ; i += 256){
        int row = i >> 3, zi = i & 7;
        tile[row][zi] = (zb + zi < KP) ? data[tbase + (size_t)row*KP + zi] : make_float2(0.f,0.f);
    }
    __syncthreads();
    ycompute<SGN>(tile, tid);
    __syncthreads();
    for (int i = tid; i < NN*WZ; i += 256){
        int row = i >> 3, zi = i & 7;
        if (zb + zi < KP) data[tbase + (size_t)row*KP + zi] = tile[row][zi];
    }
}

template<int SGN>
__global__ __launch_bounds__(256) void fft_y3(RPc P)
{
    __shared__ float2 tile[NN][WZ+1];
    float2* data = P.C[blockIdx.y];
    int b = blockIdx.x;
    int ix = b % 160, zb = (b / 160) * WZ;
    size_t tbase = (size_t)ix*XS + zb;
    int tid = threadIdx.x;
    for (int i = tid; i < NN*WZ; i += 256){
        int row = i >> 3, zi = i & 7;
        tile[row][zi] = (zb + zi < KP) ? data[tbase + (size_t)row*KP + zi] : make_float2(0.f,0.f);
    }
    __syncthreads();
    ycompute<SGN>(tile, tid);
    __syncthreads();
    for (int i = tid; i < NN*WZ; i += 256){
        int row = i >> 3, zi = i & 7;
        if (zb + zi < KP) data[tbase + (size_t)row*KP + zi] = tile[row][zi];
    }
}

// ---------------- x-axis kernels with analytic K ----------------
// spread: one block per (iy, zb). Shared fwd-x FFT once, then per radius:
// scale K_r, ilinefft_perm (registers), column-private write, coop store C_r.
__global__ __launch_bounds__(256) void fft_xK(RPc P, const float2* __restrict__ in)
{
    __shared__ float2 tile[NN][WZ+1];
    int b = blockIdx.x;
    int iy = b % 160, zb = (b / 160) * WZ;
    size_t tbase = (size_t)iy*KP + zb;
    int tid = threadIdx.x, l = tid & 31, q = tid >> 5;
    for (int i = tid; i < NN*WZ; i += 256){
        int row = i >> 3, zi = i & 7;
        tile[row][zi] = (zb + zi < KP) ? in[tbase + (size_t)row*XS + zi] : make_float2(0.f,0.f);
    }
    __syncthreads();
    float fy = (float)((iy < 80) ? iy : iy - 160) * (1.f/160.f);
    float fy2 = fy*fy;
    float cy1 = fcos_rev(fy);
    float cy2 = 2.f*cy1*cy1 - 1.f;
    float cy3 = 2.f*cy1*cy2 - cy1;
    QCol qc = make_qcol(1.f, 2.f*cy1, 2.f*cy2, 2.f*cy3, zb + q);
    int o5 = 5*br5(l);
    float2 spec[5];
    #pragma unroll
    for (int n1=0;n1<5;n1++) spec[n1] = tile[n1*32 + l][q];
    linefft<1>(spec, l);
    float K3[5][3];
    #pragma unroll
    for (int k=0;k<5;k++) kval3(qc, fy2, o5+k, K3[k]);
    #pragma unroll
    for (int r=0; r<3; r++){
        float2 acc[5];
        #pragma unroll
        for (int k=0;k<5;k++) acc[k] = cscale(spec[k], K3[k][r] * (1.f/160.f));
        ilinefft_perm(acc, l);
        // column q is group-private between coop phases
        #pragma unroll
        for (int n1=0;n1<5;n1++) tile[n1*32 + l][q] = acc[n1];
        __syncthreads();
        float2* Cr = P.C[r];
        for (int i = tid; i < NN*WZ; i += 256){
            int row = i >> 3, zi = i & 7;
            if (zb + zi < KP) Cr[tbase + (size_t)row*XS + zi] = tile[row][zi];
        }
        __syncthreads();
    }
}

// gather: CF = invx( sum_r K_r * fwdx(C_r) ), single tile + async reg staging
__global__ __launch_bounds__(256) void fft_xgather(RPc P, float2* __restrict__ out)
{
    __shared__ float2 tile[NN][WZ+1];
    int b = blockIdx.x;
    int iy = b % 160, zb = (b / 160) * WZ;
    size_t tbase = (size_t)iy*KP + zb;
    int tid = threadIdx.x, l = tid & 31, q = tid >> 5;
    // cooperative load C0 -> tile
    #pragma unroll
    for (int j=0;j<5;j++){
        int i = tid + 256*j;
        int row = i >> 3, zi = i & 7;
        tile[row][zi] = (zb + zi < KP) ? P.C[0][tbase + (size_t)row*XS + zi] : make_float2(0.f,0.f);
    }
    __syncthreads();
    float fy = (float)((iy < 80) ? iy : iy - 160) * (1.f/160.f);
    float fy2 = fy*fy;
    float cy1 = fcos_rev(fy);
    float cy2 = 2.f*cy1*cy1 - 1.f;
    float cy3 = 2.f*cy1*cy2 - cy1;
    QCol qc = make_qcol(1.f, 2.f*cy1, 2.f*cy2, 2.f*cy3, zb + q);
    int o5 = 5*br5(l);
    float K3[5][3];
    #pragma unroll
    for (int k=0;k<5;k++) kval3(qc, fy2, o5+k, K3[k]);

    // issue C1 loads early (hide under FFT of C0)
    float2 st[5];
    #pragma unroll
    for (int j=0;j<5;j++){
        int i = tid + 256*j;
        int row = i >> 3, zi = i & 7;
        st[j] = (zb + zi < KP) ? P.C[1][tbase + (size_t)row*XS + zi] : make_float2(0.f,0.f);
    }
    float2 y[5], acc[5];
    #pragma unroll
    for (int n1=0;n1<5;n1++) y[n1] = tile[n1*32 + l][q];
    linefft<1>(y, l);
    #pragma unroll
    for (int k=0;k<5;k++) acc[k] = cscale(y[k], K3[k][0] * (1.f/160.f));
    __syncthreads();
    // write staged C1, issue C2 loads
    #pragma unroll
    for (int j=0;j<5;j++){
        int i = tid + 256*j;
        tile[i >> 3][i & 7] = st[j];
    }
    __syncthreads();
    #pragma unroll
    for (int j=0;j<5;j++){
        int i = tid + 256*j;
        int row = i >> 3, zi = i & 7;
        st[j] = (zb + zi < KP) ? P.C[2][tbase + (size_t)row*XS + zi] : make_float2(0.f,0.f);
    }
    #pragma unroll
    for (int n1=0;n1<5;n1++) y[n1] = tile[n1*32 + l][q];
    linefft<1>(y, l);
    #pragma unroll
    for (int k=0;k<5;k++) acc[k] = cadd(acc[k], cscale(y[k], K3[k][1] * (1.f/160.f)));
    __syncthreads();
    #pragma unroll
    for (int j=0;j<5;j++){
        int i = tid + 256*j;
        tile[i >> 3][i & 7] = st[j];
    }
    __syncthreads();
    #pragma unroll
    for (int n1=0;n1<5;n1++) y[n1] = tile[n1*32 + l][q];
    linefft<1>(y, l);
    #pragma unroll
    for (int k=0;k<5;k++) acc[k] = cadd(acc[k], cscale(y[k], K3[k][2] * (1.f/160.f)));
    ilinefft_perm(acc, l);
    __syncthreads();
    #pragma unroll
    for (int n1=0;n1<5;n1++) tile[n1*32 + l][q] = acc[n1];
    __syncthreads();
    for (int i = tid; i < NN*WZ; i += 256){
        int row = i >> 3, zi = i & 7;
        if (zb + zi < KP) out[tbase + (size_t)row*XS + zi] = tile[row][zi];
    }
}

// ---------------- setup / CG vector ops ----------------
__global__ __launch_bounds__(256) void m2w_kernel(const float* __restrict__ mask,
        const float* __restrict__ w, float* __restrict__ M0,
        float* __restrict__ M1, float* __restrict__ M2)
{
    int i = blockIdx.x*256 + threadIdx.x;
    float m = mask[i]; float mm = m*m;
    M0[i] = mm * w[3*(size_t)i+0];
    M1[i] = mm * w[3*(size_t)i+1];
    M2[i] = mm * w[3*(size_t)i+2];
}

__global__ __launch_bounds__(256) void copy_kernel(const float* __restrict__ a, float* __restrict__ b){
    int i = blockIdx.x*256 + threadIdx.x;
    b[i] = a[i];
}

#define GSTRIDE (2048*256)
__global__ __launch_bounds__(256) void upd1_kernel(float* __restrict__ x, float* __restrict__ r,
        const float* __restrict__ p, const float* __restrict__ Ap, double* s)
{
    float alpha = (float)(s[0] / (s[1] + 1e-12));
    double acc = 0.0;
    for (int i = blockIdx.x*256 + threadIdx.x; i < N3; i += GSTRIDE){
        x[i] += alpha * p[i];
        float rn = r[i] - alpha * Ap[i];
        r[i] = rn;
        acc += (double)rn * (double)rn;
    }
    block_atomic_add(acc, &s[2]);
}
__global__ void advance_kernel(double* s){
    if (threadIdx.x == 0){
        s[3] = s[2] / (s[0] + 1e-12);   // beta
        s[0] = s[2]; s[1] = 0.0; s[2] = 0.0;
    }
}
__global__ void zero_kernel(double* s){
    if (threadIdx.x < 4) s[threadIdx.x] = 0.0;
}

// ---------------- host orchestration ----------------
extern "C" void kernel_launch(void* const* d_in, const int* in_sizes, int n_in,
                              void* d_out, int out_size, void* d_ws, size_t ws_size,
                              hipStream_t stream)
{
    (void)in_sizes; (void)n_in; (void)out_size;
    const float* w    = (const float*)d_in[0];   // [N3*3], R fastest
    const float* x2   = (const float*)d_in[1];   // [N3]
    const float* mask = (const float*)d_in[2];   // [N3]
    const float* bb   = (const float*)d_in[3];   // [N3]
    float* x = (float*)d_out;
    char* ws = (char*)d_ws;

    size_t off = 0;
    auto alloc = [&](size_t bytes)->void*{
        void* pp = ws + off;
        off += (bytes + 255) & ~(size_t)255;
        return pp;
    };
    const size_t CB = (size_t)NLINES * KP * sizeof(float2);   // 16.6 MB
    float2* CF = (float2*)alloc(CB);
    float2* C0 = (float2*)alloc(CB);
    float2* C1 = (float2*)alloc(CB);
    float2* C2 = (float2*)alloc(CB);
    float*  rr = (float*) alloc((size_t)N3*4);
    float*  pp = (float*) alloc((size_t)N3*4);
    double* S  = (double*)alloc(64);
    float*  Ap = (float*)C0;      // alias: C0 dead when Ap produced/consumed
    bool PRE = (ws_size >= off + 3*(((size_t)N3*4 + 255) & ~(size_t)255));
    float *M0=nullptr, *M1=nullptr, *M2=nullptr;
    if (PRE){
        M0 = (float*)alloc((size_t)N3*4);
        M1 = (float*)alloc((size_t)N3*4);
        M2 = (float*)alloc((size_t)N3*4);
    }
    RPc P;
    P.C[0]=C0; P.C[1]=C1; P.C[2]=C2;
    P.M[0]=M0; P.M[1]=M1; P.M[2]=M2;

    zero_kernel<<<1, 64, 0, stream>>>(S);
    if (PRE) m2w_kernel<<<16000, 256, 0, stream>>>(mask, w, M0, M1, M2);
    copy_kernel<<<16000, 256, 0, stream>>>(x2, x);

    const int GY = NBZ * 160;    // 1760
    // PM: 0 = plain fft of z; 1 = fused p-update. FIN: 1 = initial residual, 0 = CG iter.
    auto applyM = [&](const float* z, int FIN, int PM){
        if (PM) fft_z_first<1><<<1600, 256, 0, stream>>>(z, rr, pp, CF, S);
        else    fft_z_first<0><<<1600, 256, 0, stream>>>(z, rr, pp, CF, S);
        fft_y1<1><<<GY, 256, 0, stream>>>(CF);
        fft_xK<<<GY, 256, 0, stream>>>(P, CF);
        fft_y3<-1><<<dim3(GY,3), 256, 0, stream>>>(P);
        if (PRE) fft_z_mid3<true ><<<dim3(1600,3), 256, 0, stream>>>(P, mask, w);
        else     fft_z_mid3<false><<<dim3(1600,3), 256, 0, stream>>>(P, mask, w);
        fft_y3<1><<<dim3(GY,3), 256, 0, stream>>>(P);
        fft_xgather<<<GY, 256, 0, stream>>>(P, CF);
        fft_y1<-1><<<GY, 256, 0, stream>>>(CF);
        if (FIN) fft_z_fin<1><<<1600, 256, 0, stream>>>(CF, x, Ap, bb, rr, pp, S);
        else     fft_z_fin<0><<<1600, 256, 0, stream>>>(CF, pp, Ap, bb, rr, pp, S);
    };

    // r = b - M(x2); p = r; rs = <r,r>
    applyM(x, 1, 0);

    for (int it = 0; it < 10; it++){
        applyM(pp, 0, (it == 0) ? 0 : 1);          // Ap = M(p), S[1] = <p,Ap>
        upd1_kernel<<<2048, 256, 0, stream>>>(x, rr, pp, Ap, S);
        if (it < 9) advance_kernel<<<1, 64, 0, stream>>>(S);
    }
}

// Round 9
// 2519.113 us; speedup vs baseline: 3.4757x; 1.0808x over previous
//
#include <hip/hip_runtime.h>
#include <hip/hip_fp16.h>

#define NN 160
#define KP 81                // kept kz planes (Hermitian half)
#define N3 4096000           // 160^3
#define NLINES 25600         // 160^2 z-lines
#define WZ 8                 // tile width (kz columns) for x/y sweeps
#define NBZ 11               // ceil(81/8)
#define XS 12960             // x-stride in complex layout (160*81)
#define TPI 6.28318530717958647692f
#define LAM_F 0.05f
#define SC160 (1.f/160.f)

// ---------------- complex helpers ----------------
__device__ __forceinline__ float2 cxmul(float2 a, float2 b){
    return make_float2(a.x*b.x - a.y*b.y, a.x*b.y + a.y*b.x);
}
__device__ __forceinline__ float2 cadd(float2 a, float2 b){ return make_float2(a.x+b.x, a.y+b.y); }
__device__ __forceinline__ float2 csub(float2 a, float2 b){ return make_float2(a.x-b.x, a.y-b.y); }
__device__ __forceinline__ float2 cscale(float2 a, float s){ return make_float2(a.x*s, a.y*s); }
__device__ __forceinline__ float2 shfl2(float2 v, int m){
    return make_float2(__shfl_xor(v.x, m, 64), __shfl_xor(v.y, m, 64));
}
__device__ __forceinline__ int br5(int l){
    return ((l&1)<<4)|((l&2)<<2)|(l&4)|((l&8)>>2)|((l&16)>>4);
}
__device__ __forceinline__ float2 h2f(__half2 h){ return __half22float2(h); }
__device__ __forceinline__ __half2 f2h(float2 f){ return __float22half2_rn(f); }
// rev in revolutions (angle/2pi). v_sin_f32/v_cos_f32 are revolution-input
// on gfx950 -> 1 instr each, no range reduction needed.
__device__ __forceinline__ float fsin_rev(float rev){ return __builtin_amdgcn_sinf(rev); }
__device__ __forceinline__ float fcos_rev(float rev){ return __builtin_amdgcn_cosf(rev); }
template<int SGN>
__device__ __forceinline__ float2 twid(float rev){
    float s = fsin_rev(rev), c = fcos_rev(rev);
    return make_float2(c, (SGN>0) ? -s : s);
}

// ---------------- radix-5 DFT ----------------
template<int SGN>
__device__ __forceinline__ void dft5(float2 y[5]){
    const float C1 = 0.30901699437494742f;
    const float C2 = -0.80901699437494742f;
    const float S1 = 0.95105651629515357f;
    const float S2 = 0.58778525229247312f;
    float2 x0=y[0], x1=y[1], x2=y[2], x3=y[3], x4=y[4];
    float2 t1=cadd(x1,x4), t2=cadd(x2,x3), t3=csub(x1,x4), t4=csub(x2,x3);
    y[0] = cadd(x0, cadd(t1,t2));
    float2 a1 = make_float2(x0.x + C1*t1.x + C2*t2.x, x0.y + C1*t1.y + C2*t2.y);
    float2 a2 = make_float2(x0.x + C2*t1.x + C1*t2.x, x0.y + C2*t1.y + C1*t2.y);
    const float sg = (SGN>0) ? 1.f : -1.f;
    float2 b1 = make_float2(sg*(S1*t3.x + S2*t4.x), sg*(S1*t3.y + S2*t4.y));
    float2 b2 = make_float2(sg*(S2*t3.x - S1*t4.x), sg*(S2*t3.y - S1*t4.y));
    y[1] = make_float2(a1.x + b1.y, a1.y - b1.x);
    y[4] = make_float2(a1.x - b1.y, a1.y + b1.x);
    y[2] = make_float2(a2.x + b2.y, a2.y - b2.x);
    y[3] = make_float2(a2.x - b2.y, a2.y + b2.x);
}

__device__ __forceinline__ float2 bfly(float2 v, int m, float2 tw, int l){
    float2 o = shfl2(v, m);
    float2 s = cadd(v, o);
    float2 d = cxmul(csub(o, v), tw);
    return (l & m) ? d : s;
}

// 160-pt FFT: lane l in [0,32) holds y[n1]=x[n1*32+l] on entry.
// On exit, slot k holds X[k + 5*br5(l)].
template<int SGN>
__device__ __forceinline__ void linefft(float2 y[5], int l){
    dft5<SGN>(y);
    float2 w1 = twid<SGN>((float)l * (1.f/160.f));
    float2 w2 = cxmul(w1,w1);
    float2 w3 = cxmul(w2,w1);
    float2 w4 = cxmul(w2,w2);
    y[1]=cxmul(y[1],w1); y[2]=cxmul(y[2],w2); y[3]=cxmul(y[3],w3); y[4]=cxmul(y[4],w4);
    float2 tw16 = twid<SGN>((float)(l & 15) * (1.f/32.f));
    float2 tw8  = twid<SGN>((float)(l & 7)  * (1.f/16.f));
    float2 tw4  = twid<SGN>((float)(l & 3)  * (1.f/8.f));
    float2 tw2  = twid<SGN>((float)(l & 1)  * (1.f/4.f));
    #pragma unroll
    for (int k=0;k<5;k++){
        float2 v = y[k];
        v = bfly(v,16,tw16,l);
        v = bfly(v, 8,tw8 ,l);
        v = bfly(v, 4,tw4 ,l);
        v = bfly(v, 2,tw2 ,l);
        float2 o = shfl2(v,1);
        v = (l&1) ? csub(o,v) : cadd(v,o);
        y[k] = v;
    }
}

// DIT butterfly: low lane: v + tw*o ; high lane: o - tw*v
__device__ __forceinline__ float2 bflyi(float2 v, int m, float2 tw, int l){
    float2 o = shfl2(v, m);
    float2 t = cxmul(tw, (l & m) ? v : o);
    return (l & m) ? csub(o, t) : cadd(v, t);
}

// inverse 160-pt FFT consuming the forward's permuted register layout:
// entry: slot k lane l = X[k + 5*br5(l)]; exit: y[n1] = x[n1*32+l] (UNscaled).
__device__ __forceinline__ void ilinefft_perm(float2 y[5], int l){
    float2 tw2  = twid<-1>((float)(l & 1)  * (1.f/4.f));
    float2 tw4  = twid<-1>((float)(l & 3)  * (1.f/8.f));
    float2 tw8  = twid<-1>((float)(l & 7)  * (1.f/16.f));
    float2 tw16 = twid<-1>((float)(l & 15) * (1.f/32.f));
    #pragma unroll
    for (int k=0;k<5;k++){
        float2 v = y[k];
        { float2 o = shfl2(v,1); v = (l&1) ? csub(o,v) : cadd(v,o); }
        v = bflyi(v, 2, tw2 , l);
        v = bflyi(v, 4, tw4 , l);
        v = bflyi(v, 8, tw8 , l);
        v = bflyi(v,16, tw16, l);
        y[k] = v;
    }
    float2 w1 = twid<-1>((float)l * (1.f/160.f));
    float2 w2 = cxmul(w1,w1);
    float2 w3 = cxmul(w2,w1);
    float2 w4 = cxmul(w2,w2);
    y[1]=cxmul(y[1],w1); y[2]=cxmul(y[2],w2); y[3]=cxmul(y[3],w3); y[4]=cxmul(y[4],w4);
    dft5<-1>(y);
}

struct RPc {
    __half2* C[3];
    const __half* M[3];
};

// analytic kernel ingredients: Q sums over (dy,dz) ball slices, per column
struct QCol {
    float Q1_0, Q1_1;
    float Q2_0, Q2_1, Q2_2;
    float Q3_0, Q3_1, Q3_2, Q3_3;
    float fz2;
};

__device__ __forceinline__ QCol make_qcol(float ay0,float ay1,float ay2,float ay3, int kz){
    float fz = (float)kz * (1.f/160.f);
    float cz1 = fcos_rev(fz);
    float cz2 = 2.f*cz1*cz1 - 1.f;
    float cz3 = 2.f*cz1*cz2 - cz1;
    float az0=1.f, az1=2.f*cz1, az2=2.f*cz2, az3=2.f*cz3;
    float P00=ay0*az0, P01=ay0*az1, P02=ay0*az2, P03=ay0*az3;
    float P10=ay1*az0, P11=ay1*az1, P12=ay1*az2;
    float P20=ay2*az0, P21=ay2*az1, P22=ay2*az2;
    float P30=ay3*az0;
    QCol q;
    q.Q1_0 = P00 + P01 + P10;
    q.Q1_1 = P00;
    q.Q2_0 = P00+P01+P02+P10+P11+P20;
    q.Q2_1 = P00+P01+P10+P11;
    q.Q2_2 = P00;
    q.Q3_0 = P00+P01+P02+P03+P10+P11+P12+P20+P21+P22+P30;
    q.Q3_1 = P00+P01+P02+P10+P11+P12+P20+P21+P22;
    q.Q3_2 = P00+P01+P02+P10+P11+P12+P20+P21;
    q.Q3_3 = P00;
    q.fz2 = fz*fz;
    return q;
}

// all three K_r with one cosine chain. kx in [0,160).
__device__ __forceinline__ void kval3(const QCol& q, float fy2, int kx, float K[3]){
    float c1 = fcos_rev((float)kx * (1.f/160.f));
    float c2 = 2.f*c1*c1 - 1.f;
    float c3 = 2.f*c1*c2 - c1;
    float s1 = (q.Q1_0 + 2.f*c1*q.Q1_1) * (1.f/7.f);
    float s2 = (q.Q2_0 + 2.f*(c1*q.Q2_1 + c2*q.Q2_2)) * (1.f/33.f);
    float s3 = (q.Q3_0 + 2.f*(c1*q.Q3_1 + c2*q.Q3_2 + c3*q.Q3_3)) * (1.f/123.f);
    float fxw = (float)((kx < 80) ? kx : 160 - kx) * (1.f/160.f);
    float k2 = fxw*fxw + fy2 + q.fz2;
    float D = (1.f/3.f) - ((k2 == 0.f) ? 0.f : q.fz2 * __builtin_amdgcn_rcpf(k2));
    K[0] = (1.f - s1) * D;
    K[1] = (1.f - s2) * D;
    K[2] = (1.f - s3) * D;
}

// ---------------- CG reduction helper ----------------
__device__ __forceinline__ void block_atomic_add(double v, double* target){
    #pragma unroll
    for (int off=32; off>0; off>>=1) v += __shfl_down(v, off, 64);
    __shared__ double sm[4];
    int wv = threadIdx.x >> 6;
    if ((threadIdx.x & 63) == 0) sm[wv] = v;
    __syncthreads();
    if (threadIdx.x == 0) atomicAdd(target, sm[0]+sm[1]+sm[2]+sm[3]);
}

// ======== z-axis kernels: wave-local, barrier-free ========
// Forward passes carry 1/160 each axis; inverse passes are UNscaled.
// PM=0: fft real zin. PM=1: p = r + beta*p (beta=S[3]), store p, fft p.
template<int PM>
__global__ __launch_bounds__(256) void fft_z_first(const float* __restrict__ zin,
    const float* __restrict__ rrv, float* __restrict__ ppv,
    __half2* __restrict__ out, const double* __restrict__ S)
{
    __shared__ float2 ldsC[8*162];
    int tid = threadIdx.x, l = tid & 31, g = tid >> 5;
    int fl = g*162;
    size_t base160 = (size_t)blockIdx.x * 2560 + (size_t)(2*g)*160;
    size_t baseC   = (size_t)blockIdx.x * 1296 + (size_t)g*162;
    float beta = PM ? (float)S[3] : 0.f;
    float2 y[5];
    #pragma unroll
    for (int n1=0;n1<5;n1++){
        int n = n1*32 + l;
        float a, b;
        if (PM){
            a = rrv[base160 + n]       + beta * ppv[base160 + n];
            b = rrv[base160 + 160 + n] + beta * ppv[base160 + 160 + n];
            ppv[base160 + n] = a;
            ppv[base160 + 160 + n] = b;
        } else {
            a = zin[base160 + n];
            b = zin[base160 + 160 + n];
        }
        y[n1] = make_float2(a * SC160, b * SC160);   // fwd 1/160
    }
    linefft<1>(y, l);
    int o5 = 5*br5(l);
    #pragma unroll
    for (int k=0;k<5;k++) ldsC[fl + o5 + k] = y[k];
    #pragma unroll
    for (int t=0;t<6;t++){
        int j = l + 32*t;
        if (j < 162){
            int k = (j < 81) ? j : j - 81;
            float2 Sk = ldsC[fl + k];
            float2 Sm = ldsC[fl + ((160 - k) % 160)];
            float2 o = (j >= 81)
                ? make_float2(0.5f*(Sk.y + Sm.y), -0.5f*(Sk.x - Sm.x))    // B
                : make_float2(0.5f*(Sk.x + Sm.x),  0.5f*(Sk.y - Sm.y));   // A
            out[baseC + j] = f2h(o);
        }
    }
}

// fused: inverse-z (unscaled) -> *(m2w_r/160) -> forward-z
template<bool PRE>
__global__ __launch_bounds__(256) void fft_z_mid3(RPc P, const float* __restrict__ mask,
                                                 const float* __restrict__ wfull)
{
    __shared__ float2 ldsC[8*162];
    int r = blockIdx.y;
    __half2* C = P.C[r];
    int tid = threadIdx.x, l = tid & 31, g = tid >> 5;
    int fl = g*162;
    size_t baseC   = (size_t)blockIdx.x * 1296 + (size_t)g*162;
    size_t base160 = (size_t)blockIdx.x * 2560 + (size_t)(2*g)*160;
    int o5 = 5*br5(l);
    float ma[5], mb[5];
    if (PRE){
        const __half* M = P.M[r];
        #pragma unroll
        for (int k=0;k<5;k++){
            ma[k] = __half2float(M[base160 + o5 + k]) * SC160;
            mb[k] = __half2float(M[base160 + 160 + o5 + k]) * SC160;
        }
    } else {
        #pragma unroll
        for (int k=0;k<5;k++){
            size_t ia = base160 + o5 + k, ib = base160 + 160 + o5 + k;
            float m1 = mask[ia], m2 = mask[ib];
            ma[k] = m1*m1*wfull[ia*3 + r] * SC160;
            mb[k] = m2*m2*wfull[ib*3 + r] * SC160;
        }
    }
    #pragma unroll
    for (int t=0;t<6;t++){
        int j = l + 32*t;
        if (j < 162) ldsC[fl + j] = h2f(C[baseC + j]);
    }
    float2 y[5];
    #pragma unroll
    for (int n1=0;n1<5;n1++){
        int e = n1*32 + l;
        float2 X;
        if (e <= 80){
            float2 A = ldsC[fl + e], B = ldsC[fl + 81 + e];
            X = make_float2(A.x - B.y, A.y + B.x);
        } else {
            int m = 160 - e;
            float2 A = ldsC[fl + m], B = ldsC[fl + 81 + m];
            X = make_float2(A.x + B.y, B.x - A.y);
        }
        y[n1] = X;
    }
    linefft<-1>(y, l);
    #pragma unroll
    for (int k=0;k<5;k++){
        float a = y[k].x * ma[k];     // m2w/160 applied; fwd needs no extra scale
        float b = y[k].y * mb[k];
        ldsC[fl + o5 + k] = make_float2(a, b);
    }
    #pragma unroll
    for (int n1=0;n1<5;n1++) y[n1] = ldsC[fl + n1*32 + l];
    linefft<1>(y, l);
    #pragma unroll
    for (int k=0;k<5;k++) ldsC[fl + o5 + k] = y[k];
    #pragma unroll
    for (int t=0;t<6;t++){
        int j = l + 32*t;
        if (j < 162){
            int k = (j < 81) ? j : j - 81;
            float2 Sk = ldsC[fl + k];
            float2 Sm = ldsC[fl + ((160 - k) % 160)];
            float2 o = (j >= 81)
                ? make_float2(0.5f*(Sk.y + Sm.y), -0.5f*(Sk.x - Sm.x))
                : make_float2(0.5f*(Sk.x + Sm.x),  0.5f*(Sk.y - Sm.y));
            C[baseC + j] = f2h(o);
        }
    }
}

// final inverse-z (unscaled) + epilogue.
// FIN=0: Ap=v, S[1]+=<z,v>. FIN=1: r=b-v -> rr,pp, S[0]+=<r,r>.
template<int FIN>
__global__ __launch_bounds__(256) void fft_z_fin(const __half2* __restrict__ in,
    const float* __restrict__ zsp, float* __restrict__ Ap,
    const float* __restrict__ bb, float* __restrict__ rrv, float* __restrict__ ppv,
    double* __restrict__ S)
{
    __shared__ float2 ldsC[8*162];
    float* ldsF = (float*)ldsC;      // region g: floats [324g, 324g+320)
    int tid = threadIdx.x, l = tid & 31, g = tid >> 5;
    int fl = g*162;
    size_t baseC   = (size_t)blockIdx.x * 1296 + (size_t)g*162;
    size_t base160 = (size_t)blockIdx.x * 2560 + (size_t)(2*g)*160;
    int o5 = 5*br5(l);
    float za[5], zb[5], pa[5], pb[5];
    #pragma unroll
    for (int k=0;k<5;k++){
        za[k] = zsp[base160 + o5 + k];
        zb[k] = zsp[base160 + 160 + o5 + k];
        if (FIN){
            pa[k] = bb[base160 + o5 + k];
            pb[k] = bb[base160 + 160 + o5 + k];
        }
    }
    #pragma unroll
    for (int t=0;t<6;t++){
        int j = l + 32*t;
        if (j < 162) ldsC[fl + j] = h2f(in[baseC + j]);
    }
    float2 y[5];
    #pragma unroll
    for (int n1=0;n1<5;n1++){
        int e = n1*32 + l;
        float2 X;
        if (e <= 80){
            float2 A = ldsC[fl + e], B = ldsC[fl + 81 + e];
            X = make_float2(A.x - B.y, A.y + B.x);
        } else {
            int m = 160 - e;
            float2 A = ldsC[fl + m], B = ldsC[fl + 81 + m];
            X = make_float2(A.x + B.y, B.x - A.y);
        }
        y[n1] = X;
    }
    linefft<-1>(y, l);
    double acc = 0.0;
    int fb = g*324;
    #pragma unroll
    for (int k=0;k<5;k++){
        float va = LAM_F*za[k] + y[k].x;      // inverse unscaled
        float vb = LAM_F*zb[k] + y[k].y;
        if (FIN == 0){
            acc += (double)za[k]*(double)va + (double)zb[k]*(double)vb;
            ldsF[fb + o5 + k] = va;
            ldsF[fb + 160 + o5 + k] = vb;
        } else {
            float ra = pa[k] - va, rb = pb[k] - vb;
            acc += (double)ra*(double)ra + (double)rb*(double)rb;
            ldsF[fb + o5 + k] = ra;
            ldsF[fb + 160 + o5 + k] = rb;
        }
    }
    #pragma unroll
    for (int t=0;t<10;t++){
        int n = l + 32*t;
        float v = ldsF[fb + n];
        if (FIN == 0){
            Ap[base160 + n] = v;
        } else {
            rrv[base160 + n] = v;
            ppv[base160 + n] = v;
        }
    }
    block_atomic_add(acc, FIN ? &S[0] : &S[1]);
}

// ---------------- y-axis sweeps (strided, guarded half-spectrum, W=8) ----------------
// SGN>0 (fwd): scale 1/160 ; SGN<0 (inv): unscaled.
template<int SGN>
__device__ __forceinline__ void ycompute(float2 (*tile)[WZ+1], int tid){
    int l = tid & 31, q = tid >> 5;
    const float SC = (SGN>0) ? SC160 : 1.f;
    float2 y[5];
    #pragma unroll
    for (int n1=0;n1<5;n1++) y[n1] = tile[l + 32*n1][q];
    linefft<SGN>(y, l);
    int o5 = 5*br5(l);
    #pragma unroll
    for (int k=0;k<5;k++) tile[o5+k][q] = cscale(y[k], SC);
}

// b = zchunk*160 + ix  (zb-outer so line-sharing blocks b, b+160 share an XCD)
template<int SGN>
__global__ __launch_bounds__(256) void fft_y1(__half2* __restrict__ data)
{
    __shared__ float2 tile[NN][WZ+1];
    int b = blockIdx.x;
    int ix = b % 160, zb = (b / 160) * WZ;
    size_t tbase = (size_t)ix*XS + zb;
    int tid = threadIdx.x;
    for (int i = tid; i < NN*WZ; i += 256){
        int row = i >> 3, zi = i & 7;
        tile[row][zi] = (zb + zi < KP) ? h2f(data[tbase + (size_t)row*KP + zi]) : make_float2(0.f,0.f);
    }
    __syncthreads();
    ycompute<SGN>(tile, tid);
    __syncthreads();
    for (int i = tid; i < NN*WZ; i += 256){
        int row = i >> 3, zi = i & 7;
        if (zb + zi < KP) data[tbase + (size_t)row*KP + zi] = f2h(tile[row][zi]);
    }
}

template<int SGN>
__global__ __launch_bounds__(256) void fft_y3(RPc P)
{
    __shared__ float2 tile[NN][WZ+1];
    __half2* data = P.C[blockIdx.y];
    int b = blockIdx.x;
    int ix = b % 160, zb = (b / 160) * WZ;
    size_t tbase = (size_t)ix*XS + zb;
    int tid = threadIdx.x;
    for (int i = tid; i < NN*WZ; i += 256){
        int row = i >> 3, zi = i & 7;
        tile[row][zi] = (zb + zi < KP) ? h2f(data[tbase + (size_t)row*KP + zi]) : make_float2(0.f,0.f);
    }
    __syncthreads();
    ycompute<SGN>(tile, tid);
    __syncthreads();
    for (int i = tid; i < NN*WZ; i += 256){
        int row = i >> 3, zi = i & 7;
        if (zb + zi < KP) data[tbase + (size_t)row*KP + zi] = f2h(tile[row][zi]);
    }
}

// ---------------- x-axis kernels with analytic K ----------------
// spread: one block per (iy, zb). Shared fwd-x FFT once, then per radius:
// scale K_r/160, ilinefft_perm (registers), column-private write, coop store C_r.
__global__ __launch_bounds__(256) void fft_xK(RPc P, const __half2* __restrict__ in)
{
    __shared__ float2 tile[NN][WZ+1];
    int b = blockIdx.x;
    int iy = b % 160, zb = (b / 160) * WZ;
    size_t tbase = (size_t)iy*KP + zb;
    int tid = threadIdx.x, l = tid & 31, q = tid >> 5;
    for (int i = tid; i < NN*WZ; i += 256){
        int row = i >> 3, zi = i & 7;
        tile[row][zi] = (zb + zi < KP) ? h2f(in[tbase + (size_t)row*XS + zi]) : make_float2(0.f,0.f);
    }
    __syncthreads();
    float fy = (float)((iy < 80) ? iy : iy - 160) * (1.f/160.f);
    float fy2 = fy*fy;
    float cy1 = fcos_rev(fy);
    float cy2 = 2.f*cy1*cy1 - 1.f;
    float cy3 = 2.f*cy1*cy2 - cy1;
    QCol qc = make_qcol(1.f, 2.f*cy1, 2.f*cy2, 2.f*cy3, zb + q);
    int o5 = 5*br5(l);
    float2 spec[5];
    #pragma unroll
    for (int n1=0;n1<5;n1++) spec[n1] = tile[n1*32 + l][q];
    linefft<1>(spec, l);
    float K3[5][3];
    #pragma unroll
    for (int k=0;k<5;k++) kval3(qc, fy2, o5+k, K3[k]);
    #pragma unroll
    for (int r=0; r<3; r++){
        float2 acc[5];
        #pragma unroll
        for (int k=0;k<5;k++) acc[k] = cscale(spec[k], K3[k][r] * SC160);
        ilinefft_perm(acc, l);
        // column q is group-private between coop phases
        #pragma unroll
        for (int n1=0;n1<5;n1++) tile[n1*32 + l][q] = acc[n1];
        __syncthreads();
        __half2* Cr = P.C[r];
        for (int i = tid; i < NN*WZ; i += 256){
            int row = i >> 3, zi = i & 7;
            if (zb + zi < KP) Cr[tbase + (size_t)row*XS + zi] = f2h(tile[row][zi]);
        }
        __syncthreads();
    }
}

// gather: CF = invx( sum_r (K_r/160) * fwdx(C_r) ), single tile + reg staging
__global__ __launch_bounds__(256) void fft_xgather(RPc P, __half2* __restrict__ out)
{
    __shared__ float2 tile[NN][WZ+1];
    int b = blockIdx.x;
    int iy = b % 160, zb = (b / 160) * WZ;
    size_t tbase = (size_t)iy*KP + zb;
    int tid = threadIdx.x, l = tid & 31, q = tid >> 5;
    // cooperative load C0 -> tile
    #pragma unroll
    for (int j=0;j<5;j++){
        int i = tid + 256*j;
        int row = i >> 3, zi = i & 7;
        tile[row][zi] = (zb + zi < KP) ? h2f(P.C[0][tbase + (size_t)row*XS + zi]) : make_float2(0.f,0.f);
    }
    __syncthreads();
    float fy = (float)((iy < 80) ? iy : iy - 160) * (1.f/160.f);
    float fy2 = fy*fy;
    float cy1 = fcos_rev(fy);
    float cy2 = 2.f*cy1*cy1 - 1.f;
    float cy3 = 2.f*cy1*cy2 - cy1;
    QCol qc = make_qcol(1.f, 2.f*cy1, 2.f*cy2, 2.f*cy3, zb + q);
    int o5 = 5*br5(l);
    float K3[5][3];
    #pragma unroll
    for (int k=0;k<5;k++) kval3(qc, fy2, o5+k, K3[k]);

    // issue C1 loads early (hide under FFT of C0)
    float2 st[5];
    #pragma unroll
    for (int j=0;j<5;j++){
        int i = tid + 256*j;
        int row = i >> 3, zi = i & 7;
        st[j] = (zb + zi < KP) ? h2f(P.C[1][tbase + (size_t)row*XS + zi]) : make_float2(0.f,0.f);
    }
    float2 y[5], acc[5];
    #pragma unroll
    for (int n1=0;n1<5;n1++) y[n1] = tile[n1*32 + l][q];
    linefft<1>(y, l);
    #pragma unroll
    for (int k=0;k<5;k++) acc[k] = cscale(y[k], K3[k][0] * SC160);
    __syncthreads();
    // write staged C1, issue C2 loads
    #pragma unroll
    for (int j=0;j<5;j++){
        int i = tid + 256*j;
        tile[i >> 3][i & 7] = st[j];
    }
    __syncthreads();
    #pragma unroll
    for (int j=0;j<5;j++){
        int i = tid + 256*j;
        int row = i >> 3, zi = i & 7;
        st[j] = (zb + zi < KP) ? h2f(P.C[2][tbase + (size_t)row*XS + zi]) : make_float2(0.f,0.f);
    }
    #pragma unroll
    for (int n1=0;n1<5;n1++) y[n1] = tile[n1*32 + l][q];
    linefft<1>(y, l);
    #pragma unroll
    for (int k=0;k<5;k++) acc[k] = cadd(acc[k], cscale(y[k], K3[k][1] * SC160));
    __syncthreads();
    #pragma unroll
    for (int j=0;j<5;j++){
        int i = tid + 256*j;
        tile[i >> 3][i & 7] = st[j];
    }
    __syncthreads();
    #pragma unroll
    for (int n1=0;n1<5;n1++) y[n1] = tile[n1*32 + l][q];
    linefft<1>(y, l);
    #pragma unroll
    for (int k=0;k<5;k++) acc[k] = cadd(acc[k], cscale(y[k], K3[k][2] * SC160));
    ilinefft_perm(acc, l);
    __syncthreads();
    #pragma unroll
    for (int n1=0;n1<5;n1++) tile[n1*32 + l][q] = acc[n1];
    __syncthreads();
    for (int i = tid; i < NN*WZ; i += 256){
        int row = i >> 3, zi = i & 7;
        if (zb + zi < KP) out[tbase + (size_t)row*XS + zi] = f2h(tile[row][zi]);
    }
}

// ---------------- setup / CG vector ops ----------------
__global__ __launch_bounds__(256) void m2w_kernel(const float* __restrict__ mask,
        const float* __restrict__ w, __half* __restrict__ M0,
        __half* __restrict__ M1, __half* __restrict__ M2)
{
    int i = blockIdx.x*256 + threadIdx.x;
    float m = mask[i]; float mm = m*m;
    M0[i] = __float2half(mm * w[3*(size_t)i+0]);
    M1[i] = __float2half(mm * w[3*(size_t)i+1]);
    M2[i] = __float2half(mm * w[3*(size_t)i+2]);
}

__global__ __launch_bounds__(256) void copy_kernel(const float* __restrict__ a, float* __restrict__ b){
    int i = blockIdx.x*256 + threadIdx.x;
    b[i] = a[i];
}

#define GSTRIDE (2048*256)
__global__ __launch_bounds__(256) void upd1_kernel(float* __restrict__ x, float* __restrict__ r,
        const float* __restrict__ p, const float* __restrict__ Ap, double* s)
{
    float alpha = (float)(s[0] / (s[1] + 1e-12));
    double acc = 0.0;
    for (int i = blockIdx.x*256 + threadIdx.x; i < N3; i += GSTRIDE){
        x[i] += alpha * p[i];
        float rn = r[i] - alpha * Ap[i];
        r[i] = rn;
        acc += (double)rn * (double)rn;
    }
    block_atomic_add(acc, &s[2]);
}
__global__ void advance_kernel(double* s){
    if (threadIdx.x == 0){
        s[3] = s[2] / (s[0] + 1e-12);   // beta
        s[0] = s[2]; s[1] = 0.0; s[2] = 0.0;
    }
}
__global__ void zero_kernel(double* s){
    if (threadIdx.x < 4) s[threadIdx.x] = 0.0;
}

// ---------------- host orchestration ----------------
extern "C" void kernel_launch(void* const* d_in, const int* in_sizes, int n_in,
                              void* d_out, int out_size, void* d_ws, size_t ws_size,
                              hipStream_t stream)
{
    (void)in_sizes; (void)n_in; (void)out_size;
    const float* w    = (const float*)d_in[0];   // [N3*3], R fastest
    const float* x2   = (const float*)d_in[1];   // [N3]
    const float* mask = (const float*)d_in[2];   // [N3]
    const float* bb   = (const float*)d_in[3];   // [N3]
    float* x = (float*)d_out;
    char* ws = (char*)d_ws;

    size_t off = 0;
    auto alloc = [&](size_t bytes)->void*{
        void* pp = ws + off;
        off += (bytes + 255) & ~(size_t)255;
        return pp;
    };
    const size_t CB = (size_t)NLINES * KP * sizeof(__half2);   // 8.3 MB
    __half2* CF = (__half2*)alloc(CB);
    __half2* C0 = (__half2*)alloc(CB);
    __half2* C1 = (__half2*)alloc(CB);
    __half2* C2 = (__half2*)alloc(CB);
    float*  rr = (float*) alloc((size_t)N3*4);
    float*  pp = (float*) alloc((size_t)N3*4);
    float*  Ap = (float*) alloc((size_t)N3*4);
    double* S  = (double*)alloc(64);
    bool PRE = (ws_size >= off + 3*(((size_t)N3*2 + 255) & ~(size_t)255));
    __half *M0=nullptr, *M1=nullptr, *M2=nullptr;
    if (PRE){
        M0 = (__half*)alloc((size_t)N3*2);
        M1 = (__half*)alloc((size_t)N3*2);
        M2 = (__half*)alloc((size_t)N3*2);
    }
    RPc P;
    P.C[0]=C0; P.C[1]=C1; P.C[2]=C2;
    P.M[0]=M0; P.M[1]=M1; P.M[2]=M2;

    zero_kernel<<<1, 64, 0, stream>>>(S);
    if (PRE) m2w_kernel<<<16000, 256, 0, stream>>>(mask, w, M0, M1, M2);
    copy_kernel<<<16000, 256, 0, stream>>>(x2, x);

    const int GY = NBZ * 160;    // 1760
    // PM: 0 = plain fft of z; 1 = fused p-update. FIN: 1 = initial residual, 0 = CG iter.
    auto applyM = [&](const float* z, int FIN, int PM){
        if (PM) fft_z_first<1><<<1600, 256, 0, stream>>>(z, rr, pp, CF, S);
        else    fft_z_first<0><<<1600, 256, 0, stream>>>(z, rr, pp, CF, S);
        fft_y1<1><<<GY, 256, 0, stream>>>(CF);
        fft_xK<<<GY, 256, 0, stream>>>(P, CF);
        fft_y3<-1><<<dim3(GY,3), 256, 0, stream>>>(P);
        if (PRE) fft_z_mid3<true ><<<dim3(1600,3), 256, 0, stream>>>(P, mask, w);
        else     fft_z_mid3<false><<<dim3(1600,3), 256, 0, stream>>>(P, mask, w);
        fft_y3<1><<<dim3(GY,3), 256, 0, stream>>>(P);
        fft_xgather<<<GY, 256, 0, stream>>>(P, CF);
        fft_y1<-1><<<GY, 256, 0, stream>>>(CF);
        if (FIN) fft_z_fin<1><<<1600, 256, 0, stream>>>(CF, x, Ap, bb, rr, pp, S);
        else     fft_z_fin<0><<<1600, 256, 0, stream>>>(CF, pp, Ap, bb, rr, pp, S);
    };

    // r = b - M(x2); p = r; rs = <r,r>
    applyM(x, 1, 0);

    for (int it = 0; it < 10; it++){
        applyM(pp, 0, (it == 0) ? 0 : 1);          // Ap = M(p), S[1] = <p,Ap>
        upd1_kernel<<<2048, 256, 0, stream>>>(x, rr, pp, Ap, S);
        if (it < 9) advance_kernel<<<1, 64, 0, stream>>>(S);
    }
}